// Round 5
// baseline (310.899 us; speedup 1.0000x reference)
//
#include <hip/hip_runtime.h>
#include <math.h>

#define B_    2
#define SEQ_  2048
#define D_    256
#define H_    8
#define DK_   32
#define L_    2
#define DFF_  1024

// decay cutoff: exp(-44) ~ 8e-20, below fp32 noise for any plausible score scale
#define TD_CUT 44.0f

typedef short  bf16x8 __attribute__((ext_vector_type(8)));
typedef float  f32x4  __attribute__((ext_vector_type(4)));

__device__ __forceinline__ int compute_kcut(float tdv) {
    int kcut = SEQ_;
    if (tdv > 1e-9f) {
        float kc = TD_CUT / tdv;
        kcut = (kc >= (float)SEQ_) ? SEQ_ : ((int)kc + 1);
    }
    int kcr = (kcut + 31) & ~31;          // round up to tile size
    if (kcr > SEQ_) kcr = SEQ_;
    return kcr;
}

__device__ __forceinline__ unsigned short f2bf(float f) {
    unsigned int u = __float_as_uint(f);
    unsigned int r = u + 0x7FFFu + ((u >> 16) & 1u);   // round-to-nearest-even
    return (unsigned short)(r >> 16);
}
__device__ __forceinline__ float bf2f(unsigned short u) {
    return __uint_as_float(((unsigned int)u) << 16);
}

// async 16B global -> LDS DMA (dest = wave-uniform base + lane*16)
__device__ __forceinline__ void gload_lds16(const unsigned short* g, unsigned short* l) {
    __builtin_amdgcn_global_load_lds(
        (const __attribute__((address_space(1))) unsigned int*)(const unsigned int*)g,
        (__attribute__((address_space(3))) unsigned int*)(unsigned int*)l,
        16, 0, 0);
}

// ---------------------------------------------------------------------------
// Kernel 0: fp32 -> bf16 weight pre-convert (all 6 weight tensors, both layers)
// ---------------------------------------------------------------------------
__global__ __launch_bounds__(256) void cvt_kernel(
    const float* __restrict__ p0, const float* __restrict__ p1,
    const float* __restrict__ p2, const float* __restrict__ p3,
    const float* __restrict__ p4, const float* __restrict__ p5,
    unsigned short* __restrict__ q0, unsigned short* __restrict__ q1,
    unsigned short* __restrict__ q2, unsigned short* __restrict__ q3,
    unsigned short* __restrict__ q4, unsigned short* __restrict__ q5)
{
    int t = blockIdx.x * 256 + threadIdx.x;        // chunk of 8 elems
    const float* src; unsigned short* dst; int base;
    if (t < 65536) {
        int a = t >> 14;                           // 0..3
        src = a == 0 ? p0 : a == 1 ? p1 : a == 2 ? p2 : p3;
        dst = a == 0 ? q0 : a == 1 ? q1 : a == 2 ? q2 : q3;
        base = (t & 16383) * 8;
    } else {
        int u = t - 65536;
        int a = u >> 16;                           // 0..1
        src = a ? p5 : p4;
        dst = a ? q5 : q4;
        base = (u & 65535) * 8;
    }
    float4 v0 = *(const float4*)(src + base);
    float4 v1 = *(const float4*)(src + base + 4);
    bf16x8 o;
    o[0] = (short)f2bf(v0.x); o[1] = (short)f2bf(v0.y);
    o[2] = (short)f2bf(v0.z); o[3] = (short)f2bf(v0.w);
    o[4] = (short)f2bf(v1.x); o[5] = (short)f2bf(v1.y);
    o[6] = (short)f2bf(v1.z); o[7] = (short)f2bf(v1.w);
    *(bf16x8*)(dst + base) = o;
}

// ---------------------------------------------------------------------------
// Kernel 1: conv1d(K=3, SAME) + bias + affine + relu + pe; fp32 + bf16 out.
// ---------------------------------------------------------------------------
__global__ __launch_bounds__(256) void conv_pe_kernel(
    const float* __restrict__ x, const float* __restrict__ w,
    const float* __restrict__ cb, const float* __restrict__ bg,
    const float* __restrict__ bb, const float* __restrict__ pe,
    float* __restrict__ h, unsigned short* __restrict__ hbf)
{
    int idx = blockIdx.x * 256 + threadIdx.x;      // b*SEQ*D + s*D + d
    int d = idx & 255;
    int s = (idx >> 8) & 2047;
    int b = idx >> 19;

    const float* xp = x + b * SEQ_;
    float xm1 = (s > 0)        ? xp[s - 1] : 0.f;
    float x0  = xp[s];
    float xp1 = (s < SEQ_ - 1) ? xp[s + 1] : 0.f;

    float acc = xm1 * w[d * 3 + 0] + x0 * w[d * 3 + 1] + xp1 * w[d * 3 + 2];
    acc += cb[d];
    acc = acc * rsqrtf(1.f + 1e-5f) * bg[d] + bb[d];
    acc = fmaxf(acc, 0.f);
    float v = acc + pe[s * D_ + d];
    h[idx] = v;
    hbf[idx] = f2bf(v);
}

// ---------------------------------------------------------------------------
// Kernel 2: q/k/v GEMM, bf16 in / bf16 out.  C[m,n] = A[m,:]·W[n,:] + bias[n].
// 64x64 tile, BK=32, 4 waves 2x2 of 32x32. blockIdx.z selects (W,bias,C).
// ---------------------------------------------------------------------------
__global__ __launch_bounds__(256) void gemm_qkv(
    const unsigned short* __restrict__ A,
    const unsigned short* __restrict__ W0, const unsigned short* __restrict__ W1,
    const unsigned short* __restrict__ W2,
    const float* __restrict__ b0, const float* __restrict__ b1,
    const float* __restrict__ b2,
    unsigned short* __restrict__ O0, unsigned short* __restrict__ O1,
    unsigned short* __restrict__ O2,
    int M, int N, int K)
{
    int z = blockIdx.z;
    const unsigned short* W = (z == 0) ? W0 : (z == 1) ? W1 : W2;
    const float* bias = (z == 0) ? b0 : (z == 1) ? b1 : b2;
    unsigned short* C = (z == 0) ? O0 : (z == 1) ? O1 : O2;

    __shared__ unsigned short As[64 * 32];
    __shared__ unsigned short Bs[64 * 32];

    int tid  = threadIdx.x;
    int wave = tid >> 6, lane = tid & 63;
    int wm = (wave & 1) * 32, wn = (wave >> 1) * 32;
    int bm = blockIdx.y * 64, bn = blockIdx.x * 64;

    int sr  = tid >> 2;
    int scb = (tid & 3) ^ (sr & 3);
    const unsigned short* aG = A + (size_t)(bm + sr) * K + scb * 8;
    const unsigned short* wG = W + (size_t)(bn + sr) * K + scb * 8;
    unsigned short* aL = &As[tid * 8];
    unsigned short* bL = &Bs[tid * 8];

    int fr = lane & 15;
    int kb = lane >> 4;
    int cb = (kb ^ (fr & 3)) * 8;
    int oA0 = (wm + fr) * 32 + cb;
    int oA1 = (wm + 16 + fr) * 32 + cb;
    int oB0 = (wn + fr) * 32 + cb;
    int oB1 = (wn + 16 + fr) * 32 + cb;

    f32x4 acc[2][2];
#pragma unroll
    for (int i = 0; i < 2; ++i)
#pragma unroll
        for (int j = 0; j < 2; ++j) acc[i][j] = (f32x4){0.f, 0.f, 0.f, 0.f};

    for (int k0 = 0; k0 < K; k0 += 32) {
        __syncthreads();
        gload_lds16(aG + k0, aL);
        gload_lds16(wG + k0, bL);
        __syncthreads();

        bf16x8 a0f = *(const bf16x8*)&As[oA0];
        bf16x8 a1f = *(const bf16x8*)&As[oA1];
        bf16x8 b0f = *(const bf16x8*)&Bs[oB0];
        bf16x8 b1f = *(const bf16x8*)&Bs[oB1];

        acc[0][0] = __builtin_amdgcn_mfma_f32_16x16x32_bf16(a0f, b0f, acc[0][0], 0, 0, 0);
        acc[0][1] = __builtin_amdgcn_mfma_f32_16x16x32_bf16(a0f, b1f, acc[0][1], 0, 0, 0);
        acc[1][0] = __builtin_amdgcn_mfma_f32_16x16x32_bf16(a1f, b0f, acc[1][0], 0, 0, 0);
        acc[1][1] = __builtin_amdgcn_mfma_f32_16x16x32_bf16(a1f, b1f, acc[1][1], 0, 0, 0);
    }

    int crow = (lane >> 4) * 4;
    int ccol = lane & 15;
#pragma unroll
    for (int j = 0; j < 2; ++j) {
        float bj = bias[bn + wn + j * 16 + ccol];
#pragma unroll
        for (int i = 0; i < 2; ++i) {
#pragma unroll
            for (int r = 0; r < 4; ++r) {
                float v = acc[i][j][r] + bj;
                C[(size_t)(bm + wm + i * 16 + crow + r) * N + bn + wn + j * 16 + ccol] = f2bf(v);
            }
        }
    }
}

// ---------------------------------------------------------------------------
// Kernel 2b: row-wide GEMM, block = 64 rows x 256 cols, 4 waves each 64x64
// (4x4 tiles of 16x16 -> 16 MFMA/wave/K-step, m97 density).
// mode 0: C = relu(A@W^T + bias) -> bf16 cbf (cols offset bn = blockIdx.x*256)
// mode 1: h = LayerNorm(resid + A@W^T + bias)*g + b -> fp32 hout + bf16 hbfout
//         (full 256-col row per block enables the fused LN)
// ---------------------------------------------------------------------------
__global__ __launch_bounds__(256) void gemm_row256(
    const unsigned short* __restrict__ A, const unsigned short* __restrict__ W,
    const float* __restrict__ bias, const float* __restrict__ resid,
    const float* __restrict__ g, const float* __restrict__ bta,
    float* __restrict__ hout, unsigned short* __restrict__ hbfout,
    unsigned short* __restrict__ cbf,
    int N, int K, int mode)
{
    __shared__ unsigned short As[64 * 32];      // 256 slots of 16B
    __shared__ unsigned short Bs[256 * 32];     // 1024 slots of 16B
    __shared__ float lsum[4][64];
    __shared__ float lsq[4][64];

    int tid = threadIdx.x;
    int wave = tid >> 6, lane = tid & 63;
    int bm = blockIdx.y * 64, bn = blockIdx.x * 256;

    // staging: 1280 slots, 5 per thread (slot = i*256 + tid)
    const unsigned short* gp[5];
    unsigned short* lp[5];
    {
        int s = tid;                            // i = 0 -> As
        int row = s >> 2, cbk = (s & 3) ^ (row & 3);
        gp[0] = A + (size_t)(bm + row) * K + cbk * 8;
        lp[0] = &As[s * 8];
#pragma unroll
        for (int i = 1; i < 5; ++i) {
            int sB = (i - 1) * 256 + tid;
            int r = sB >> 2, ck = (sB & 3) ^ (r & 3);
            gp[i] = W + (size_t)(bn + r) * K + ck * 8;
            lp[i] = &Bs[sB * 8];
        }
    }

    int fr = lane & 15, kb = lane >> 4;
    int oA[4], oB[4];
#pragma unroll
    for (int t = 0; t < 4; ++t) {
        int m = t * 16 + fr;
        oA[t] = m * 32 + ((kb ^ (m & 3)) * 8);
        int n = wave * 64 + t * 16 + fr;
        oB[t] = n * 32 + ((kb ^ (n & 3)) * 8);
    }

    f32x4 acc[4][4];
#pragma unroll
    for (int i = 0; i < 4; ++i)
#pragma unroll
        for (int j = 0; j < 4; ++j) acc[i][j] = (f32x4){0.f, 0.f, 0.f, 0.f};

    for (int k0 = 0; k0 < K; k0 += 32) {
        __syncthreads();
#pragma unroll
        for (int i = 0; i < 5; ++i) gload_lds16(gp[i] + k0, lp[i]);
        __syncthreads();

        bf16x8 af[4], bf[4];
#pragma unroll
        for (int t = 0; t < 4; ++t) af[t] = *(const bf16x8*)&As[oA[t]];
#pragma unroll
        for (int t = 0; t < 4; ++t) bf[t] = *(const bf16x8*)&Bs[oB[t]];
#pragma unroll
        for (int i = 0; i < 4; ++i)
#pragma unroll
            for (int j = 0; j < 4; ++j)
                acc[i][j] = __builtin_amdgcn_mfma_f32_16x16x32_bf16(af[i], bf[j], acc[i][j], 0, 0, 0);
    }

    int q = lane >> 4, cl = lane & 15;

    if (mode == 0) {                           // bias + relu -> bf16
#pragma unroll
        for (int ct = 0; ct < 4; ++ct) {
            int col = wave * 64 + ct * 16 + cl;
            float bj = bias[bn + col];
#pragma unroll
            for (int rt = 0; rt < 4; ++rt)
#pragma unroll
                for (int r = 0; r < 4; ++r) {
                    float v = fmaxf(acc[rt][ct][r] + bj, 0.f);
                    cbf[(size_t)(bm + rt * 16 + q * 4 + r) * N + bn + col] = f2bf(v);
                }
        }
        return;
    }

    // mode 1: z = resid + acc + bias; LayerNorm over the 256-col row
    float rsum[4][4], rsq[4][4];
#pragma unroll
    for (int rt = 0; rt < 4; ++rt)
#pragma unroll
        for (int r = 0; r < 4; ++r) { rsum[rt][r] = 0.f; rsq[rt][r] = 0.f; }

#pragma unroll
    for (int ct = 0; ct < 4; ++ct) {
        int col = wave * 64 + ct * 16 + cl;
        float bj = bias[col];
#pragma unroll
        for (int rt = 0; rt < 4; ++rt)
#pragma unroll
            for (int r = 0; r < 4; ++r) {
                int row = bm + rt * 16 + q * 4 + r;
                float z = acc[rt][ct][r] + bj + resid[(size_t)row * 256 + col];
                acc[rt][ct][r] = z;
                rsum[rt][r] += z;
                rsq[rt][r] += z * z;
            }
    }
    // reduce over the 16 lanes that share each row
#pragma unroll
    for (int rt = 0; rt < 4; ++rt)
#pragma unroll
        for (int r = 0; r < 4; ++r) {
#pragma unroll
            for (int off = 1; off < 16; off <<= 1) {
                rsum[rt][r] += __shfl_xor(rsum[rt][r], off);
                rsq[rt][r]  += __shfl_xor(rsq[rt][r], off);
            }
        }
    if (cl == 0) {
#pragma unroll
        for (int rt = 0; rt < 4; ++rt)
#pragma unroll
            for (int r = 0; r < 4; ++r) {
                lsum[wave][rt * 16 + q * 4 + r] = rsum[rt][r];
                lsq[wave][rt * 16 + q * 4 + r]  = rsq[rt][r];
            }
    }
    __syncthreads();
    if (tid < 64) {
        float s = lsum[0][tid] + lsum[1][tid] + lsum[2][tid] + lsum[3][tid];
        float sq = lsq[0][tid] + lsq[1][tid] + lsq[2][tid] + lsq[3][tid];
        float mean = s * (1.f / 256.f);
        float var = sq * (1.f / 256.f) - mean * mean;
        lsum[0][tid] = mean;
        lsq[0][tid]  = rsqrtf(var + 1e-5f);
    }
    __syncthreads();

#pragma unroll
    for (int rt = 0; rt < 4; ++rt)
#pragma unroll
        for (int r = 0; r < 4; ++r) {
            int lrow = rt * 16 + q * 4 + r;
            float mean = lsum[0][lrow];
            float inv  = lsq[0][lrow];
            int row = bm + lrow;
#pragma unroll
            for (int ct = 0; ct < 4; ++ct) {
                int col = wave * 64 + ct * 16 + cl;
                float o = (acc[rt][ct][r] - mean) * inv * g[col] + bta[col];
                hout[(size_t)row * 256 + col] = o;
                hbfout[(size_t)row * 256 + col] = f2bf(o);
            }
        }
}

// ---------------------------------------------------------------------------
// Kernel 3a: V-suffix partial sums (bf16 V), atomically accumulated.
// ---------------------------------------------------------------------------
__global__ __launch_bounds__(256) void vtail_kernel(
    const unsigned short* __restrict__ v, const float* __restrict__ td_l,
    float* __restrict__ vtail)
{
    int hh = blockIdx.x, b = blockIdx.y, z = blockIdx.z;
    int kcr = compute_kcut(td_l[hh]);
    int rbeg = z * 64, rend = rbeg + 64;
    if (rend <= kcr) return;
    int lo = rbeg > kcr ? rbeg : kcr;

    int d = threadIdx.x & 31, c = threadIdx.x >> 5;    // 8 row-chunks
    float s = 0.f;
    for (int k = lo + c; k < rend; k += 8)
        s += bf2f(v[((size_t)(b * SEQ_ + k)) * D_ + hh * DK_ + d]);

    __shared__ float sm[8][32];
    sm[c][d] = s;
    __syncthreads();
    if (threadIdx.x < 32) {
        float t = 0.f;
#pragma unroll
        for (int i = 0; i < 8; ++i) t += sm[i][threadIdx.x];
        atomicAdd(&vtail[((size_t)(b * H_ + hh)) * DK_ + threadIdx.x], t);
    }
}

// ---------------------------------------------------------------------------
// Kernel 3b: decay-truncated flash attention + analytic tail. bf16 in/out.
// ---------------------------------------------------------------------------
__global__ __launch_bounds__(128) void attn_kernel(
    const unsigned short* __restrict__ q, const unsigned short* __restrict__ k,
    const unsigned short* __restrict__ v, const float* __restrict__ vtail,
    unsigned short* __restrict__ ctxbf,
    const float* __restrict__ scale_p, const float* __restrict__ td_l)
{
    int b = blockIdx.z, hh = blockIdx.y;
    int tid = threadIdx.x;
    int qrow = blockIdx.x * 128 + tid;

    float sc  = 0.17677669529663687f * scale_p[0];   // 1/sqrt(32) * scale[l]
    float tdv = td_l[hh];
    int kcr = compute_kcut(tdv);
    int ntiles = kcr >> 5;

    __shared__ float kt[32][36];
    __shared__ float vt[32][36];

    const unsigned short* qptr = q + ((size_t)(b * SEQ_ + qrow)) * D_ + hh * DK_;
    float qreg[32];
#pragma unroll
    for (int j = 0; j < 4; ++j) {                    // 4 x uint4 = 32 bf16
        uint4 u = ((const uint4*)qptr)[j];
        qreg[j*8+0] = __uint_as_float(u.x << 16); qreg[j*8+1] = __uint_as_float(u.x & 0xFFFF0000u);
        qreg[j*8+2] = __uint_as_float(u.y << 16); qreg[j*8+3] = __uint_as_float(u.y & 0xFFFF0000u);
        qreg[j*8+4] = __uint_as_float(u.z << 16); qreg[j*8+5] = __uint_as_float(u.z & 0xFFFF0000u);
        qreg[j*8+6] = __uint_as_float(u.w << 16); qreg[j*8+7] = __uint_as_float(u.w & 0xFFFF0000u);
    }
    float O[32];
#pragma unroll
    for (int d = 0; d < 32; ++d) O[d] = 0.f;
    float mrun = -1e30f, lrun = 0.f;

    for (int t = 0; t < ntiles; ++t) {
        int k0 = t * 32;
        __syncthreads();
        {   // stage 32-key K/V tile: 128 slots of 8 bf16 each per tensor
            int r = tid >> 2, c8 = (tid & 3) * 8;
            size_t goff = ((size_t)(b * SEQ_ + k0 + r)) * D_ + hh * DK_ + c8;
            uint4 uk = *(const uint4*)(k + goff);
            uint4 uv = *(const uint4*)(v + goff);
            float4 k0v = make_float4(__uint_as_float(uk.x << 16), __uint_as_float(uk.x & 0xFFFF0000u),
                                     __uint_as_float(uk.y << 16), __uint_as_float(uk.y & 0xFFFF0000u));
            float4 k1v = make_float4(__uint_as_float(uk.z << 16), __uint_as_float(uk.z & 0xFFFF0000u),
                                     __uint_as_float(uk.w << 16), __uint_as_float(uk.w & 0xFFFF0000u));
            float4 v0v = make_float4(__uint_as_float(uv.x << 16), __uint_as_float(uv.x & 0xFFFF0000u),
                                     __uint_as_float(uv.y << 16), __uint_as_float(uv.y & 0xFFFF0000u));
            float4 v1v = make_float4(__uint_as_float(uv.z << 16), __uint_as_float(uv.z & 0xFFFF0000u),
                                     __uint_as_float(uv.w << 16), __uint_as_float(uv.w & 0xFFFF0000u));
            *(float4*)&kt[r][c8]     = k0v;
            *(float4*)&kt[r][c8 + 4] = k1v;
            *(float4*)&vt[r][c8]     = v0v;
            *(float4*)&vt[r][c8 + 4] = v1v;
        }
        __syncthreads();

        float sb[32];
        float tmax = -1e30f;
#pragma unroll
        for (int kk = 0; kk < 32; ++kk) {
            float acc = 0.f;
#pragma unroll
            for (int d4 = 0; d4 < 8; ++d4) {
                float4 kv = *(const float4*)&kt[kk][d4 * 4];
                acc += qreg[d4 * 4 + 0] * kv.x + qreg[d4 * 4 + 1] * kv.y
                     + qreg[d4 * 4 + 2] * kv.z + qreg[d4 * 4 + 3] * kv.w;
            }
            float dec = __expf(-tdv * (float)(k0 + kk));
            float sv = acc * sc * dec;
            sb[kk] = sv;
            tmax = fmaxf(tmax, sv);
        }
        float mnew = fmaxf(mrun, tmax);
        float alpha = __expf(mrun - mnew);
        lrun *= alpha;
#pragma unroll
        for (int d = 0; d < 32; ++d) O[d] *= alpha;
#pragma unroll
        for (int kk = 0; kk < 32; ++kk) {
            float sv = sb[kk];
            float e = __expf(sv - mnew);
            float sg = 1.f / (1.f + __expf(-sv));
            float p = e * sg;
            lrun += e;
#pragma unroll
            for (int d4 = 0; d4 < 8; ++d4) {
                float4 vv = *(const float4*)&vt[kk][d4 * 4];
                O[d4 * 4 + 0] += p * vv.x; O[d4 * 4 + 1] += p * vv.y;
                O[d4 * 4 + 2] += p * vv.z; O[d4 * 4 + 3] += p * vv.w;
            }
        }
        mrun = mnew;
    }

    // analytic tail: all keys >= kcr have score exactly 0 (decay underflow)
    if (kcr < SEQ_) {
        float mnew = fmaxf(mrun, 0.f);
        float alpha = __expf(mrun - mnew);
        lrun *= alpha;
        float ew = __expf(-mnew);
        lrun += (float)(SEQ_ - kcr) * ew;
        const float* vtp = vtail + ((size_t)(b * H_ + hh)) * DK_;
        float pw = 0.5f * ew;                // sigmoid(0) = 0.5
#pragma unroll
        for (int d = 0; d < 32; ++d) O[d] = O[d] * alpha + pw * vtp[d];
    }

    float invL = 1.f / lrun;
    unsigned short* obf = ctxbf + ((size_t)(b * SEQ_ + qrow)) * D_ + hh * DK_;
#pragma unroll
    for (int d4 = 0; d4 < 8; ++d4) {
        float o0 = O[d4 * 4 + 0] * invL, o1 = O[d4 * 4 + 1] * invL;
        float o2 = O[d4 * 4 + 2] * invL, o3 = O[d4 * 4 + 3] * invL;
        unsigned int u01 = (unsigned)f2bf(o0) | ((unsigned)f2bf(o1) << 16);
        unsigned int u23 = (unsigned)f2bf(o2) | ((unsigned)f2bf(o3) << 16);
        ((uint2*)obf)[d4] = make_uint2(u01, u23);
    }
}

// ---------------------------------------------------------------------------
// Kernel 5: out[b] = dot(h[b, SEQ-1, :], outW) * (1-0.5) + outb[0]
// ---------------------------------------------------------------------------
__global__ __launch_bounds__(128) void final_kernel(
    const float* __restrict__ h, const float* __restrict__ outW,
    const float* __restrict__ outb, float* __restrict__ out)
{
    int b = threadIdx.x >> 6, lane = threadIdx.x & 63;
    const float* hp = h + ((size_t)(b * SEQ_ + SEQ_ - 1)) * D_;
    float4 h4 = *(const float4*)(hp + lane * 4);
    float4 w4 = *(const float4*)(outW + lane * 4);
    float s = h4.x * w4.x + h4.y * w4.y + h4.z * w4.z + h4.w * w4.w;
#pragma unroll
    for (int off = 1; off < 64; off <<= 1) s += __shfl_xor(s, off);
    if (lane == 0) out[b] = s * 0.5f + outb[0];
}

// ---------------------------------------------------------------------------
extern "C" void kernel_launch(void* const* d_in, const int* in_sizes, int n_in,
                              void* d_out, int out_size, void* d_ws, size_t ws_size,
                              hipStream_t stream)
{
    (void)in_sizes; (void)n_in; (void)out_size; (void)ws_size;
    const float* x      = (const float*)d_in[0];
    const float* conv_w = (const float*)d_in[1];
    const float* conv_b = (const float*)d_in[2];
    const float* bn_g   = (const float*)d_in[3];
    const float* bn_b   = (const float*)d_in[4];
    const float* pe     = (const float*)d_in[5];
    const float* qW     = (const float*)d_in[6];
    const float* qb     = (const float*)d_in[7];
    const float* kW     = (const float*)d_in[8];
    const float* kb     = (const float*)d_in[9];
    const float* vW     = (const float*)d_in[10];
    const float* vb     = (const float*)d_in[11];
    const float* oW     = (const float*)d_in[12];
    const float* ob     = (const float*)d_in[13];
    const float* scale  = (const float*)d_in[14];
    const float* td     = (const float*)d_in[15];
    const float* ln1g   = (const float*)d_in[16];
    const float* ln1b   = (const float*)d_in[17];
    const float* f1W    = (const float*)d_in[18];
    const float* f1b    = (const float*)d_in[19];
    const float* f2W    = (const float*)d_in[20];
    const float* f2b    = (const float*)d_in[21];
    const float* ln2g   = (const float*)d_in[22];
    const float* ln2b   = (const float*)d_in[23];
    const float* outW   = (const float*)d_in[24];
    const float* outb   = (const float*)d_in[25];
    float* out = (float*)d_out;

    float* ws = (float*)d_ws;
    const size_t MT = (size_t)B_ * SEQ_ * D_;      // 1,048,576
    float* h     = ws;                             // MT fp32
    float* vtail = ws + MT;                        // 1024 fp32
    unsigned short* bfb = (unsigned short*)(ws + MT + 1024);
    unsigned short* h_bf   = bfb;                  // MT
    unsigned short* ctx_bf = bfb + MT;             // MT
    unsigned short* q_bf   = bfb + 2 * MT;         // MT
    unsigned short* k_bf   = bfb + 3 * MT;         // MT
    unsigned short* v_bf   = bfb + 4 * MT;         // MT
    unsigned short* ff1_bf = bfb + 5 * MT;         // 4*MT
    unsigned short* wq_bf  = bfb + 9 * MT;         // MT/8 each
    unsigned short* wk_bf  = wq_bf + MT / 8;
    unsigned short* wv_bf  = wk_bf + MT / 8;
    unsigned short* wo_bf  = wv_bf + MT / 8;
    unsigned short* wf1_bf = wo_bf + MT / 8;       // MT/2 each
    unsigned short* wf2_bf = wf1_bf + MT / 2;

    const int Mrows = B_ * SEQ_;                   // 4096

    cvt_kernel<<<768, 256, 0, stream>>>(qW, kW, vW, oW, f1W, f2W,
                                        wq_bf, wk_bf, wv_bf, wo_bf, wf1_bf, wf2_bf);

    conv_pe_kernel<<<(B_ * SEQ_ * D_) / 256, 256, 0, stream>>>(
        x, conv_w, conv_b, bn_g, bn_b, pe, h, h_bf);

    for (int l = 0; l < L_; ++l) {
        const unsigned short* wq_l  = wq_bf  + (size_t)l * D_ * D_;
        const unsigned short* wk_l  = wk_bf  + (size_t)l * D_ * D_;
        const unsigned short* wv_l  = wv_bf  + (size_t)l * D_ * D_;
        const unsigned short* wo_l  = wo_bf  + (size_t)l * D_ * D_;
        const unsigned short* wf1_l = wf1_bf + (size_t)l * DFF_ * D_;
        const unsigned short* wf2_l = wf2_bf + (size_t)l * DFF_ * D_;

        gemm_qkv<<<dim3(D_ / 64, Mrows / 64, 3), 256, 0, stream>>>(
            h_bf, wq_l, wk_l, wv_l, qb + l * D_, kb + l * D_, vb + l * D_,
            q_bf, k_bf, v_bf, Mrows, D_, D_);

        hipMemsetAsync(vtail, 0, (size_t)B_ * H_ * DK_ * sizeof(float), stream);
        vtail_kernel<<<dim3(H_, B_, 32), 256, 0, stream>>>(v_bf, td + l * H_, vtail);
        attn_kernel<<<dim3(SEQ_ / 128, H_, B_), 128, 0, stream>>>(
            q_bf, k_bf, v_bf, vtail, ctx_bf, scale + l, td + l * H_);

        // o-proj + residual + LN1 (fused)
        gemm_row256<<<dim3(1, Mrows / 64), 256, 0, stream>>>(
            ctx_bf, wo_l, ob + l * D_, h, ln1g + l * D_, ln1b + l * D_,
            h, h_bf, nullptr, D_, D_, 1);

        // FFN1: relu, bf16 out
        gemm_row256<<<dim3(DFF_ / 256, Mrows / 64), 256, 0, stream>>>(
            h_bf, wf1_l, f1b + l * DFF_, nullptr, nullptr, nullptr,
            nullptr, nullptr, ff1_bf, DFF_, D_, 0);

        // FFN2 + residual + LN2 (fused)
        gemm_row256<<<dim3(1, Mrows / 64), 256, 0, stream>>>(
            ff1_bf, wf2_l, f2b + l * D_, h, ln2g + l * D_, ln2b + l * D_,
            h, h_bf, nullptr, D_, DFF_, 1);
    }

    final_kernel<<<1, 128, 0, stream>>>(h, outW, outb, out);
}

// Round 6
// 249.787 us; speedup vs baseline: 1.2447x; 1.2447x over previous
//
#include <hip/hip_runtime.h>
#include <math.h>

#define B_    2
#define SEQ_  2048
#define D_    256
#define H_    8
#define DK_   32
#define L_    2
#define DFF_  1024

// decay cutoff: exp(-44) ~ 8e-20, below fp32 noise for any plausible score scale
#define TD_CUT 44.0f

typedef short  bf16x8 __attribute__((ext_vector_type(8)));
typedef float  f32x4  __attribute__((ext_vector_type(4)));

__device__ __forceinline__ int compute_kcut(float tdv) {
    int kcut = SEQ_;
    if (tdv > 1e-9f) {
        float kc = TD_CUT / tdv;
        kcut = (kc >= (float)SEQ_) ? SEQ_ : ((int)kc + 1);
    }
    int kcr = (kcut + 31) & ~31;          // round up to tile size
    if (kcr > SEQ_) kcr = SEQ_;
    return kcr;
}

__device__ __forceinline__ unsigned short f2bf(float f) {
    unsigned int u = __float_as_uint(f);
    unsigned int r = u + 0x7FFFu + ((u >> 16) & 1u);   // round-to-nearest-even
    return (unsigned short)(r >> 16);
}
__device__ __forceinline__ float bf2f(unsigned short u) {
    return __uint_as_float(((unsigned int)u) << 16);
}

// async 16B global -> LDS DMA (dest = wave-uniform base + lane*16)
__device__ __forceinline__ void gload_lds16(const unsigned short* g, unsigned short* l) {
    __builtin_amdgcn_global_load_lds(
        (const __attribute__((address_space(1))) unsigned int*)(const unsigned int*)g,
        (__attribute__((address_space(3))) unsigned int*)(unsigned int*)l,
        16, 0, 0);
}

// ---------------------------------------------------------------------------
// Kernel 0: fp32 -> bf16 weight pre-convert (all 6 weight tensors, both layers)
// ---------------------------------------------------------------------------
__global__ __launch_bounds__(256) void cvt_kernel(
    const float* __restrict__ p0, const float* __restrict__ p1,
    const float* __restrict__ p2, const float* __restrict__ p3,
    const float* __restrict__ p4, const float* __restrict__ p5,
    unsigned short* __restrict__ q0, unsigned short* __restrict__ q1,
    unsigned short* __restrict__ q2, unsigned short* __restrict__ q3,
    unsigned short* __restrict__ q4, unsigned short* __restrict__ q5)
{
    int t = blockIdx.x * 256 + threadIdx.x;        // chunk of 8 elems
    const float* src; unsigned short* dst; int base;
    if (t < 65536) {
        int a = t >> 14;                           // 0..3
        src = a == 0 ? p0 : a == 1 ? p1 : a == 2 ? p2 : p3;
        dst = a == 0 ? q0 : a == 1 ? q1 : a == 2 ? q2 : q3;
        base = (t & 16383) * 8;
    } else {
        int u = t - 65536;
        int a = u >> 16;                           // 0..1
        src = a ? p5 : p4;
        dst = a ? q5 : q4;
        base = (u & 65535) * 8;
    }
    float4 v0 = *(const float4*)(src + base);
    float4 v1 = *(const float4*)(src + base + 4);
    bf16x8 o;
    o[0] = (short)f2bf(v0.x); o[1] = (short)f2bf(v0.y);
    o[2] = (short)f2bf(v0.z); o[3] = (short)f2bf(v0.w);
    o[4] = (short)f2bf(v1.x); o[5] = (short)f2bf(v1.y);
    o[6] = (short)f2bf(v1.z); o[7] = (short)f2bf(v1.w);
    *(bf16x8*)(dst + base) = o;
}

// ---------------------------------------------------------------------------
// Kernel 1: conv1d(K=3, SAME) + bias + affine + relu + pe; fp32 + bf16 out.
// ---------------------------------------------------------------------------
__global__ __launch_bounds__(256) void conv_pe_kernel(
    const float* __restrict__ x, const float* __restrict__ w,
    const float* __restrict__ cb, const float* __restrict__ bg,
    const float* __restrict__ bb, const float* __restrict__ pe,
    float* __restrict__ h, unsigned short* __restrict__ hbf)
{
    int idx = blockIdx.x * 256 + threadIdx.x;      // b*SEQ*D + s*D + d
    int d = idx & 255;
    int s = (idx >> 8) & 2047;
    int b = idx >> 19;

    const float* xp = x + b * SEQ_;
    float xm1 = (s > 0)        ? xp[s - 1] : 0.f;
    float x0  = xp[s];
    float xp1 = (s < SEQ_ - 1) ? xp[s + 1] : 0.f;

    float acc = xm1 * w[d * 3 + 0] + x0 * w[d * 3 + 1] + xp1 * w[d * 3 + 2];
    acc += cb[d];
    acc = acc * rsqrtf(1.f + 1e-5f) * bg[d] + bb[d];
    acc = fmaxf(acc, 0.f);
    float v = acc + pe[s * D_ + d];
    h[idx] = v;
    hbf[idx] = f2bf(v);
}

// ---------------------------------------------------------------------------
// Kernel 2: q/k/v GEMM, bf16 in / bf16 out.  C[m,n] = A[m,:]·W[n,:] + bias[n].
// 64x64 tile, BK=32, 4 waves 2x2 of 32x32. blockIdx.z selects (W,bias,C).
// ---------------------------------------------------------------------------
__global__ __launch_bounds__(256) void gemm_qkv(
    const unsigned short* __restrict__ A,
    const unsigned short* __restrict__ W0, const unsigned short* __restrict__ W1,
    const unsigned short* __restrict__ W2,
    const float* __restrict__ b0, const float* __restrict__ b1,
    const float* __restrict__ b2,
    unsigned short* __restrict__ O0, unsigned short* __restrict__ O1,
    unsigned short* __restrict__ O2,
    int M, int N, int K)
{
    int z = blockIdx.z;
    const unsigned short* W = (z == 0) ? W0 : (z == 1) ? W1 : W2;
    const float* bias = (z == 0) ? b0 : (z == 1) ? b1 : b2;
    unsigned short* C = (z == 0) ? O0 : (z == 1) ? O1 : O2;

    __shared__ unsigned short As[64 * 32];
    __shared__ unsigned short Bs[64 * 32];

    int tid  = threadIdx.x;
    int wave = tid >> 6, lane = tid & 63;
    int wm = (wave & 1) * 32, wn = (wave >> 1) * 32;
    int bm = blockIdx.y * 64, bn = blockIdx.x * 64;

    int sr  = tid >> 2;
    int scb = (tid & 3) ^ (sr & 3);
    const unsigned short* aG = A + (size_t)(bm + sr) * K + scb * 8;
    const unsigned short* wG = W + (size_t)(bn + sr) * K + scb * 8;
    unsigned short* aL = &As[tid * 8];
    unsigned short* bL = &Bs[tid * 8];

    int fr = lane & 15;
    int kb = lane >> 4;
    int cb = (kb ^ (fr & 3)) * 8;
    int oA0 = (wm + fr) * 32 + cb;
    int oA1 = (wm + 16 + fr) * 32 + cb;
    int oB0 = (wn + fr) * 32 + cb;
    int oB1 = (wn + 16 + fr) * 32 + cb;

    f32x4 acc[2][2];
#pragma unroll
    for (int i = 0; i < 2; ++i)
#pragma unroll
        for (int j = 0; j < 2; ++j) acc[i][j] = (f32x4){0.f, 0.f, 0.f, 0.f};

    for (int k0 = 0; k0 < K; k0 += 32) {
        __syncthreads();
        gload_lds16(aG + k0, aL);
        gload_lds16(wG + k0, bL);
        __syncthreads();

        bf16x8 a0f = *(const bf16x8*)&As[oA0];
        bf16x8 a1f = *(const bf16x8*)&As[oA1];
        bf16x8 b0f = *(const bf16x8*)&Bs[oB0];
        bf16x8 b1f = *(const bf16x8*)&Bs[oB1];

        acc[0][0] = __builtin_amdgcn_mfma_f32_16x16x32_bf16(a0f, b0f, acc[0][0], 0, 0, 0);
        acc[0][1] = __builtin_amdgcn_mfma_f32_16x16x32_bf16(a0f, b1f, acc[0][1], 0, 0, 0);
        acc[1][0] = __builtin_amdgcn_mfma_f32_16x16x32_bf16(a1f, b0f, acc[1][0], 0, 0, 0);
        acc[1][1] = __builtin_amdgcn_mfma_f32_16x16x32_bf16(a1f, b1f, acc[1][1], 0, 0, 0);
    }

    int crow = (lane >> 4) * 4;
    int ccol = lane & 15;
#pragma unroll
    for (int j = 0; j < 2; ++j) {
        float bj = bias[bn + wn + j * 16 + ccol];
#pragma unroll
        for (int i = 0; i < 2; ++i) {
#pragma unroll
            for (int r = 0; r < 4; ++r) {
                float v = acc[i][j][r] + bj;
                C[(size_t)(bm + wm + i * 16 + crow + r) * N + bn + wn + j * 16 + ccol] = f2bf(v);
            }
        }
    }
}

// ---------------------------------------------------------------------------
// Kernel 2b: FFN1 GEMM, block = 64 rows x 256 cols, 4 waves each 64x64
// (16 MFMA/wave/K-step). C = relu(A@W^T + bias) -> bf16.
// ---------------------------------------------------------------------------
__global__ __launch_bounds__(256) void gemm_relu256(
    const unsigned short* __restrict__ A, const unsigned short* __restrict__ W,
    const float* __restrict__ bias, unsigned short* __restrict__ cbf,
    int N, int K)
{
    __shared__ unsigned short As[64 * 32];      // 256 slots of 16B
    __shared__ unsigned short Bs[256 * 32];     // 1024 slots of 16B

    int tid = threadIdx.x;
    int wave = tid >> 6, lane = tid & 63;
    int bm = blockIdx.y * 64, bn = blockIdx.x * 256;

    const unsigned short* gp[5];
    unsigned short* lp[5];
    {
        int s = tid;
        int row = s >> 2, cbk = (s & 3) ^ (row & 3);
        gp[0] = A + (size_t)(bm + row) * K + cbk * 8;
        lp[0] = &As[s * 8];
#pragma unroll
        for (int i = 1; i < 5; ++i) {
            int sB = (i - 1) * 256 + tid;
            int r = sB >> 2, ck = (sB & 3) ^ (r & 3);
            gp[i] = W + (size_t)(bn + r) * K + ck * 8;
            lp[i] = &Bs[sB * 8];
        }
    }

    int fr = lane & 15, kb = lane >> 4;
    int oA[4], oB[4];
#pragma unroll
    for (int t = 0; t < 4; ++t) {
        int m = t * 16 + fr;
        oA[t] = m * 32 + ((kb ^ (m & 3)) * 8);
        int n = wave * 64 + t * 16 + fr;
        oB[t] = n * 32 + ((kb ^ (n & 3)) * 8);
    }

    f32x4 acc[4][4];
#pragma unroll
    for (int i = 0; i < 4; ++i)
#pragma unroll
        for (int j = 0; j < 4; ++j) acc[i][j] = (f32x4){0.f, 0.f, 0.f, 0.f};

    for (int k0 = 0; k0 < K; k0 += 32) {
        __syncthreads();
#pragma unroll
        for (int i = 0; i < 5; ++i) gload_lds16(gp[i] + k0, lp[i]);
        __syncthreads();

        bf16x8 af[4], bf[4];
#pragma unroll
        for (int t = 0; t < 4; ++t) af[t] = *(const bf16x8*)&As[oA[t]];
#pragma unroll
        for (int t = 0; t < 4; ++t) bf[t] = *(const bf16x8*)&Bs[oB[t]];
#pragma unroll
        for (int i = 0; i < 4; ++i)
#pragma unroll
            for (int j = 0; j < 4; ++j)
                acc[i][j] = __builtin_amdgcn_mfma_f32_16x16x32_bf16(af[i], bf[j], acc[i][j], 0, 0, 0);
    }

    int q = lane >> 4, cl = lane & 15;
#pragma unroll
    for (int ct = 0; ct < 4; ++ct) {
        int col = wave * 64 + ct * 16 + cl;
        float bj = bias[bn + col];
#pragma unroll
        for (int rt = 0; rt < 4; ++rt)
#pragma unroll
            for (int r = 0; r < 4; ++r) {
                float v = fmaxf(acc[rt][ct][r] + bj, 0.f);
                cbf[(size_t)(bm + rt * 16 + q * 4 + r) * N + bn + col] = f2bf(v);
            }
    }
}

// ---------------------------------------------------------------------------
// Kernel 2c: fused GEMM + residual + LayerNorm.
// Block = 16 rows x 256 cols (full model row), grid = M/16 = 256 blocks.
// 4 waves: wave w owns cols [w*64, w*64+64) as 4 16x16 tiles (1 A-frag shared).
// h = LayerNorm(resid + A@W^T + bias)*g + b -> fp32 hout + bf16 hbfout.
// ---------------------------------------------------------------------------
__global__ __launch_bounds__(256) void gemm_ln16(
    const unsigned short* __restrict__ A, const unsigned short* __restrict__ W,
    const float* __restrict__ bias, const float* __restrict__ resid,
    const float* __restrict__ g, const float* __restrict__ bta,
    float* __restrict__ hout, unsigned short* __restrict__ hbfout, int K)
{
    __shared__ unsigned short As[16 * 32];      // 64 slots of 16B
    __shared__ unsigned short Bs[256 * 32];     // 1024 slots of 16B
    __shared__ float lsum[4][16], lsq[4][16];
    __shared__ float mean_s[16], inv_s[16];

    int tid = threadIdx.x;
    int wave = tid >> 6, lane = tid & 63;
    int bm = blockIdx.x * 16;

    const unsigned short* gpB[4];
    unsigned short* lpB[4];
#pragma unroll
    for (int i = 0; i < 4; ++i) {
        int sB = i * 256 + tid;
        int r = sB >> 2, ck = (sB & 3) ^ (r & 3);
        gpB[i] = W + (size_t)r * K + ck * 8;
        lpB[i] = &Bs[sB * 8];
    }
    const unsigned short* gpA = nullptr;
    unsigned short* lpA = nullptr;
    if (tid < 64) {
        int row = tid >> 2, ck = (tid & 3) ^ (row & 3);
        gpA = A + (size_t)(bm + row) * K + ck * 8;
        lpA = &As[tid * 8];
    }

    int fr = lane & 15, kb = lane >> 4;
    int oA = fr * 32 + ((kb ^ (fr & 3)) * 8);
    int oB[4];
#pragma unroll
    for (int t = 0; t < 4; ++t) {
        int n = wave * 64 + t * 16 + fr;
        oB[t] = n * 32 + ((kb ^ (n & 3)) * 8);
    }

    f32x4 acc[4];
#pragma unroll
    for (int j = 0; j < 4; ++j) acc[j] = (f32x4){0.f, 0.f, 0.f, 0.f};

    for (int k0 = 0; k0 < K; k0 += 32) {
        __syncthreads();
#pragma unroll
        for (int i = 0; i < 4; ++i) gload_lds16(gpB[i] + k0, lpB[i]);
        if (tid < 64) gload_lds16(gpA + k0, lpA);
        __syncthreads();

        bf16x8 af = *(const bf16x8*)&As[oA];
        bf16x8 bf[4];
#pragma unroll
        for (int t = 0; t < 4; ++t) bf[t] = *(const bf16x8*)&Bs[oB[t]];
#pragma unroll
        for (int j = 0; j < 4; ++j)
            acc[j] = __builtin_amdgcn_mfma_f32_16x16x32_bf16(af, bf[j], acc[j], 0, 0, 0);
    }

    int q = lane >> 4, cl = lane & 15;

    // z = acc + bias + resid; per-row partial sums over this wave's 64 cols
    float zsum[4] = {0.f, 0.f, 0.f, 0.f}, zsq[4] = {0.f, 0.f, 0.f, 0.f};
#pragma unroll
    for (int ct = 0; ct < 4; ++ct) {
        int col = wave * 64 + ct * 16 + cl;
        float bj = bias[col];
#pragma unroll
        for (int r = 0; r < 4; ++r) {
            int row = bm + q * 4 + r;
            float z = acc[ct][r] + bj + resid[(size_t)row * 256 + col];
            acc[ct][r] = z;
            zsum[r] += z;
            zsq[r]  += z * z;
        }
    }
#pragma unroll
    for (int r = 0; r < 4; ++r) {
#pragma unroll
        for (int off = 1; off < 16; off <<= 1) {
            zsum[r] += __shfl_xor(zsum[r], off);
            zsq[r]  += __shfl_xor(zsq[r], off);
        }
    }
    if (cl == 0) {
#pragma unroll
        for (int r = 0; r < 4; ++r) {
            lsum[wave][q * 4 + r] = zsum[r];
            lsq[wave][q * 4 + r]  = zsq[r];
        }
    }
    __syncthreads();
    if (tid < 16) {
        float s  = lsum[0][tid] + lsum[1][tid] + lsum[2][tid] + lsum[3][tid];
        float sq = lsq[0][tid] + lsq[1][tid] + lsq[2][tid] + lsq[3][tid];
        float mean = s * (1.f / 256.f);
        float var  = sq * (1.f / 256.f) - mean * mean;
        mean_s[tid] = mean;
        inv_s[tid]  = rsqrtf(var + 1e-5f);
    }
    __syncthreads();

#pragma unroll
    for (int ct = 0; ct < 4; ++ct) {
        int col = wave * 64 + ct * 16 + cl;
        float gc = g[col], bc = bta[col];
#pragma unroll
        for (int r = 0; r < 4; ++r) {
            int lrow = q * 4 + r;
            float o = (acc[ct][r] - mean_s[lrow]) * inv_s[lrow] * gc + bc;
            size_t off = (size_t)(bm + lrow) * 256 + col;
            hout[off] = o;
            hbfout[off] = f2bf(o);
        }
    }
}

// ---------------------------------------------------------------------------
// Kernel 3a: V-suffix partial sums (bf16 V), atomically accumulated.
// ---------------------------------------------------------------------------
__global__ __launch_bounds__(256) void vtail_kernel(
    const unsigned short* __restrict__ v, const float* __restrict__ td_l,
    float* __restrict__ vtail)
{
    int hh = blockIdx.x, b = blockIdx.y, z = blockIdx.z;
    int kcr = compute_kcut(td_l[hh]);
    int rbeg = z * 64, rend = rbeg + 64;
    if (rend <= kcr) return;
    int lo = rbeg > kcr ? rbeg : kcr;

    int d = threadIdx.x & 31, c = threadIdx.x >> 5;    // 8 row-chunks
    float s = 0.f;
    for (int kk = lo + c; kk < rend; kk += 8)
        s += bf2f(v[((size_t)(b * SEQ_ + kk)) * D_ + hh * DK_ + d]);

    __shared__ float sm[8][32];
    sm[c][d] = s;
    __syncthreads();
    if (threadIdx.x < 32) {
        float t = 0.f;
#pragma unroll
        for (int i = 0; i < 8; ++i) t += sm[i][threadIdx.x];
        atomicAdd(&vtail[((size_t)(b * H_ + hh)) * DK_ + threadIdx.x], t);
    }
}

// ---------------------------------------------------------------------------
// Kernel 3b: decay-truncated flash attention, 4-way key-split + LDS merge.
// grid (SEQ/32, H, B), 128 threads: thread = (row = tid>>2, split = tid&3).
// Split s processes keys [s*8, s*8+8) of each 32-key tile; partials merged
// exactly (online-softmax merge) + analytic tail for keys >= kcut.
// ---------------------------------------------------------------------------
__global__ __launch_bounds__(128) void attn_kernel(
    const unsigned short* __restrict__ q, const unsigned short* __restrict__ k,
    const unsigned short* __restrict__ v, const float* __restrict__ vtail,
    unsigned short* __restrict__ ctxbf,
    const float* __restrict__ scale_p, const float* __restrict__ td_l)
{
    int b = blockIdx.z, hh = blockIdx.y;
    int tid = threadIdx.x;
    int row = tid >> 2;                 // 0..31
    int sp  = tid & 3;                  // key-split 0..3
    int qrow = blockIdx.x * 32 + row;

    float sc  = 0.17677669529663687f * scale_p[0];   // 1/sqrt(32) * scale[l]
    float tdv = td_l[hh];
    int kcr = compute_kcut(tdv);
    int ntiles = kcr >> 5;

    __shared__ float kt[32][36];
    __shared__ float vt[32][36];
    __shared__ float Os[4][32][36];     // [split][row][dim(padded)]
    __shared__ float ms[4][32], ls[4][32];

    const unsigned short* qptr = q + ((size_t)(b * SEQ_ + qrow)) * D_ + hh * DK_;
    float qreg[32];
#pragma unroll
    for (int j = 0; j < 4; ++j) {
        uint4 u = ((const uint4*)qptr)[j];
        qreg[j*8+0] = __uint_as_float(u.x << 16); qreg[j*8+1] = __uint_as_float(u.x & 0xFFFF0000u);
        qreg[j*8+2] = __uint_as_float(u.y << 16); qreg[j*8+3] = __uint_as_float(u.y & 0xFFFF0000u);
        qreg[j*8+4] = __uint_as_float(u.z << 16); qreg[j*8+5] = __uint_as_float(u.z & 0xFFFF0000u);
        qreg[j*8+6] = __uint_as_float(u.w << 16); qreg[j*8+7] = __uint_as_float(u.w & 0xFFFF0000u);
    }
    float O[32];
#pragma unroll
    for (int d = 0; d < 32; ++d) O[d] = 0.f;
    float mrun = -1e30f, lrun = 0.f;

    for (int t = 0; t < ntiles; ++t) {
        int k0 = t * 32;
        __syncthreads();
        {   // stage 32-key K/V tile (bf16 -> fp32 LDS): 128 slots of 8 each
            int r = tid >> 2, c8 = (tid & 3) * 8;
            size_t goff = ((size_t)(b * SEQ_ + k0 + r)) * D_ + hh * DK_ + c8;
            uint4 uk = *(const uint4*)(k + goff);
            uint4 uv = *(const uint4*)(v + goff);
            *(float4*)&kt[r][c8]     = make_float4(__uint_as_float(uk.x << 16), __uint_as_float(uk.x & 0xFFFF0000u),
                                                   __uint_as_float(uk.y << 16), __uint_as_float(uk.y & 0xFFFF0000u));
            *(float4*)&kt[r][c8 + 4] = make_float4(__uint_as_float(uk.z << 16), __uint_as_float(uk.z & 0xFFFF0000u),
                                                   __uint_as_float(uk.w << 16), __uint_as_float(uk.w & 0xFFFF0000u));
            *(float4*)&vt[r][c8]     = make_float4(__uint_as_float(uv.x << 16), __uint_as_float(uv.x & 0xFFFF0000u),
                                                   __uint_as_float(uv.y << 16), __uint_as_float(uv.y & 0xFFFF0000u));
            *(float4*)&vt[r][c8 + 4] = make_float4(__uint_as_float(uv.z << 16), __uint_as_float(uv.z & 0xFFFF0000u),
                                                   __uint_as_float(uv.w << 16), __uint_as_float(uv.w & 0xFFFF0000u));
        }
        __syncthreads();

        // this split's 8 keys of the tile
        float sb[8];
        float tmax = -1e30f;
#pragma unroll
        for (int kk = 0; kk < 8; ++kk) {
            int kl = sp * 8 + kk;
            float acc = 0.f;
#pragma unroll
            for (int d4 = 0; d4 < 8; ++d4) {
                float4 kv = *(const float4*)&kt[kl][d4 * 4];
                acc += qreg[d4 * 4 + 0] * kv.x + qreg[d4 * 4 + 1] * kv.y
                     + qreg[d4 * 4 + 2] * kv.z + qreg[d4 * 4 + 3] * kv.w;
            }
            float dec = __expf(-tdv * (float)(k0 + kl));
            float sv = acc * sc * dec;
            sb[kk] = sv;
            tmax = fmaxf(tmax, sv);
        }
        float mnew = fmaxf(mrun, tmax);
        float alpha = __expf(mrun - mnew);
        lrun *= alpha;
#pragma unroll
        for (int d = 0; d < 32; ++d) O[d] *= alpha;
#pragma unroll
        for (int kk = 0; kk < 8; ++kk) {
            int kl = sp * 8 + kk;
            float sv = sb[kk];
            float e = __expf(sv - mnew);
            float sg = 1.f / (1.f + __expf(-sv));
            float p = e * sg;
            lrun += e;
#pragma unroll
            for (int d4 = 0; d4 < 8; ++d4) {
                float4 vv = *(const float4*)&vt[kl][d4 * 4];
                O[d4 * 4 + 0] += p * vv.x; O[d4 * 4 + 1] += p * vv.y;
                O[d4 * 4 + 2] += p * vv.z; O[d4 * 4 + 3] += p * vv.w;
            }
        }
        mrun = mnew;
    }

    // publish this split's partial
#pragma unroll
    for (int d4 = 0; d4 < 8; ++d4)
        *(float4*)&Os[sp][row][d4 * 4] =
            make_float4(O[d4*4+0], O[d4*4+1], O[d4*4+2], O[d4*4+3]);
    ms[sp][row] = mrun;
    ls[sp][row] = lrun;
    __syncthreads();

    // merge: thread (row, g=sp) handles dims [g*8, g*8+8)
    {
        int g = sp;
        float m0 = fmaxf(fmaxf(ms[0][row], ms[1][row]), fmaxf(ms[2][row], ms[3][row]));
        float mt = (kcr < SEQ_) ? fmaxf(m0, 0.f) : m0;
        float w0 = __expf(ms[0][row] - mt), w1 = __expf(ms[1][row] - mt);
        float w2 = __expf(ms[2][row] - mt), w3 = __expf(ms[3][row] - mt);
        float Lt = ls[0][row]*w0 + ls[1][row]*w1 + ls[2][row]*w2 + ls[3][row]*w3;
        float ew = 0.f;
        const float* vtp = vtail + ((size_t)(b * H_ + hh)) * DK_;
        if (kcr < SEQ_) {
            ew = __expf(-mt);                // exp(0 - mt)
            Lt += (float)(SEQ_ - kcr) * ew;
        }
        float invL = 1.f / Lt;
        unsigned int packed[4];
#pragma unroll
        for (int dd = 0; dd < 8; dd += 2) {
            int d0 = g * 8 + dd, d1 = d0 + 1;
            float n0 = Os[0][row][d0]*w0 + Os[1][row][d0]*w1 + Os[2][row][d0]*w2 + Os[3][row][d0]*w3;
            float n1 = Os[0][row][d1]*w0 + Os[1][row][d1]*w1 + Os[2][row][d1]*w2 + Os[3][row][d1]*w3;
            if (kcr < SEQ_) { n0 += 0.5f * ew * vtp[d0]; n1 += 0.5f * ew * vtp[d1]; }
            packed[dd >> 1] = (unsigned)f2bf(n0 * invL) | ((unsigned)f2bf(n1 * invL) << 16);
        }
        unsigned short* obf = ctxbf + ((size_t)(b * SEQ_ + qrow)) * D_ + hh * DK_ + g * 8;
        *(uint4*)obf = make_uint4(packed[0], packed[1], packed[2], packed[3]);
    }
}

// ---------------------------------------------------------------------------
// Kernel 5: out[b] = dot(h[b, SEQ-1, :], outW) * (1-0.5) + outb[0]
// ---------------------------------------------------------------------------
__global__ __launch_bounds__(128) void final_kernel(
    const float* __restrict__ h, const float* __restrict__ outW,
    const float* __restrict__ outb, float* __restrict__ out)
{
    int b = threadIdx.x >> 6, lane = threadIdx.x & 63;
    const float* hp = h + ((size_t)(b * SEQ_ + SEQ_ - 1)) * D_;
    float4 h4 = *(const float4*)(hp + lane * 4);
    float4 w4 = *(const float4*)(outW + lane * 4);
    float s = h4.x * w4.x + h4.y * w4.y + h4.z * w4.z + h4.w * w4.w;
#pragma unroll
    for (int off = 1; off < 64; off <<= 1) s += __shfl_xor(s, off);
    if (lane == 0) out[b] = s * 0.5f + outb[0];
}

// ---------------------------------------------------------------------------
extern "C" void kernel_launch(void* const* d_in, const int* in_sizes, int n_in,
                              void* d_out, int out_size, void* d_ws, size_t ws_size,
                              hipStream_t stream)
{
    (void)in_sizes; (void)n_in; (void)out_size; (void)ws_size;
    const float* x      = (const float*)d_in[0];
    const float* conv_w = (const float*)d_in[1];
    const float* conv_b = (const float*)d_in[2];
    const float* bn_g   = (const float*)d_in[3];
    const float* bn_b   = (const float*)d_in[4];
    const float* pe     = (const float*)d_in[5];
    const float* qW     = (const float*)d_in[6];
    const float* qb     = (const float*)d_in[7];
    const float* kW     = (const float*)d_in[8];
    const float* kb     = (const float*)d_in[9];
    const float* vW     = (const float*)d_in[10];
    const float* vb     = (const float*)d_in[11];
    const float* oW     = (const float*)d_in[12];
    const float* ob     = (const float*)d_in[13];
    const float* scale  = (const float*)d_in[14];
    const float* td     = (const float*)d_in[15];
    const float* ln1g   = (const float*)d_in[16];
    const float* ln1b   = (const float*)d_in[17];
    const float* f1W    = (const float*)d_in[18];
    const float* f1b    = (const float*)d_in[19];
    const float* f2W    = (const float*)d_in[20];
    const float* f2b    = (const float*)d_in[21];
    const float* ln2g   = (const float*)d_in[22];
    const float* ln2b   = (const float*)d_in[23];
    const float* outW   = (const float*)d_in[24];
    const float* outb   = (const float*)d_in[25];
    float* out = (float*)d_out;

    float* ws = (float*)d_ws;
    const size_t MT = (size_t)B_ * SEQ_ * D_;      // 1,048,576
    float* h     = ws;                             // MT fp32
    float* vtail = ws + MT;                        // 1024 fp32
    unsigned short* bfb = (unsigned short*)(ws + MT + 1024);
    unsigned short* h_bf   = bfb;                  // MT
    unsigned short* ctx_bf = bfb + MT;             // MT
    unsigned short* q_bf   = bfb + 2 * MT;         // MT
    unsigned short* k_bf   = bfb + 3 * MT;         // MT
    unsigned short* v_bf   = bfb + 4 * MT;         // MT
    unsigned short* ff1_bf = bfb + 5 * MT;         // 4*MT
    unsigned short* wq_bf  = bfb + 9 * MT;         // MT/8 each
    unsigned short* wk_bf  = wq_bf + MT / 8;
    unsigned short* wv_bf  = wk_bf + MT / 8;
    unsigned short* wo_bf  = wv_bf + MT / 8;
    unsigned short* wf1_bf = wo_bf + MT / 8;       // MT/2 each
    unsigned short* wf2_bf = wf1_bf + MT / 2;

    const int Mrows = B_ * SEQ_;                   // 4096

    cvt_kernel<<<768, 256, 0, stream>>>(qW, kW, vW, oW, f1W, f2W,
                                        wq_bf, wk_bf, wv_bf, wo_bf, wf1_bf, wf2_bf);

    conv_pe_kernel<<<(B_ * SEQ_ * D_) / 256, 256, 0, stream>>>(
        x, conv_w, conv_b, bn_g, bn_b, pe, h, h_bf);

    for (int l = 0; l < L_; ++l) {
        const unsigned short* wq_l  = wq_bf  + (size_t)l * D_ * D_;
        const unsigned short* wk_l  = wk_bf  + (size_t)l * D_ * D_;
        const unsigned short* wv_l  = wv_bf  + (size_t)l * D_ * D_;
        const unsigned short* wo_l  = wo_bf  + (size_t)l * D_ * D_;
        const unsigned short* wf1_l = wf1_bf + (size_t)l * DFF_ * D_;
        const unsigned short* wf2_l = wf2_bf + (size_t)l * DFF_ * D_;

        gemm_qkv<<<dim3(D_ / 64, Mrows / 64, 3), 256, 0, stream>>>(
            h_bf, wq_l, wk_l, wv_l, qb + l * D_, kb + l * D_, vb + l * D_,
            q_bf, k_bf, v_bf, Mrows, D_, D_);

        hipMemsetAsync(vtail, 0, (size_t)B_ * H_ * DK_ * sizeof(float), stream);
        vtail_kernel<<<dim3(H_, B_, 32), 256, 0, stream>>>(v_bf, td + l * H_, vtail);
        attn_kernel<<<dim3(SEQ_ / 32, H_, B_), 128, 0, stream>>>(
            q_bf, k_bf, v_bf, vtail, ctx_bf, scale + l, td + l * H_);

        // o-proj + residual + LN1 (fused), 256 blocks
        gemm_ln16<<<Mrows / 16, 256, 0, stream>>>(
            ctx_bf, wo_l, ob + l * D_, h, ln1g + l * D_, ln1b + l * D_,
            h, h_bf, D_);

        // FFN1: relu, bf16 out
        gemm_relu256<<<dim3(DFF_ / 256, Mrows / 64), 256, 0, stream>>>(
            h_bf, wf1_l, f1b + l * DFF_, ff1_bf, DFF_, D_);

        // FFN2 + residual + LN2 (fused), 256 blocks
        gemm_ln16<<<Mrows / 16, 256, 0, stream>>>(
            ff1_bf, wf2_l, f2b + l * D_, h, ln2g + l * D_, ln2b + l * D_,
            h, h_bf, DFF_);
    }

    final_kernel<<<1, 128, 0, stream>>>(h, outW, outb, out);
}

// Round 7
// 246.716 us; speedup vs baseline: 1.2601x; 1.0124x over previous
//
#include <hip/hip_runtime.h>
#include <math.h>

#define B_    2
#define SEQ_  2048
#define D_    256
#define H_    8
#define DK_   32
#define L_    2
#define DFF_  1024

#define TD_CUT 44.0f
#define PAD 264   // padded row (shorts) for manual LDS tiles: 2-way (free) bank aliasing

typedef short  bf16x8 __attribute__((ext_vector_type(8)));
typedef float  f32x4  __attribute__((ext_vector_type(4)));

__device__ __forceinline__ int compute_kcut(float tdv) {
    int kcut = SEQ_;
    if (tdv > 1e-9f) {
        float kc = TD_CUT / tdv;
        kcut = (kc >= (float)SEQ_) ? SEQ_ : ((int)kc + 1);
    }
    int kcr = (kcut + 31) & ~31;
    if (kcr > SEQ_) kcr = SEQ_;
    return kcr;
}

__device__ __forceinline__ unsigned short f2bf(float f) {
    unsigned int u = __float_as_uint(f);
    unsigned int r = u + 0x7FFFu + ((u >> 16) & 1u);   // RNE
    return (unsigned short)(r >> 16);
}
__device__ __forceinline__ float bf2f(unsigned short u) {
    return __uint_as_float(((unsigned int)u) << 16);
}

__device__ __forceinline__ void gload_lds16(const unsigned short* g, unsigned short* l) {
    __builtin_amdgcn_global_load_lds(
        (const __attribute__((address_space(1))) unsigned int*)(const unsigned int*)g,
        (__attribute__((address_space(3))) unsigned int*)(unsigned int*)l,
        16, 0, 0);
}

// ---------------------------------------------------------------------------
// Kernel 1: prep = weight fp32->bf16 convert (blocks 0..767) + conv/pe (rest)
// ---------------------------------------------------------------------------
__global__ __launch_bounds__(256) void prep_kernel(
    const float* __restrict__ x, const float* __restrict__ w,
    const float* __restrict__ cb, const float* __restrict__ bg,
    const float* __restrict__ bb, const float* __restrict__ pe,
    float* __restrict__ h, unsigned short* __restrict__ hbf,
    const float* __restrict__ p0, const float* __restrict__ p1,
    const float* __restrict__ p2, const float* __restrict__ p3,
    const float* __restrict__ p4, const float* __restrict__ p5,
    unsigned short* __restrict__ q0, unsigned short* __restrict__ q1,
    unsigned short* __restrict__ q2, unsigned short* __restrict__ q3,
    unsigned short* __restrict__ q4, unsigned short* __restrict__ q5)
{
    int bid = blockIdx.x;
    if (bid < 768) {                              // ---- cvt path
        int t = bid * 256 + threadIdx.x;
        const float* src; unsigned short* dst; int base;
        if (t < 65536) {
            int a = t >> 14;
            src = a == 0 ? p0 : a == 1 ? p1 : a == 2 ? p2 : p3;
            dst = a == 0 ? q0 : a == 1 ? q1 : a == 2 ? q2 : q3;
            base = (t & 16383) * 8;
        } else {
            int u = t - 65536;
            int a = u >> 16;
            src = a ? p5 : p4;
            dst = a ? q5 : q4;
            base = (u & 65535) * 8;
        }
        float4 v0 = *(const float4*)(src + base);
        float4 v1 = *(const float4*)(src + base + 4);
        bf16x8 o;
        o[0] = (short)f2bf(v0.x); o[1] = (short)f2bf(v0.y);
        o[2] = (short)f2bf(v0.z); o[3] = (short)f2bf(v0.w);
        o[4] = (short)f2bf(v1.x); o[5] = (short)f2bf(v1.y);
        o[6] = (short)f2bf(v1.z); o[7] = (short)f2bf(v1.w);
        *(bf16x8*)(dst + base) = o;
        return;
    }
    // ---- conv path
    int idx = (bid - 768) * 256 + threadIdx.x;    // b*SEQ*D + s*D + d
    int d = idx & 255;
    int s = (idx >> 8) & 2047;
    int b = idx >> 19;

    const float* xp = x + b * SEQ_;
    float xm1 = (s > 0)        ? xp[s - 1] : 0.f;
    float x0  = xp[s];
    float xp1 = (s < SEQ_ - 1) ? xp[s + 1] : 0.f;

    float acc = xm1 * w[d * 3 + 0] + x0 * w[d * 3 + 1] + xp1 * w[d * 3 + 2];
    acc += cb[d];
    acc = acc * rsqrtf(1.f + 1e-5f) * bg[d] + bb[d];
    acc = fmaxf(acc, 0.f);
    float v = acc + pe[s * D_ + d];
    h[idx] = v;
    hbf[idx] = f2bf(v);
}

// ---------------------------------------------------------------------------
// Kernel 2: q/k/v GEMM (bf16 in/out) + fused vtail partial sums for V (z==2).
// 64x64 tile, BK=32, 4 waves 2x2. vpart[rb][col] = sum_{rows>=kcut} Vbf.
// ---------------------------------------------------------------------------
__global__ __launch_bounds__(256) void gemm_qkv(
    const unsigned short* __restrict__ A,
    const unsigned short* __restrict__ W0, const unsigned short* __restrict__ W1,
    const unsigned short* __restrict__ W2,
    const float* __restrict__ b0, const float* __restrict__ b1,
    const float* __restrict__ b2,
    unsigned short* __restrict__ O0, unsigned short* __restrict__ O1,
    unsigned short* __restrict__ O2,
    const float* __restrict__ td_l, float* __restrict__ vpart,
    int M, int N, int K)
{
    int z = blockIdx.z;
    const unsigned short* W = (z == 0) ? W0 : (z == 1) ? W1 : W2;
    const float* bias = (z == 0) ? b0 : (z == 1) ? b1 : b2;
    unsigned short* C = (z == 0) ? O0 : (z == 1) ? O1 : O2;

    __shared__ unsigned short As[64 * 32];
    __shared__ unsigned short Bs[64 * 32];
    __shared__ float vsc[4][2][16];

    int tid  = threadIdx.x;
    int wave = tid >> 6, lane = tid & 63;
    int wm = (wave & 1) * 32, wn = (wave >> 1) * 32;
    int bm = blockIdx.y * 64, bn = blockIdx.x * 64;

    int sr  = tid >> 2;
    int scb = (tid & 3) ^ (sr & 3);
    const unsigned short* aG = A + (size_t)(bm + sr) * K + scb * 8;
    const unsigned short* wG = W + (size_t)(bn + sr) * K + scb * 8;
    unsigned short* aL = &As[tid * 8];
    unsigned short* bL = &Bs[tid * 8];

    int fr = lane & 15;
    int kb = lane >> 4;
    int cb = (kb ^ (fr & 3)) * 8;
    int oA0 = (wm + fr) * 32 + cb;
    int oA1 = (wm + 16 + fr) * 32 + cb;
    int oB0 = (wn + fr) * 32 + cb;
    int oB1 = (wn + 16 + fr) * 32 + cb;

    f32x4 acc[2][2];
#pragma unroll
    for (int i = 0; i < 2; ++i)
#pragma unroll
        for (int j = 0; j < 2; ++j) acc[i][j] = (f32x4){0.f, 0.f, 0.f, 0.f};

    for (int k0 = 0; k0 < K; k0 += 32) {
        __syncthreads();
        gload_lds16(aG + k0, aL);
        gload_lds16(wG + k0, bL);
        __syncthreads();

        bf16x8 a0f = *(const bf16x8*)&As[oA0];
        bf16x8 a1f = *(const bf16x8*)&As[oA1];
        bf16x8 b0f = *(const bf16x8*)&Bs[oB0];
        bf16x8 b1f = *(const bf16x8*)&Bs[oB1];

        acc[0][0] = __builtin_amdgcn_mfma_f32_16x16x32_bf16(a0f, b0f, acc[0][0], 0, 0, 0);
        acc[0][1] = __builtin_amdgcn_mfma_f32_16x16x32_bf16(a0f, b1f, acc[0][1], 0, 0, 0);
        acc[1][0] = __builtin_amdgcn_mfma_f32_16x16x32_bf16(a1f, b0f, acc[1][0], 0, 0, 0);
        acc[1][1] = __builtin_amdgcn_mfma_f32_16x16x32_bf16(a1f, b1f, acc[1][1], 0, 0, 0);
    }

    int crow = (lane >> 4) * 4;
    int ccol = lane & 15;
    float psum[2] = {0.f, 0.f};
    int kc[2];
    kc[0] = compute_kcut(td_l[(bn + wn) >> 5]);
    kc[1] = compute_kcut(td_l[(bn + wn + 16) >> 5]);

#pragma unroll
    for (int j = 0; j < 2; ++j) {
        float bj = bias[bn + wn + j * 16 + ccol];
#pragma unroll
        for (int i = 0; i < 2; ++i) {
#pragma unroll
            for (int r = 0; r < 4; ++r) {
                float v = acc[i][j][r] + bj;
                unsigned short ubf = f2bf(v);
                C[(size_t)(bm + wm + i * 16 + crow + r) * N + bn + wn + j * 16 + ccol] = ubf;
                if (z == 2) {
                    int srow = (bm + wm + i * 16 + crow + r) & 2047;
                    if (srow >= kc[j]) psum[j] += bf2f(ubf);
                }
            }
        }
    }

    if (z == 2) {
        // reduce over the 4 crow groups sharing each column
#pragma unroll
        for (int j = 0; j < 2; ++j) {
            psum[j] += __shfl_xor(psum[j], 16);
            psum[j] += __shfl_xor(psum[j], 32);
        }
        if (lane < 16) { vsc[wave][0][lane] = psum[0]; vsc[wave][1][lane] = psum[1]; }
        __syncthreads();
        if (tid < 64) {
            int wh = tid >> 5, jj = (tid >> 4) & 1, cc = tid & 15;
            float s = vsc[2 * wh][jj][cc] + vsc[2 * wh + 1][jj][cc];
            vpart[(size_t)blockIdx.y * 256 + bn + wh * 32 + jj * 16 + cc] = s;
        }
    }
}

// ---------------------------------------------------------------------------
// Kernel 3: decay-truncated flash attention, 4-way key-split + LDS merge,
// with vtail gathered from vpart partials (32 row-blocks per batch).
// grid (SEQ/32, H, B), 128 threads: thread = (row = tid>>2, split = tid&3).
// ---------------------------------------------------------------------------
__global__ __launch_bounds__(128) void attn_kernel(
    const unsigned short* __restrict__ q, const unsigned short* __restrict__ k,
    const unsigned short* __restrict__ v, const float* __restrict__ vpart,
    unsigned short* __restrict__ ctxbf,
    const float* __restrict__ scale_p, const float* __restrict__ td_l)
{
    int b = blockIdx.z, hh = blockIdx.y;
    int tid = threadIdx.x;
    int row = tid >> 2;
    int sp  = tid & 3;
    int qrow = blockIdx.x * 32 + row;

    float sc  = 0.17677669529663687f * scale_p[0];
    float tdv = td_l[hh];
    int kcr = compute_kcut(tdv);
    int ntiles = kcr >> 5;

    __shared__ float kt[32][36];
    __shared__ float vt[32][36];
    __shared__ float Os[4][32][36];
    __shared__ float ms[4][32], ls[4][32];
    __shared__ float vtmp[4][32];

    // gather vtail partials (32 row-blocks of this batch)
    {
        int d = tid & 31, gq = tid >> 5;
        float s = 0.f;
        for (int rb = gq; rb < 32; rb += 4)
            s += vpart[(size_t)(b * 32 + rb) * 256 + hh * 32 + d];
        vtmp[gq][d] = s;
    }

    const unsigned short* qptr = q + ((size_t)(b * SEQ_ + qrow)) * D_ + hh * DK_;
    float qreg[32];
#pragma unroll
    for (int j = 0; j < 4; ++j) {
        uint4 u = ((const uint4*)qptr)[j];
        qreg[j*8+0] = __uint_as_float(u.x << 16); qreg[j*8+1] = __uint_as_float(u.x & 0xFFFF0000u);
        qreg[j*8+2] = __uint_as_float(u.y << 16); qreg[j*8+3] = __uint_as_float(u.y & 0xFFFF0000u);
        qreg[j*8+4] = __uint_as_float(u.z << 16); qreg[j*8+5] = __uint_as_float(u.z & 0xFFFF0000u);
        qreg[j*8+6] = __uint_as_float(u.w << 16); qreg[j*8+7] = __uint_as_float(u.w & 0xFFFF0000u);
    }
    float O[32];
#pragma unroll
    for (int d = 0; d < 32; ++d) O[d] = 0.f;
    float mrun = -1e30f, lrun = 0.f;

    for (int t = 0; t < ntiles; ++t) {
        int k0 = t * 32;
        __syncthreads();
        {
            int r = tid >> 2, c8 = (tid & 3) * 8;
            size_t goff = ((size_t)(b * SEQ_ + k0 + r)) * D_ + hh * DK_ + c8;
            uint4 uk = *(const uint4*)(k + goff);
            uint4 uv = *(const uint4*)(v + goff);
            *(float4*)&kt[r][c8]     = make_float4(__uint_as_float(uk.x << 16), __uint_as_float(uk.x & 0xFFFF0000u),
                                                   __uint_as_float(uk.y << 16), __uint_as_float(uk.y & 0xFFFF0000u));
            *(float4*)&kt[r][c8 + 4] = make_float4(__uint_as_float(uk.z << 16), __uint_as_float(uk.z & 0xFFFF0000u),
                                                   __uint_as_float(uk.w << 16), __uint_as_float(uk.w & 0xFFFF0000u));
            *(float4*)&vt[r][c8]     = make_float4(__uint_as_float(uv.x << 16), __uint_as_float(uv.x & 0xFFFF0000u),
                                                   __uint_as_float(uv.y << 16), __uint_as_float(uv.y & 0xFFFF0000u));
            *(float4*)&vt[r][c8 + 4] = make_float4(__uint_as_float(uv.z << 16), __uint_as_float(uv.z & 0xFFFF0000u),
                                                   __uint_as_float(uv.w << 16), __uint_as_float(uv.w & 0xFFFF0000u));
        }
        __syncthreads();

        float sb[8];
        float tmax = -1e30f;
#pragma unroll
        for (int kk = 0; kk < 8; ++kk) {
            int kl = sp * 8 + kk;
            float acc = 0.f;
#pragma unroll
            for (int d4 = 0; d4 < 8; ++d4) {
                float4 kv = *(const float4*)&kt[kl][d4 * 4];
                acc += qreg[d4 * 4 + 0] * kv.x + qreg[d4 * 4 + 1] * kv.y
                     + qreg[d4 * 4 + 2] * kv.z + qreg[d4 * 4 + 3] * kv.w;
            }
            float dec = __expf(-tdv * (float)(k0 + kl));
            float sv = acc * sc * dec;
            sb[kk] = sv;
            tmax = fmaxf(tmax, sv);
        }
        float mnew = fmaxf(mrun, tmax);
        float alpha = __expf(mrun - mnew);
        lrun *= alpha;
#pragma unroll
        for (int d = 0; d < 32; ++d) O[d] *= alpha;
#pragma unroll
        for (int kk = 0; kk < 8; ++kk) {
            int kl = sp * 8 + kk;
            float sv = sb[kk];
            float e = __expf(sv - mnew);
            float sg = 1.f / (1.f + __expf(-sv));
            float p = e * sg;
            lrun += e;
#pragma unroll
            for (int d4 = 0; d4 < 8; ++d4) {
                float4 vv = *(const float4*)&vt[kl][d4 * 4];
                O[d4 * 4 + 0] += p * vv.x; O[d4 * 4 + 1] += p * vv.y;
                O[d4 * 4 + 2] += p * vv.z; O[d4 * 4 + 3] += p * vv.w;
            }
        }
        mrun = mnew;
    }

#pragma unroll
    for (int d4 = 0; d4 < 8; ++d4)
        *(float4*)&Os[sp][row][d4 * 4] =
            make_float4(O[d4*4+0], O[d4*4+1], O[d4*4+2], O[d4*4+3]);
    ms[sp][row] = mrun;
    ls[sp][row] = lrun;
    __syncthreads();

    {
        int g = sp;
        float m0 = fmaxf(fmaxf(ms[0][row], ms[1][row]), fmaxf(ms[2][row], ms[3][row]));
        float mt = (kcr < SEQ_) ? fmaxf(m0, 0.f) : m0;
        float w0 = __expf(ms[0][row] - mt), w1 = __expf(ms[1][row] - mt);
        float w2 = __expf(ms[2][row] - mt), w3 = __expf(ms[3][row] - mt);
        float Lt = ls[0][row]*w0 + ls[1][row]*w1 + ls[2][row]*w2 + ls[3][row]*w3;
        float ew = 0.f;
        if (kcr < SEQ_) {
            ew = __expf(-mt);
            Lt += (float)(SEQ_ - kcr) * ew;
        }
        float invL = 1.f / Lt;
        unsigned int packed[4];
#pragma unroll
        for (int dd = 0; dd < 8; dd += 2) {
            int d0 = g * 8 + dd, d1 = d0 + 1;
            float n0 = Os[0][row][d0]*w0 + Os[1][row][d0]*w1 + Os[2][row][d0]*w2 + Os[3][row][d0]*w3;
            float n1 = Os[0][row][d1]*w0 + Os[1][row][d1]*w1 + Os[2][row][d1]*w2 + Os[3][row][d1]*w3;
            if (kcr < SEQ_) {
                float vt0 = vtmp[0][d0] + vtmp[1][d0] + vtmp[2][d0] + vtmp[3][d0];
                float vt1 = vtmp[0][d1] + vtmp[1][d1] + vtmp[2][d1] + vtmp[3][d1];
                n0 += 0.5f * ew * vt0; n1 += 0.5f * ew * vt1;
            }
            packed[dd >> 1] = (unsigned)f2bf(n0 * invL) | ((unsigned)f2bf(n1 * invL) << 16);
        }
        unsigned short* obf = ctxbf + ((size_t)(b * SEQ_ + qrow)) * D_ + hh * DK_ + g * 8;
        *(uint4*)obf = make_uint4(packed[0], packed[1], packed[2], packed[3]);
    }
}

// ---------------------------------------------------------------------------
// Kernel 4: fused post-attention block: block = 16 full rows.
//   h1 = LN1(resid + ctx@woT + ob)       (h1 kept in regs + bf16 LDS)
//   ff = relu(h1@w1T + f1b)              (per-256-col chunk, LDS only)
//   h  = LN2(h1 + ff@w2T + f2b)          -> hout fp32 + hbf
// Last-layer blocks owning rows 2047/4095 also emit out[b].
// ---------------------------------------------------------------------------
__global__ __launch_bounds__(256) void post_kernel(
    const unsigned short* __restrict__ ctx, const unsigned short* __restrict__ wo,
    const float* __restrict__ ob, const float* __restrict__ resid,
    const float* __restrict__ g1, const float* __restrict__ bt1,
    const unsigned short* __restrict__ w1, const float* __restrict__ f1b,
    const unsigned short* __restrict__ w2, const float* __restrict__ f2b,
    const float* __restrict__ g2, const float* __restrict__ bt2,
    float* __restrict__ hout, unsigned short* __restrict__ hbfout,
    const float* __restrict__ outW, const float* __restrict__ outb,
    float* __restrict__ out, int doFinal)
{
    __shared__ unsigned short As[16 * 256];     // DMA-staged ctx rows (swizzled)
    __shared__ unsigned short Bs[1024 * 8];     // 16KB weight staging (per k-step)
    __shared__ unsigned short h1s[16 * PAD];    // h1 bf16 (padded)
    __shared__ unsigned short ffc[16 * PAD];    // ff1 chunk bf16 (padded)
    __shared__ float lsum[4][16], lsq[4][16], mean_s[16], inv_s[16];
    __shared__ float red[256];

    int tid = threadIdx.x;
    int wave = tid >> 6, lane = tid & 63;
    int bm = blockIdx.x * 16;
    int fr = lane & 15, kb = lane >> 4;
    int q = kb, cl = fr;

    // pre-stage all ctx rows: 512 slots of 16B, 2 per thread
#pragma unroll
    for (int i = 0; i < 2; ++i) {
        int s = i * 256 + tid;
        int row = s >> 5, cbs = s & 31;
        int ks = cbs >> 2, jg = (cbs & 3) ^ (row & 3);
        gload_lds16(ctx + (size_t)(bm + row) * 256 + ks * 32 + jg * 8, &As[s * 8]);
    }

    int oB[4];
#pragma unroll
    for (int t = 0; t < 4; ++t) {
        int n = wave * 64 + t * 16 + fr;
        oB[t] = n * 32 + ((kb ^ (n & 3)) * 8);
    }

#define STAGE_BS(Wptr, Kstride, kbase)                                          \
    {                                                                           \
        _Pragma("unroll")                                                       \
        for (int i_ = 0; i_ < 4; ++i_) {                                        \
            int sB = i_ * 256 + tid;                                            \
            int r_ = sB >> 2;                                                   \
            int jg_ = (sB & 3) ^ (r_ & 3);                                      \
            gload_lds16((Wptr) + (size_t)r_ * (Kstride) + (kbase) + jg_ * 8,    \
                        &Bs[sB * 8]);                                           \
        }                                                                       \
    }

    // ---------- Phase O: o-proj (K=256) ----------
    f32x4 acc[4];
#pragma unroll
    for (int t = 0; t < 4; ++t) acc[t] = (f32x4){0.f, 0.f, 0.f, 0.f};

    for (int ks = 0; ks < 8; ++ks) {
        __syncthreads();
        STAGE_BS(wo, 256, ks * 32);
        __syncthreads();
        bf16x8 af = *(const bf16x8*)&As[fr * 256 + ks * 32 + ((kb ^ (fr & 3)) * 8)];
#pragma unroll
        for (int t = 0; t < 4; ++t)
            acc[t] = __builtin_amdgcn_mfma_f32_16x16x32_bf16(
                af, *(const bf16x8*)&Bs[oB[t]], acc[t], 0, 0, 0);
    }

    // epilogue O: +bias +resid, LN1 -> h1 regs + h1s LDS
    float h1[4][4];
    {
        float zs[4] = {0.f,0.f,0.f,0.f}, zq[4] = {0.f,0.f,0.f,0.f};
#pragma unroll
        for (int ct = 0; ct < 4; ++ct) {
            int col = wave * 64 + ct * 16 + cl;
            float bj = ob[col];
#pragma unroll
            for (int r = 0; r < 4; ++r) {
                int row = bm + q * 4 + r;
                float z = acc[ct][r] + bj + resid[(size_t)row * 256 + col];
                h1[ct][r] = z;
                zs[r] += z; zq[r] += z * z;
            }
        }
#pragma unroll
        for (int r = 0; r < 4; ++r) {
#pragma unroll
            for (int off = 1; off < 16; off <<= 1) {
                zs[r] += __shfl_xor(zs[r], off);
                zq[r] += __shfl_xor(zq[r], off);
            }
        }
        if (cl == 0) {
#pragma unroll
            for (int r = 0; r < 4; ++r) { lsum[wave][q*4+r] = zs[r]; lsq[wave][q*4+r] = zq[r]; }
        }
        __syncthreads();
        if (tid < 16) {
            float s  = lsum[0][tid] + lsum[1][tid] + lsum[2][tid] + lsum[3][tid];
            float sq = lsq[0][tid] + lsq[1][tid] + lsq[2][tid] + lsq[3][tid];
            float mean = s * (1.f / 256.f);
            float var  = sq * (1.f / 256.f) - mean * mean;
            mean_s[tid] = mean;
            inv_s[tid]  = rsqrtf(var + 1e-5f);
        }
        __syncthreads();
#pragma unroll
        for (int ct = 0; ct < 4; ++ct) {
            int col = wave * 64 + ct * 16 + cl;
            float gc = g1[col], bc = bt1[col];
#pragma unroll
            for (int r = 0; r < 4; ++r) {
                int lr = q * 4 + r;
                float hv = (h1[ct][r] - mean_s[lr]) * inv_s[lr] * gc + bc;
                h1[ct][r] = hv;
                h1s[lr * PAD + col] = f2bf(hv);
            }
        }
    }
    __syncthreads();    // h1s ready

    // ---------- FFN: 4 chunks of 256 ff1-cols ----------
    f32x4 acc2[4];
#pragma unroll
    for (int t = 0; t < 4; ++t) acc2[t] = (f32x4){0.f, 0.f, 0.f, 0.f};

    for (int c = 0; c < 4; ++c) {
        f32x4 a1[4];
#pragma unroll
        for (int t = 0; t < 4; ++t) a1[t] = (f32x4){0.f, 0.f, 0.f, 0.f};

        const unsigned short* w1c = w1 + (size_t)c * 256 * 256;
        for (int ks = 0; ks < 8; ++ks) {
            __syncthreads();
            STAGE_BS(w1c, 256, ks * 32);
            __syncthreads();
            bf16x8 af = *(const bf16x8*)&h1s[fr * PAD + ks * 32 + kb * 8];
#pragma unroll
            for (int t = 0; t < 4; ++t)
                a1[t] = __builtin_amdgcn_mfma_f32_16x16x32_bf16(
                    af, *(const bf16x8*)&Bs[oB[t]], a1[t], 0, 0, 0);
        }
        __syncthreads();   // prev-chunk ffc reads complete (and Bs reads)
#pragma unroll
        for (int ct = 0; ct < 4; ++ct) {
            int col = wave * 64 + ct * 16 + cl;
            float bj = f1b[c * 256 + col];
#pragma unroll
            for (int r = 0; r < 4; ++r) {
                float v = fmaxf(a1[ct][r] + bj, 0.f);
                ffc[(q * 4 + r) * PAD + col] = f2bf(v);
            }
        }
        __syncthreads();   // ffc ready

        for (int ks = 0; ks < 8; ++ks) {
            __syncthreads();
            STAGE_BS(w2, 1024, c * 256 + ks * 32);
            __syncthreads();
            bf16x8 af = *(const bf16x8*)&ffc[fr * PAD + ks * 32 + kb * 8];
#pragma unroll
            for (int t = 0; t < 4; ++t)
                acc2[t] = __builtin_amdgcn_mfma_f32_16x16x32_bf16(
                    af, *(const bf16x8*)&Bs[oB[t]], acc2[t], 0, 0, 0);
        }
    }

    // epilogue FFN2: +bias +h1, LN2 -> hout/hbf
    float h2[4][4];
    {
        float zs[4] = {0.f,0.f,0.f,0.f}, zq[4] = {0.f,0.f,0.f,0.f};
#pragma unroll
        for (int ct = 0; ct < 4; ++ct) {
            int col = wave * 64 + ct * 16 + cl;
            float bj = f2b[col];
#pragma unroll
            for (int r = 0; r < 4; ++r) {
                float z = acc2[ct][r] + bj + h1[ct][r];
                h2[ct][r] = z;
                zs[r] += z; zq[r] += z * z;
            }
        }
#pragma unroll
        for (int r = 0; r < 4; ++r) {
#pragma unroll
            for (int off = 1; off < 16; off <<= 1) {
                zs[r] += __shfl_xor(zs[r], off);
                zq[r] += __shfl_xor(zq[r], off);
            }
        }
        __syncthreads();   // reuse lsum/lsq safely
        if (cl == 0) {
#pragma unroll
            for (int r = 0; r < 4; ++r) { lsum[wave][q*4+r] = zs[r]; lsq[wave][q*4+r] = zq[r]; }
        }
        __syncthreads();
        if (tid < 16) {
            float s  = lsum[0][tid] + lsum[1][tid] + lsum[2][tid] + lsum[3][tid];
            float sq = lsq[0][tid] + lsq[1][tid] + lsq[2][tid] + lsq[3][tid];
            float mean = s * (1.f / 256.f);
            float var  = sq * (1.f / 256.f) - mean * mean;
            mean_s[tid] = mean;
            inv_s[tid]  = rsqrtf(var + 1e-5f);
        }
        __syncthreads();
#pragma unroll
        for (int ct = 0; ct < 4; ++ct) {
            int col = wave * 64 + ct * 16 + cl;
            float gc = g2[col], bc = bt2[col];
#pragma unroll
            for (int r = 0; r < 4; ++r) {
                int lr = q * 4 + r;
                float o = (h2[ct][r] - mean_s[lr]) * inv_s[lr] * gc + bc;
                h2[ct][r] = o;
                size_t off = (size_t)(bm + lr) * 256 + col;
                hout[off] = o;
                hbfout[off] = f2bf(o);
            }
        }
    }

    // final output fold (last layer, blocks owning rows 2047 / 4095)
    int brow = bm + 15;
    if (doFinal && (brow == 2047 || brow == 4095)) {
        if (q == 3) {
#pragma unroll
            for (int ct = 0; ct < 4; ++ct) {
                int col = wave * 64 + ct * 16 + cl;
                red[col] = h2[ct][3] * outW[col];
            }
        }
        __syncthreads();
        if (tid < 64) {
            float s = red[tid] + red[tid + 64] + red[tid + 128] + red[tid + 192];
#pragma unroll
            for (int off = 1; off < 64; off <<= 1) s += __shfl_xor(s, off);
            if (tid == 0) out[brow >> 11] = s * 0.5f + outb[0];
        }
    }
}

// ---------------------------------------------------------------------------
extern "C" void kernel_launch(void* const* d_in, const int* in_sizes, int n_in,
                              void* d_out, int out_size, void* d_ws, size_t ws_size,
                              hipStream_t stream)
{
    (void)in_sizes; (void)n_in; (void)out_size; (void)ws_size;
    const float* x      = (const float*)d_in[0];
    const float* conv_w = (const float*)d_in[1];
    const float* conv_b = (const float*)d_in[2];
    const float* bn_g   = (const float*)d_in[3];
    const float* bn_b   = (const float*)d_in[4];
    const float* pe     = (const float*)d_in[5];
    const float* qW     = (const float*)d_in[6];
    const float* qb     = (const float*)d_in[7];
    const float* kW     = (const float*)d_in[8];
    const float* kb     = (const float*)d_in[9];
    const float* vW     = (const float*)d_in[10];
    const float* vb     = (const float*)d_in[11];
    const float* oW     = (const float*)d_in[12];
    const float* ob     = (const float*)d_in[13];
    const float* scale  = (const float*)d_in[14];
    const float* td     = (const float*)d_in[15];
    const float* ln1g   = (const float*)d_in[16];
    const float* ln1b   = (const float*)d_in[17];
    const float* f1W    = (const float*)d_in[18];
    const float* f1b    = (const float*)d_in[19];
    const float* f2W    = (const float*)d_in[20];
    const float* f2b    = (const float*)d_in[21];
    const float* ln2g   = (const float*)d_in[22];
    const float* ln2b   = (const float*)d_in[23];
    const float* outW   = (const float*)d_in[24];
    const float* outb   = (const float*)d_in[25];
    float* out = (float*)d_out;

    float* ws = (float*)d_ws;
    const size_t MT = (size_t)B_ * SEQ_ * D_;      // 1,048,576
    float* h     = ws;                             // MT fp32
    float* vpart = ws + MT;                        // 64*256 fp32
    unsigned short* bfb = (unsigned short*)(ws + MT + 64 * 256);
    unsigned short* h_bf   = bfb;
    unsigned short* ctx_bf = bfb + MT;
    unsigned short* q_bf   = bfb + 2 * MT;
    unsigned short* k_bf   = bfb + 3 * MT;
    unsigned short* v_bf   = bfb + 4 * MT;
    unsigned short* wq_bf  = bfb + 5 * MT;
    unsigned short* wk_bf  = wq_bf + MT / 8;
    unsigned short* wv_bf  = wk_bf + MT / 8;
    unsigned short* wo_bf  = wv_bf + MT / 8;
    unsigned short* wf1_bf = wo_bf + MT / 8;
    unsigned short* wf2_bf = wf1_bf + MT / 2;

    const int Mrows = B_ * SEQ_;                   // 4096

    prep_kernel<<<768 + (B_ * SEQ_ * D_) / 256, 256, 0, stream>>>(
        x, conv_w, conv_b, bn_g, bn_b, pe, h, h_bf,
        qW, kW, vW, oW, f1W, f2W,
        wq_bf, wk_bf, wv_bf, wo_bf, wf1_bf, wf2_bf);

    for (int l = 0; l < L_; ++l) {
        const unsigned short* wq_l  = wq_bf  + (size_t)l * D_ * D_;
        const unsigned short* wk_l  = wk_bf  + (size_t)l * D_ * D_;
        const unsigned short* wv_l  = wv_bf  + (size_t)l * D_ * D_;
        const unsigned short* wo_l  = wo_bf  + (size_t)l * D_ * D_;
        const unsigned short* wf1_l = wf1_bf + (size_t)l * DFF_ * D_;
        const unsigned short* wf2_l = wf2_bf + (size_t)l * DFF_ * D_;

        gemm_qkv<<<dim3(D_ / 64, Mrows / 64, 3), 256, 0, stream>>>(
            h_bf, wq_l, wk_l, wv_l, qb + l * D_, kb + l * D_, vb + l * D_,
            q_bf, k_bf, v_bf, td + l * H_, vpart, Mrows, D_, D_);

        attn_kernel<<<dim3(SEQ_ / 32, H_, B_), 128, 0, stream>>>(
            q_bf, k_bf, v_bf, vpart, ctx_bf, scale + l, td + l * H_);

        post_kernel<<<Mrows / 16, 256, 0, stream>>>(
            ctx_bf, wo_l, ob + l * D_, h,
            ln1g + l * D_, ln1b + l * D_,
            wf1_l, f1b + l * DFF_,
            wf2_l, f2b + l * D_,
            ln2g + l * D_, ln2b + l * D_,
            h, h_bf, outW, outb, out, (l == L_ - 1) ? 1 : 0);
    }
}

// Round 8
// 224.025 us; speedup vs baseline: 1.3878x; 1.1013x over previous
//
#include <hip/hip_runtime.h>
#include <math.h>

#define B_    2
#define SEQ_  2048
#define D_    256
#define H_    8
#define DK_   32
#define L_    2
#define DFF_  1024

#define TD_CUT 44.0f
#define PAD 264   // padded LDS row (shorts) for direct-written tiles

typedef short  bf16x8 __attribute__((ext_vector_type(8)));
typedef float  f32x4  __attribute__((ext_vector_type(4)));

__device__ __forceinline__ int compute_kcut(float tdv) {
    int kcut = SEQ_;
    if (tdv > 1e-9f) {
        float kc = TD_CUT / tdv;
        kcut = (kc >= (float)SEQ_) ? SEQ_ : ((int)kc + 1);
    }
    int kcr = (kcut + 31) & ~31;
    if (kcr > SEQ_) kcr = SEQ_;
    return kcr;
}

__device__ __forceinline__ unsigned short f2bf(float f) {
    unsigned int u = __float_as_uint(f);
    unsigned int r = u + 0x7FFFu + ((u >> 16) & 1u);   // RNE
    return (unsigned short)(r >> 16);
}
__device__ __forceinline__ float bf2f(unsigned short u) {
    return __uint_as_float(((unsigned int)u) << 16);
}

__device__ __forceinline__ void gload_lds16(const unsigned short* g, unsigned short* l) {
    __builtin_amdgcn_global_load_lds(
        (const __attribute__((address_space(1))) unsigned int*)(const unsigned int*)g,
        (__attribute__((address_space(3))) unsigned int*)(unsigned int*)l,
        16, 0, 0);
}

// ---------------------------------------------------------------------------
// Kernel 1: prep = weight fp32->bf16 convert (blocks 0..767) + conv/pe (rest)
// ---------------------------------------------------------------------------
__global__ __launch_bounds__(256) void prep_kernel(
    const float* __restrict__ x, const float* __restrict__ w,
    const float* __restrict__ cb, const float* __restrict__ bg,
    const float* __restrict__ bb, const float* __restrict__ pe,
    float* __restrict__ h, unsigned short* __restrict__ hbf,
    const float* __restrict__ p0, const float* __restrict__ p1,
    const float* __restrict__ p2, const float* __restrict__ p3,
    const float* __restrict__ p4, const float* __restrict__ p5,
    unsigned short* __restrict__ q0, unsigned short* __restrict__ q1,
    unsigned short* __restrict__ q2, unsigned short* __restrict__ q3,
    unsigned short* __restrict__ q4, unsigned short* __restrict__ q5)
{
    int bid = blockIdx.x;
    if (bid < 768) {                              // ---- cvt path
        int t = bid * 256 + threadIdx.x;
        const float* src; unsigned short* dst; int base;
        if (t < 65536) {
            int a = t >> 14;
            src = a == 0 ? p0 : a == 1 ? p1 : a == 2 ? p2 : p3;
            dst = a == 0 ? q0 : a == 1 ? q1 : a == 2 ? q2 : q3;
            base = (t & 16383) * 8;
        } else {
            int u = t - 65536;
            int a = u >> 16;
            src = a ? p5 : p4;
            dst = a ? q5 : q4;
            base = (u & 65535) * 8;
        }
        float4 v0 = *(const float4*)(src + base);
        float4 v1 = *(const float4*)(src + base + 4);
        bf16x8 o;
        o[0] = (short)f2bf(v0.x); o[1] = (short)f2bf(v0.y);
        o[2] = (short)f2bf(v0.z); o[3] = (short)f2bf(v0.w);
        o[4] = (short)f2bf(v1.x); o[5] = (short)f2bf(v1.y);
        o[6] = (short)f2bf(v1.z); o[7] = (short)f2bf(v1.w);
        *(bf16x8*)(dst + base) = o;
        return;
    }
    // ---- conv path
    int idx = (bid - 768) * 256 + threadIdx.x;    // b*SEQ*D + s*D + d
    int d = idx & 255;
    int s = (idx >> 8) & 2047;
    int b = idx >> 19;

    const float* xp = x + b * SEQ_;
    float xm1 = (s > 0)        ? xp[s - 1] : 0.f;
    float x0  = xp[s];
    float xp1 = (s < SEQ_ - 1) ? xp[s + 1] : 0.f;

    float acc = xm1 * w[d * 3 + 0] + x0 * w[d * 3 + 1] + xp1 * w[d * 3 + 2];
    acc += cb[d];
    acc = acc * rsqrtf(1.f + 1e-5f) * bg[d] + bb[d];
    acc = fmaxf(acc, 0.f);
    float v = acc + pe[s * D_ + d];
    h[idx] = v;
    hbf[idx] = f2bf(v);
}

// ---------------------------------------------------------------------------
// Kernel 2: q/k/v GEMM (bf16 in/out) + fused vtail partial sums for V (z==2).
// 64x64 tile, BK=32. Swizzle s(r)=(r>>1)&3 -> conflict-free b128 frag reads.
// ---------------------------------------------------------------------------
__global__ __launch_bounds__(256) void gemm_qkv(
    const unsigned short* __restrict__ A,
    const unsigned short* __restrict__ W0, const unsigned short* __restrict__ W1,
    const unsigned short* __restrict__ W2,
    const float* __restrict__ b0, const float* __restrict__ b1,
    const float* __restrict__ b2,
    unsigned short* __restrict__ O0, unsigned short* __restrict__ O1,
    unsigned short* __restrict__ O2,
    const float* __restrict__ td_l, float* __restrict__ vpart,
    int M, int N, int K)
{
    int z = blockIdx.z;
    const unsigned short* W = (z == 0) ? W0 : (z == 1) ? W1 : W2;
    const float* bias = (z == 0) ? b0 : (z == 1) ? b1 : b2;
    unsigned short* C = (z == 0) ? O0 : (z == 1) ? O1 : O2;

    __shared__ unsigned short As[64 * 32];
    __shared__ unsigned short Bs[64 * 32];
    __shared__ float vsc[4][2][16];

    int tid  = threadIdx.x;
    int wave = tid >> 6, lane = tid & 63;
    int wm = (wave & 1) * 32, wn = (wave >> 1) * 32;
    int bm = blockIdx.y * 64, bn = blockIdx.x * 64;

    int sr  = tid >> 2;
    int scb = (tid & 3) ^ ((sr >> 1) & 3);
    const unsigned short* aG = A + (size_t)(bm + sr) * K + scb * 8;
    const unsigned short* wG = W + (size_t)(bn + sr) * K + scb * 8;
    unsigned short* aL = &As[tid * 8];
    unsigned short* bL = &Bs[tid * 8];

    int fr = lane & 15;
    int kb = lane >> 4;
    int cb = (kb ^ ((fr >> 1) & 3)) * 8;
    int oA0 = (wm + fr) * 32 + cb;
    int oA1 = (wm + 16 + fr) * 32 + cb;
    int oB0 = (wn + fr) * 32 + cb;
    int oB1 = (wn + 16 + fr) * 32 + cb;

    f32x4 acc[2][2];
#pragma unroll
    for (int i = 0; i < 2; ++i)
#pragma unroll
        for (int j = 0; j < 2; ++j) acc[i][j] = (f32x4){0.f, 0.f, 0.f, 0.f};

    for (int k0 = 0; k0 < K; k0 += 32) {
        __syncthreads();
        gload_lds16(aG + k0, aL);
        gload_lds16(wG + k0, bL);
        __syncthreads();

        bf16x8 a0f = *(const bf16x8*)&As[oA0];
        bf16x8 a1f = *(const bf16x8*)&As[oA1];
        bf16x8 b0f = *(const bf16x8*)&Bs[oB0];
        bf16x8 b1f = *(const bf16x8*)&Bs[oB1];

        acc[0][0] = __builtin_amdgcn_mfma_f32_16x16x32_bf16(a0f, b0f, acc[0][0], 0, 0, 0);
        acc[0][1] = __builtin_amdgcn_mfma_f32_16x16x32_bf16(a0f, b1f, acc[0][1], 0, 0, 0);
        acc[1][0] = __builtin_amdgcn_mfma_f32_16x16x32_bf16(a1f, b0f, acc[1][0], 0, 0, 0);
        acc[1][1] = __builtin_amdgcn_mfma_f32_16x16x32_bf16(a1f, b1f, acc[1][1], 0, 0, 0);
    }

    int crow = (lane >> 4) * 4;
    int ccol = lane & 15;
    float psum[2] = {0.f, 0.f};
    int kc[2];
    kc[0] = compute_kcut(td_l[(bn + wn) >> 5]);
    kc[1] = compute_kcut(td_l[(bn + wn + 16) >> 5]);

#pragma unroll
    for (int j = 0; j < 2; ++j) {
        float bj = bias[bn + wn + j * 16 + ccol];
#pragma unroll
        for (int i = 0; i < 2; ++i) {
#pragma unroll
            for (int r = 0; r < 4; ++r) {
                float v = acc[i][j][r] + bj;
                unsigned short ubf = f2bf(v);
                C[(size_t)(bm + wm + i * 16 + crow + r) * N + bn + wn + j * 16 + ccol] = ubf;
                if (z == 2) {
                    int srow = (bm + wm + i * 16 + crow + r) & 2047;
                    if (srow >= kc[j]) psum[j] += bf2f(ubf);
                }
            }
        }
    }

    if (z == 2) {
#pragma unroll
        for (int j = 0; j < 2; ++j) {
            psum[j] += __shfl_xor(psum[j], 16);
            psum[j] += __shfl_xor(psum[j], 32);
        }
        if (lane < 16) { vsc[wave][0][lane] = psum[0]; vsc[wave][1][lane] = psum[1]; }
        __syncthreads();
        if (tid < 64) {
            int wh = tid >> 5, jj = (tid >> 4) & 1, cc = tid & 15;
            float s = vsc[2 * wh][jj][cc] + vsc[2 * wh + 1][jj][cc];
            vpart[(size_t)blockIdx.y * 256 + bn + wh * 32 + jj * 16 + cc] = s;
        }
    }
}

// ---------------------------------------------------------------------------
// Kernel 3: decay-truncated flash attention, 4-way key-split + LDS merge.
// ---------------------------------------------------------------------------
__global__ __launch_bounds__(128) void attn_kernel(
    const unsigned short* __restrict__ q, const unsigned short* __restrict__ k,
    const unsigned short* __restrict__ v, const float* __restrict__ vpart,
    unsigned short* __restrict__ ctxbf,
    const float* __restrict__ scale_p, const float* __restrict__ td_l)
{
    int b = blockIdx.z, hh = blockIdx.y;
    int tid = threadIdx.x;
    int row = tid >> 2;
    int sp  = tid & 3;
    int qrow = blockIdx.x * 32 + row;

    float sc  = 0.17677669529663687f * scale_p[0];
    float tdv = td_l[hh];
    int kcr = compute_kcut(tdv);
    int ntiles = kcr >> 5;

    __shared__ float kt[32][36];
    __shared__ float vt[32][36];
    __shared__ float Os[4][32][36];
    __shared__ float ms[4][32], ls[4][32];
    __shared__ float vtmp[4][32];

    {
        int d = tid & 31, gq = tid >> 5;
        float s = 0.f;
        for (int rb = gq; rb < 32; rb += 4)
            s += vpart[(size_t)(b * 32 + rb) * 256 + hh * 32 + d];
        vtmp[gq][d] = s;
    }

    const unsigned short* qptr = q + ((size_t)(b * SEQ_ + qrow)) * D_ + hh * DK_;
    float qreg[32];
#pragma unroll
    for (int j = 0; j < 4; ++j) {
        uint4 u = ((const uint4*)qptr)[j];
        qreg[j*8+0] = __uint_as_float(u.x << 16); qreg[j*8+1] = __uint_as_float(u.x & 0xFFFF0000u);
        qreg[j*8+2] = __uint_as_float(u.y << 16); qreg[j*8+3] = __uint_as_float(u.y & 0xFFFF0000u);
        qreg[j*8+4] = __uint_as_float(u.z << 16); qreg[j*8+5] = __uint_as_float(u.z & 0xFFFF0000u);
        qreg[j*8+6] = __uint_as_float(u.w << 16); qreg[j*8+7] = __uint_as_float(u.w & 0xFFFF0000u);
    }
    float O[32];
#pragma unroll
    for (int d = 0; d < 32; ++d) O[d] = 0.f;
    float mrun = -1e30f, lrun = 0.f;

    for (int t = 0; t < ntiles; ++t) {
        int k0 = t * 32;
        __syncthreads();
        {
            int r = tid >> 2, c8 = (tid & 3) * 8;
            size_t goff = ((size_t)(b * SEQ_ + k0 + r)) * D_ + hh * DK_ + c8;
            uint4 uk = *(const uint4*)(k + goff);
            uint4 uv = *(const uint4*)(v + goff);
            *(float4*)&kt[r][c8]     = make_float4(__uint_as_float(uk.x << 16), __uint_as_float(uk.x & 0xFFFF0000u),
                                                   __uint_as_float(uk.y << 16), __uint_as_float(uk.y & 0xFFFF0000u));
            *(float4*)&kt[r][c8 + 4] = make_float4(__uint_as_float(uk.z << 16), __uint_as_float(uk.z & 0xFFFF0000u),
                                                   __uint_as_float(uk.w << 16), __uint_as_float(uk.w & 0xFFFF0000u));
            *(float4*)&vt[r][c8]     = make_float4(__uint_as_float(uv.x << 16), __uint_as_float(uv.x & 0xFFFF0000u),
                                                   __uint_as_float(uv.y << 16), __uint_as_float(uv.y & 0xFFFF0000u));
            *(float4*)&vt[r][c8 + 4] = make_float4(__uint_as_float(uv.z << 16), __uint_as_float(uv.z & 0xFFFF0000u),
                                                   __uint_as_float(uv.w << 16), __uint_as_float(uv.w & 0xFFFF0000u));
        }
        __syncthreads();

        float sb[8];
        float tmax = -1e30f;
#pragma unroll
        for (int kk = 0; kk < 8; ++kk) {
            int kl = sp * 8 + kk;
            float acc = 0.f;
#pragma unroll
            for (int d4 = 0; d4 < 8; ++d4) {
                float4 kv = *(const float4*)&kt[kl][d4 * 4];
                acc += qreg[d4 * 4 + 0] * kv.x + qreg[d4 * 4 + 1] * kv.y
                     + qreg[d4 * 4 + 2] * kv.z + qreg[d4 * 4 + 3] * kv.w;
            }
            float dec = __expf(-tdv * (float)(k0 + kl));
            float sv = acc * sc * dec;
            sb[kk] = sv;
            tmax = fmaxf(tmax, sv);
        }
        float mnew = fmaxf(mrun, tmax);
        float alpha = __expf(mrun - mnew);
        lrun *= alpha;
#pragma unroll
        for (int d = 0; d < 32; ++d) O[d] *= alpha;
#pragma unroll
        for (int kk = 0; kk < 8; ++kk) {
            int kl = sp * 8 + kk;
            float sv = sb[kk];
            float e = __expf(sv - mnew);
            float sg = 1.f / (1.f + __expf(-sv));
            float p = e * sg;
            lrun += e;
#pragma unroll
            for (int d4 = 0; d4 < 8; ++d4) {
                float4 vv = *(const float4*)&vt[kl][d4 * 4];
                O[d4 * 4 + 0] += p * vv.x; O[d4 * 4 + 1] += p * vv.y;
                O[d4 * 4 + 2] += p * vv.z; O[d4 * 4 + 3] += p * vv.w;
            }
        }
        mrun = mnew;
    }

#pragma unroll
    for (int d4 = 0; d4 < 8; ++d4)
        *(float4*)&Os[sp][row][d4 * 4] =
            make_float4(O[d4*4+0], O[d4*4+1], O[d4*4+2], O[d4*4+3]);
    ms[sp][row] = mrun;
    ls[sp][row] = lrun;
    __syncthreads();

    {
        int g = sp;
        float m0 = fmaxf(fmaxf(ms[0][row], ms[1][row]), fmaxf(ms[2][row], ms[3][row]));
        float mt = (kcr < SEQ_) ? fmaxf(m0, 0.f) : m0;
        float w0 = __expf(ms[0][row] - mt), w1 = __expf(ms[1][row] - mt);
        float w2 = __expf(ms[2][row] - mt), w3 = __expf(ms[3][row] - mt);
        float Lt = ls[0][row]*w0 + ls[1][row]*w1 + ls[2][row]*w2 + ls[3][row]*w3;
        float ew = 0.f;
        if (kcr < SEQ_) {
            ew = __expf(-mt);
            Lt += (float)(SEQ_ - kcr) * ew;
        }
        float invL = 1.f / Lt;
        unsigned int packed[4];
#pragma unroll
        for (int dd = 0; dd < 8; dd += 2) {
            int d0 = g * 8 + dd, d1 = d0 + 1;
            float n0 = Os[0][row][d0]*w0 + Os[1][row][d0]*w1 + Os[2][row][d0]*w2 + Os[3][row][d0]*w3;
            float n1 = Os[0][row][d1]*w0 + Os[1][row][d1]*w1 + Os[2][row][d1]*w2 + Os[3][row][d1]*w3;
            if (kcr < SEQ_) {
                float vt0 = vtmp[0][d0] + vtmp[1][d0] + vtmp[2][d0] + vtmp[3][d0];
                float vt1 = vtmp[0][d1] + vtmp[1][d1] + vtmp[2][d1] + vtmp[3][d1];
                n0 += 0.5f * ew * vt0; n1 += 0.5f * ew * vt1;
            }
            packed[dd >> 1] = (unsigned)f2bf(n0 * invL) | ((unsigned)f2bf(n1 * invL) << 16);
        }
        unsigned short* obf = ctxbf + ((size_t)(b * SEQ_ + qrow)) * D_ + hh * DK_ + g * 8;
        *(uint4*)obf = make_uint4(packed[0], packed[1], packed[2], packed[3]);
    }
}

// ---------------------------------------------------------------------------
// Kernel 4: fused post-attention block, 16 rows/block, double-buffered BK=64.
//   h1 = LN1(resid + ctx@woT + ob);  ff = relu(h1@w1T);  h = LN2(h1 + ff@w2T)
// Weight staging: Bs[2] ping-pong 32KB halves; stored block cb holds global
// block cb^(r&7) (64-short rows) -> conflict-free b128 reads.
// ---------------------------------------------------------------------------
__global__ __launch_bounds__(256) void post_kernel(
    const unsigned short* __restrict__ ctx, const unsigned short* __restrict__ wo,
    const float* __restrict__ ob, const float* __restrict__ resid,
    const float* __restrict__ g1, const float* __restrict__ bt1,
    const unsigned short* __restrict__ w1, const float* __restrict__ f1b,
    const unsigned short* __restrict__ w2, const float* __restrict__ f2b,
    const float* __restrict__ g2, const float* __restrict__ bt2,
    float* __restrict__ hout, unsigned short* __restrict__ hbfout,
    const float* __restrict__ outW, const float* __restrict__ outb,
    float* __restrict__ out, int doFinal)
{
    __shared__ unsigned short As[16 * 256];     // ctx rows (DMA, swizzled r&7)
    __shared__ unsigned short Bs[2][2048 * 8];  // 2 x 32KB weight ping-pong
    __shared__ unsigned short h1s[16 * PAD];
    __shared__ unsigned short ffc[16 * PAD];
    __shared__ float lsum[4][16], lsq[4][16], mean_s[16], inv_s[16];
    __shared__ float red[256];

    int tid = threadIdx.x;
    int wave = tid >> 6, lane = tid & 63;
    int bm = blockIdx.x * 16;
    int fr = lane & 15, kb = lane >> 4;
    int q = kb, cl = fr;
    int frs = fr & 7;

    // stage all 16 ctx rows: 512 slots, stored block c holds global c^(r&7)
#pragma unroll
    for (int i = 0; i < 2; ++i) {
        int s = i * 256 + tid;
        int r = s >> 5, c = s & 31;
        gload_lds16(ctx + (size_t)(bm + r) * 256 + ((c ^ (r & 7)) * 8), &As[s * 8]);
    }

    // stage one BK=64 slab (256 rows x 64 k) into Bs[buf]
    auto stage64 = [&](int buf, const unsigned short* W, int Kstride, int kbase) {
#pragma unroll
        for (int i = 0; i < 8; ++i) {
            int sB = i * 256 + tid;
            int r = sB >> 3, cb3 = sB & 7;
            gload_lds16(W + (size_t)r * Kstride + kbase + ((cb3 ^ (r & 7)) * 8),
                        &Bs[buf][sB * 8]);
        }
    };

    // ---------- Phase O: o-proj (K=256, 4 dbuf steps) ----------
    f32x4 acc[4];
#pragma unroll
    for (int t = 0; t < 4; ++t) acc[t] = (f32x4){0.f, 0.f, 0.f, 0.f};

    stage64(0, wo, 256, 0);
    for (int ks = 0; ks < 4; ++ks) {
        __syncthreads();
        if (ks < 3) stage64((ks + 1) & 1, wo, 256, (ks + 1) * 64);
        const unsigned short* Bc = Bs[ks & 1];
#pragma unroll
        for (int t2 = 0; t2 < 2; ++t2) {
            int tk = ks * 2 + t2;
            bf16x8 af = *(const bf16x8*)&As[fr * 256 + (((tk * 4 + kb) ^ frs) * 8)];
#pragma unroll
            for (int t = 0; t < 4; ++t) {
                int n = wave * 64 + t * 16 + fr;
                bf16x8 bfv = *(const bf16x8*)&Bc[n * 64 + (((t2 * 4 + kb) ^ frs) * 8)];
                acc[t] = __builtin_amdgcn_mfma_f32_16x16x32_bf16(af, bfv, acc[t], 0, 0, 0);
            }
        }
    }

    // epilogue O: +bias +resid, LN1 -> h1 regs + h1s LDS
    float h1[4][4];
    {
        float zs[4] = {0.f,0.f,0.f,0.f}, zq[4] = {0.f,0.f,0.f,0.f};
#pragma unroll
        for (int ct = 0; ct < 4; ++ct) {
            int col = wave * 64 + ct * 16 + cl;
            float bj = ob[col];
#pragma unroll
            for (int r = 0; r < 4; ++r) {
                int row = bm + q * 4 + r;
                float z = acc[ct][r] + bj + resid[(size_t)row * 256 + col];
                h1[ct][r] = z;
                zs[r] += z; zq[r] += z * z;
            }
        }
#pragma unroll
        for (int r = 0; r < 4; ++r) {
#pragma unroll
            for (int off = 1; off < 16; off <<= 1) {
                zs[r] += __shfl_xor(zs[r], off);
                zq[r] += __shfl_xor(zq[r], off);
            }
        }
        if (cl == 0) {
#pragma unroll
            for (int r = 0; r < 4; ++r) { lsum[wave][q*4+r] = zs[r]; lsq[wave][q*4+r] = zq[r]; }
        }
        __syncthreads();
        if (tid < 16) {
            float s  = lsum[0][tid] + lsum[1][tid] + lsum[2][tid] + lsum[3][tid];
            float sq = lsq[0][tid] + lsq[1][tid] + lsq[2][tid] + lsq[3][tid];
            float mean = s * (1.f / 256.f);
            float var  = sq * (1.f / 256.f) - mean * mean;
            mean_s[tid] = mean;
            inv_s[tid]  = rsqrtf(var + 1e-5f);
        }
        __syncthreads();
#pragma unroll
        for (int ct = 0; ct < 4; ++ct) {
            int col = wave * 64 + ct * 16 + cl;
            float gc = g1[col], bc = bt1[col];
#pragma unroll
            for (int r = 0; r < 4; ++r) {
                int lr = q * 4 + r;
                float hv = (h1[ct][r] - mean_s[lr]) * inv_s[lr] * gc + bc;
                h1[ct][r] = hv;
                h1s[lr * PAD + col] = f2bf(hv);
            }
        }
    }
    __syncthreads();    // h1s visible

    // ---------- FFN: 4 chunks of 256 ff1-cols ----------
    f32x4 acc2[4];
#pragma unroll
    for (int t = 0; t < 4; ++t) acc2[t] = (f32x4){0.f, 0.f, 0.f, 0.f};

    for (int c = 0; c < 4; ++c) {
        f32x4 a1[4];
#pragma unroll
        for (int t = 0; t < 4; ++t) a1[t] = (f32x4){0.f, 0.f, 0.f, 0.f};

        const unsigned short* w1c = w1 + (size_t)c * 256 * 256;
        stage64(0, w1c, 256, 0);
        for (int ks = 0; ks < 4; ++ks) {
            __syncthreads();
            if (ks < 3) stage64((ks + 1) & 1, w1c, 256, (ks + 1) * 64);
            const unsigned short* Bc = Bs[ks & 1];
#pragma unroll
            for (int t2 = 0; t2 < 2; ++t2) {
                int tk = ks * 2 + t2;
                bf16x8 af = *(const bf16x8*)&h1s[fr * PAD + tk * 32 + kb * 8];
#pragma unroll
                for (int t = 0; t < 4; ++t) {
                    int n = wave * 64 + t * 16 + fr;
                    bf16x8 bfv = *(const bf16x8*)&Bc[n * 64 + (((t2 * 4 + kb) ^ frs) * 8)];
                    a1[t] = __builtin_amdgcn_mfma_f32_16x16x32_bf16(af, bfv, a1[t], 0, 0, 0);
                }
            }
        }
        // prefetch FFN2's first slab while doing the relu epilogue
        stage64(0, w2, 1024, c * 256);
#pragma unroll
        for (int ct = 0; ct < 4; ++ct) {
            int col = wave * 64 + ct * 16 + cl;
            float bj = f1b[c * 256 + col];
#pragma unroll
            for (int r = 0; r < 4; ++r) {
                float v = fmaxf(a1[ct][r] + bj, 0.f);
                ffc[(q * 4 + r) * PAD + col] = f2bf(v);
            }
        }
        __syncthreads();   // ffc visible; Bs[0] DMA drained

        for (int ks = 0; ks < 4; ++ks) {
            if (ks) __syncthreads();
            if (ks < 3) stage64((ks + 1) & 1, w2, 1024, c * 256 + (ks + 1) * 64);
            const unsigned short* Bc = Bs[ks & 1];
#pragma unroll
            for (int t2 = 0; t2 < 2; ++t2) {
                int tk = ks * 2 + t2;
                bf16x8 af = *(const bf16x8*)&ffc[fr * PAD + tk * 32 + kb * 8];
#pragma unroll
                for (int t = 0; t < 4; ++t) {
                    int n = wave * 64 + t * 16 + fr;
                    bf16x8 bfv = *(const bf16x8*)&Bc[n * 64 + (((t2 * 4 + kb) ^ frs) * 8)];
                    acc2[t] = __builtin_amdgcn_mfma_f32_16x16x32_bf16(af, bfv, acc2[t], 0, 0, 0);
                }
            }
        }
    }

    // epilogue FFN2: +bias +h1, LN2 -> hout/hbf
    float h2[4][4];
    {
        float zs[4] = {0.f,0.f,0.f,0.f}, zq[4] = {0.f,0.f,0.f,0.f};
#pragma unroll
        for (int ct = 0; ct < 4; ++ct) {
            int col = wave * 64 + ct * 16 + cl;
            float bj = f2b[col];
#pragma unroll
            for (int r = 0; r < 4; ++r) {
                float z = acc2[ct][r] + bj + h1[ct][r];
                h2[ct][r] = z;
                zs[r] += z; zq[r] += z * z;
            }
        }
#pragma unroll
        for (int r = 0; r < 4; ++r) {
#pragma unroll
            for (int off = 1; off < 16; off <<= 1) {
                zs[r] += __shfl_xor(zs[r], off);
                zq[r] += __shfl_xor(zq[r], off);
            }
        }
        __syncthreads();
        if (cl == 0) {
#pragma unroll
            for (int r = 0; r < 4; ++r) { lsum[wave][q*4+r] = zs[r]; lsq[wave][q*4+r] = zq[r]; }
        }
        __syncthreads();
        if (tid < 16) {
            float s  = lsum[0][tid] + lsum[1][tid] + lsum[2][tid] + lsum[3][tid];
            float sq = lsq[0][tid] + lsq[1][tid] + lsq[2][tid] + lsq[3][tid];
            float mean = s * (1.f / 256.f);
            float var  = sq * (1.f / 256.f) - mean * mean;
            mean_s[tid] = mean;
            inv_s[tid]  = rsqrtf(var + 1e-5f);
        }
        __syncthreads();
#pragma unroll
        for (int ct = 0; ct < 4; ++ct) {
            int col = wave * 64 + ct * 16 + cl;
            float gc = g2[col], bc = bt2[col];
#pragma unroll
            for (int r = 0; r < 4; ++r) {
                int lr = q * 4 + r;
                float o = (h2[ct][r] - mean_s[lr]) * inv_s[lr] * gc + bc;
                h2[ct][r] = o;
                size_t off = (size_t)(bm + lr) * 256 + col;
                hout[off] = o;
                hbfout[off] = f2bf(o);
            }
        }
    }

    // final output fold (last layer, blocks owning rows 2047 / 4095)
    int brow = bm + 15;
    if (doFinal && (brow == 2047 || brow == 4095)) {
        if (q == 3) {
#pragma unroll
            for (int ct = 0; ct < 4; ++ct) {
                int col = wave * 64 + ct * 16 + cl;
                red[col] = h2[ct][3] * outW[col];
            }
        }
        __syncthreads();
        if (tid < 64) {
            float s = red[tid] + red[tid + 64] + red[tid + 128] + red[tid + 192];
#pragma unroll
            for (int off = 1; off < 64; off <<= 1) s += __shfl_xor(s, off);
            if (tid == 0) out[brow >> 11] = s * 0.5f + outb[0];
        }
    }
}

// ---------------------------------------------------------------------------
extern "C" void kernel_launch(void* const* d_in, const int* in_sizes, int n_in,
                              void* d_out, int out_size, void* d_ws, size_t ws_size,
                              hipStream_t stream)
{
    (void)in_sizes; (void)n_in; (void)out_size; (void)ws_size;
    const float* x      = (const float*)d_in[0];
    const float* conv_w = (const float*)d_in[1];
    const float* conv_b = (const float*)d_in[2];
    const float* bn_g   = (const float*)d_in[3];
    const float* bn_b   = (const float*)d_in[4];
    const float* pe     = (const float*)d_in[5];
    const float* qW     = (const float*)d_in[6];
    const float* qb     = (const float*)d_in[7];
    const float* kW     = (const float*)d_in[8];
    const float* kb     = (const float*)d_in[9];
    const float* vW     = (const float*)d_in[10];
    const float* vb     = (const float*)d_in[11];
    const float* oW     = (const float*)d_in[12];
    const float* ob     = (const float*)d_in[13];
    const float* scale  = (const float*)d_in[14];
    const float* td     = (const float*)d_in[15];
    const float* ln1g   = (const float*)d_in[16];
    const float* ln1b   = (const float*)d_in[17];
    const float* f1W    = (const float*)d_in[18];
    const float* f1b    = (const float*)d_in[19];
    const float* f2W    = (const float*)d_in[20];
    const float* f2b    = (const float*)d_in[21];
    const float* ln2g   = (const float*)d_in[22];
    const float* ln2b   = (const float*)d_in[23];
    const float* outW   = (const float*)d_in[24];
    const float* outb   = (const float*)d_in[25];
    float* out = (float*)d_out;

    float* ws = (float*)d_ws;
    const size_t MT = (size_t)B_ * SEQ_ * D_;      // 1,048,576
    float* h     = ws;                             // MT fp32
    float* vpart = ws + MT;                        // 64*256 fp32
    unsigned short* bfb = (unsigned short*)(ws + MT + 64 * 256);
    unsigned short* h_bf   = bfb;
    unsigned short* ctx_bf = bfb + MT;
    unsigned short* q_bf   = bfb + 2 * MT;
    unsigned short* k_bf   = bfb + 3 * MT;
    unsigned short* v_bf   = bfb + 4 * MT;
    unsigned short* wq_bf  = bfb + 5 * MT;
    unsigned short* wk_bf  = wq_bf + MT / 8;
    unsigned short* wv_bf  = wk_bf + MT / 8;
    unsigned short* wo_bf  = wv_bf + MT / 8;
    unsigned short* wf1_bf = wo_bf + MT / 8;
    unsigned short* wf2_bf = wf1_bf + MT / 2;

    const int Mrows = B_ * SEQ_;                   // 4096

    prep_kernel<<<768 + (B_ * SEQ_ * D_) / 256, 256, 0, stream>>>(
        x, conv_w, conv_b, bn_g, bn_b, pe, h, h_bf,
        qW, kW, vW, oW, f1W, f2W,
        wq_bf, wk_bf, wv_bf, wo_bf, wf1_bf, wf2_bf);

    for (int l = 0; l < L_; ++l) {
        const unsigned short* wq_l  = wq_bf  + (size_t)l * D_ * D_;
        const unsigned short* wk_l  = wk_bf  + (size_t)l * D_ * D_;
        const unsigned short* wv_l  = wv_bf  + (size_t)l * D_ * D_;
        const unsigned short* wo_l  = wo_bf  + (size_t)l * D_ * D_;
        const unsigned short* wf1_l = wf1_bf + (size_t)l * DFF_ * D_;
        const unsigned short* wf2_l = wf2_bf + (size_t)l * DFF_ * D_;

        gemm_qkv<<<dim3(D_ / 64, Mrows / 64, 3), 256, 0, stream>>>(
            h_bf, wq_l, wk_l, wv_l, qb + l * D_, kb + l * D_, vb + l * D_,
            q_bf, k_bf, v_bf, td + l * H_, vpart, Mrows, D_, D_);

        attn_kernel<<<dim3(SEQ_ / 32, H_, B_), 128, 0, stream>>>(
            q_bf, k_bf, v_bf, vpart, ctx_bf, scale + l, td + l * H_);

        post_kernel<<<Mrows / 16, 256, 0, stream>>>(
            ctx_bf, wo_l, ob + l * D_, h,
            ln1g + l * D_, ln1b + l * D_,
            wf1_l, f1b + l * DFF_,
            wf2_l, f2b + l * D_,
            ln2g + l * D_, ln2b + l * D_,
            h, h_bf, outW, outb, out, (l == L_ - 1) ? 1 : 0);
    }
}

// Round 9
// 210.150 us; speedup vs baseline: 1.4794x; 1.0660x over previous
//
#include <hip/hip_runtime.h>
#include <math.h>

#define B_    2
#define SEQ_  2048
#define D_    256
#define H_    8
#define DK_   32
#define L_    2
#define DFF_  1024

#define TD_CUT 44.0f

typedef short  bf16x8 __attribute__((ext_vector_type(8)));
typedef float  f32x4  __attribute__((ext_vector_type(4)));

__device__ __forceinline__ int compute_kcut(float tdv) {
    int kcut = SEQ_;
    if (tdv > 1e-9f) {
        float kc = TD_CUT / tdv;
        kcut = (kc >= (float)SEQ_) ? SEQ_ : ((int)kc + 1);
    }
    int kcr = (kcut + 31) & ~31;
    if (kcr > SEQ_) kcr = SEQ_;
    return kcr;
}

__device__ __forceinline__ unsigned short f2bf(float f) {
    unsigned int u = __float_as_uint(f);
    unsigned int r = u + 0x7FFFu + ((u >> 16) & 1u);   // RNE
    return (unsigned short)(r >> 16);
}
__device__ __forceinline__ float bf2f(unsigned short u) {
    return __uint_as_float(((unsigned int)u) << 16);
}

__device__ __forceinline__ void gload_lds16(const unsigned short* g, unsigned short* l) {
    __builtin_amdgcn_global_load_lds(
        (const __attribute__((address_space(1))) unsigned int*)(const unsigned int*)g,
        (__attribute__((address_space(3))) unsigned int*)(unsigned int*)l,
        16, 0, 0);
}

// ---------------------------------------------------------------------------
// Kernel 1: prep = weight fp32->bf16 convert (blocks 0..767) + conv/pe (rest)
// ---------------------------------------------------------------------------
__global__ __launch_bounds__(256) void prep_kernel(
    const float* __restrict__ x, const float* __restrict__ w,
    const float* __restrict__ cb, const float* __restrict__ bg,
    const float* __restrict__ bb, const float* __restrict__ pe,
    float* __restrict__ h, unsigned short* __restrict__ hbf,
    const float* __restrict__ p0, const float* __restrict__ p1,
    const float* __restrict__ p2, const float* __restrict__ p3,
    const float* __restrict__ p4, const float* __restrict__ p5,
    unsigned short* __restrict__ q0, unsigned short* __restrict__ q1,
    unsigned short* __restrict__ q2, unsigned short* __restrict__ q3,
    unsigned short* __restrict__ q4, unsigned short* __restrict__ q5)
{
    int bid = blockIdx.x;
    if (bid < 768) {                              // ---- cvt path
        int t = bid * 256 + threadIdx.x;
        const float* src; unsigned short* dst; int base;
        if (t < 65536) {
            int a = t >> 14;
            src = a == 0 ? p0 : a == 1 ? p1 : a == 2 ? p2 : p3;
            dst = a == 0 ? q0 : a == 1 ? q1 : a == 2 ? q2 : q3;
            base = (t & 16383) * 8;
        } else {
            int u = t - 65536;
            int a = u >> 16;
            src = a ? p5 : p4;
            dst = a ? q5 : q4;
            base = (u & 65535) * 8;
        }
        float4 v0 = *(const float4*)(src + base);
        float4 v1 = *(const float4*)(src + base + 4);
        bf16x8 o;
        o[0] = (short)f2bf(v0.x); o[1] = (short)f2bf(v0.y);
        o[2] = (short)f2bf(v0.z); o[3] = (short)f2bf(v0.w);
        o[4] = (short)f2bf(v1.x); o[5] = (short)f2bf(v1.y);
        o[6] = (short)f2bf(v1.z); o[7] = (short)f2bf(v1.w);
        *(bf16x8*)(dst + base) = o;
        return;
    }
    // ---- conv path
    int idx = (bid - 768) * 256 + threadIdx.x;    // b*SEQ*D + s*D + d
    int d = idx & 255;
    int s = (idx >> 8) & 2047;
    int b = idx >> 19;

    const float* xp = x + b * SEQ_;
    float xm1 = (s > 0)        ? xp[s - 1] : 0.f;
    float x0  = xp[s];
    float xp1 = (s < SEQ_ - 1) ? xp[s + 1] : 0.f;

    float acc = xm1 * w[d * 3 + 0] + x0 * w[d * 3 + 1] + xp1 * w[d * 3 + 2];
    acc += cb[d];
    acc = acc * rsqrtf(1.f + 1e-5f) * bg[d] + bb[d];
    acc = fmaxf(acc, 0.f);
    float v = acc + pe[s * D_ + d];
    h[idx] = v;
    hbf[idx] = f2bf(v);
}

// ---------------------------------------------------------------------------
// Kernel 2: q/k/v GEMM (bf16 in/out) + fused vtail partial sums for V (z==2).
// ---------------------------------------------------------------------------
__global__ __launch_bounds__(256) void gemm_qkv(
    const unsigned short* __restrict__ A,
    const unsigned short* __restrict__ W0, const unsigned short* __restrict__ W1,
    const unsigned short* __restrict__ W2,
    const float* __restrict__ b0, const float* __restrict__ b1,
    const float* __restrict__ b2,
    unsigned short* __restrict__ O0, unsigned short* __restrict__ O1,
    unsigned short* __restrict__ O2,
    const float* __restrict__ td_l, float* __restrict__ vpart,
    int M, int N, int K)
{
    int z = blockIdx.z;
    const unsigned short* W = (z == 0) ? W0 : (z == 1) ? W1 : W2;
    const float* bias = (z == 0) ? b0 : (z == 1) ? b1 : b2;
    unsigned short* C = (z == 0) ? O0 : (z == 1) ? O1 : O2;

    __shared__ unsigned short As[64 * 32];
    __shared__ unsigned short Bs[64 * 32];
    __shared__ float vsc[4][2][16];

    int tid  = threadIdx.x;
    int wave = tid >> 6, lane = tid & 63;
    int wm = (wave & 1) * 32, wn = (wave >> 1) * 32;
    int bm = blockIdx.y * 64, bn = blockIdx.x * 64;

    int sr  = tid >> 2;
    int scb = (tid & 3) ^ ((sr >> 1) & 3);
    const unsigned short* aG = A + (size_t)(bm + sr) * K + scb * 8;
    const unsigned short* wG = W + (size_t)(bn + sr) * K + scb * 8;
    unsigned short* aL = &As[tid * 8];
    unsigned short* bL = &Bs[tid * 8];

    int fr = lane & 15;
    int kb = lane >> 4;
    int cb = (kb ^ ((fr >> 1) & 3)) * 8;
    int oA0 = (wm + fr) * 32 + cb;
    int oA1 = (wm + 16 + fr) * 32 + cb;
    int oB0 = (wn + fr) * 32 + cb;
    int oB1 = (wn + 16 + fr) * 32 + cb;

    f32x4 acc[2][2];
#pragma unroll
    for (int i = 0; i < 2; ++i)
#pragma unroll
        for (int j = 0; j < 2; ++j) acc[i][j] = (f32x4){0.f, 0.f, 0.f, 0.f};

    for (int k0 = 0; k0 < K; k0 += 32) {
        __syncthreads();
        gload_lds16(aG + k0, aL);
        gload_lds16(wG + k0, bL);
        __syncthreads();

        bf16x8 a0f = *(const bf16x8*)&As[oA0];
        bf16x8 a1f = *(const bf16x8*)&As[oA1];
        bf16x8 b0f = *(const bf16x8*)&Bs[oB0];
        bf16x8 b1f = *(const bf16x8*)&Bs[oB1];

        acc[0][0] = __builtin_amdgcn_mfma_f32_16x16x32_bf16(a0f, b0f, acc[0][0], 0, 0, 0);
        acc[0][1] = __builtin_amdgcn_mfma_f32_16x16x32_bf16(a0f, b1f, acc[0][1], 0, 0, 0);
        acc[1][0] = __builtin_amdgcn_mfma_f32_16x16x32_bf16(a1f, b0f, acc[1][0], 0, 0, 0);
        acc[1][1] = __builtin_amdgcn_mfma_f32_16x16x32_bf16(a1f, b1f, acc[1][1], 0, 0, 0);
    }

    int crow = (lane >> 4) * 4;
    int ccol = lane & 15;
    float psum[2] = {0.f, 0.f};
    int kc[2];
    kc[0] = compute_kcut(td_l[(bn + wn) >> 5]);
    kc[1] = compute_kcut(td_l[(bn + wn + 16) >> 5]);

#pragma unroll
    for (int j = 0; j < 2; ++j) {
        float bj = bias[bn + wn + j * 16 + ccol];
#pragma unroll
        for (int i = 0; i < 2; ++i) {
#pragma unroll
            for (int r = 0; r < 4; ++r) {
                float v = acc[i][j][r] + bj;
                unsigned short ubf = f2bf(v);
                C[(size_t)(bm + wm + i * 16 + crow + r) * N + bn + wn + j * 16 + ccol] = ubf;
                if (z == 2) {
                    int srow = (bm + wm + i * 16 + crow + r) & 2047;
                    if (srow >= kc[j]) psum[j] += bf2f(ubf);
                }
            }
        }
    }

    if (z == 2) {
#pragma unroll
        for (int j = 0; j < 2; ++j) {
            psum[j] += __shfl_xor(psum[j], 16);
            psum[j] += __shfl_xor(psum[j], 32);
        }
        if (lane < 16) { vsc[wave][0][lane] = psum[0]; vsc[wave][1][lane] = psum[1]; }
        __syncthreads();
        if (tid < 64) {
            int wh = tid >> 5, jj = (tid >> 4) & 1, cc = tid & 15;
            float s = vsc[2 * wh][jj][cc] + vsc[2 * wh + 1][jj][cc];
            vpart[(size_t)blockIdx.y * 256 + bn + wh * 32 + jj * 16 + cc] = s;
        }
    }
}

// ---------------------------------------------------------------------------
// Kernel 3: decay-truncated flash attention, 4-way key-split + LDS merge.
// ---------------------------------------------------------------------------
__global__ __launch_bounds__(128) void attn_kernel(
    const unsigned short* __restrict__ q, const unsigned short* __restrict__ k,
    const unsigned short* __restrict__ v, const float* __restrict__ vpart,
    unsigned short* __restrict__ ctxbf,
    const float* __restrict__ scale_p, const float* __restrict__ td_l)
{
    int b = blockIdx.z, hh = blockIdx.y;
    int tid = threadIdx.x;
    int row = tid >> 2;
    int sp  = tid & 3;
    int qrow = blockIdx.x * 32 + row;

    float sc  = 0.17677669529663687f * scale_p[0];
    float tdv = td_l[hh];
    int kcr = compute_kcut(tdv);
    int ntiles = kcr >> 5;

    __shared__ float kt[32][36];
    __shared__ float vt[32][36];
    __shared__ float Os[4][32][36];
    __shared__ float ms[4][32], ls[4][32];
    __shared__ float vtmp[4][32];

    {
        int d = tid & 31, gq = tid >> 5;
        float s = 0.f;
        for (int rb = gq; rb < 32; rb += 4)
            s += vpart[(size_t)(b * 32 + rb) * 256 + hh * 32 + d];
        vtmp[gq][d] = s;
    }

    const unsigned short* qptr = q + ((size_t)(b * SEQ_ + qrow)) * D_ + hh * DK_;
    float qreg[32];
#pragma unroll
    for (int j = 0; j < 4; ++j) {
        uint4 u = ((const uint4*)qptr)[j];
        qreg[j*8+0] = __uint_as_float(u.x << 16); qreg[j*8+1] = __uint_as_float(u.x & 0xFFFF0000u);
        qreg[j*8+2] = __uint_as_float(u.y << 16); qreg[j*8+3] = __uint_as_float(u.y & 0xFFFF0000u);
        qreg[j*8+4] = __uint_as_float(u.z << 16); qreg[j*8+5] = __uint_as_float(u.z & 0xFFFF0000u);
        qreg[j*8+6] = __uint_as_float(u.w << 16); qreg[j*8+7] = __uint_as_float(u.w & 0xFFFF0000u);
    }
    float O[32];
#pragma unroll
    for (int d = 0; d < 32; ++d) O[d] = 0.f;
    float mrun = -1e30f, lrun = 0.f;

    for (int t = 0; t < ntiles; ++t) {
        int k0 = t * 32;
        __syncthreads();
        {
            int r = tid >> 2, c8 = (tid & 3) * 8;
            size_t goff = ((size_t)(b * SEQ_ + k0 + r)) * D_ + hh * DK_ + c8;
            uint4 uk = *(const uint4*)(k + goff);
            uint4 uv = *(const uint4*)(v + goff);
            *(float4*)&kt[r][c8]     = make_float4(__uint_as_float(uk.x << 16), __uint_as_float(uk.x & 0xFFFF0000u),
                                                   __uint_as_float(uk.y << 16), __uint_as_float(uk.y & 0xFFFF0000u));
            *(float4*)&kt[r][c8 + 4] = make_float4(__uint_as_float(uk.z << 16), __uint_as_float(uk.z & 0xFFFF0000u),
                                                   __uint_as_float(uk.w << 16), __uint_as_float(uk.w & 0xFFFF0000u));
            *(float4*)&vt[r][c8]     = make_float4(__uint_as_float(uv.x << 16), __uint_as_float(uv.x & 0xFFFF0000u),
                                                   __uint_as_float(uv.y << 16), __uint_as_float(uv.y & 0xFFFF0000u));
            *(float4*)&vt[r][c8 + 4] = make_float4(__uint_as_float(uv.z << 16), __uint_as_float(uv.z & 0xFFFF0000u),
                                                   __uint_as_float(uv.w << 16), __uint_as_float(uv.w & 0xFFFF0000u));
        }
        __syncthreads();

        float sb[8];
        float tmax = -1e30f;
#pragma unroll
        for (int kk = 0; kk < 8; ++kk) {
            int kl = sp * 8 + kk;
            float acc = 0.f;
#pragma unroll
            for (int d4 = 0; d4 < 8; ++d4) {
                float4 kv = *(const float4*)&kt[kl][d4 * 4];
                acc += qreg[d4 * 4 + 0] * kv.x + qreg[d4 * 4 + 1] * kv.y
                     + qreg[d4 * 4 + 2] * kv.z + qreg[d4 * 4 + 3] * kv.w;
            }
            float dec = __expf(-tdv * (float)(k0 + kl));
            float sv = acc * sc * dec;
            sb[kk] = sv;
            tmax = fmaxf(tmax, sv);
        }
        float mnew = fmaxf(mrun, tmax);
        float alpha = __expf(mrun - mnew);
        lrun *= alpha;
#pragma unroll
        for (int d = 0; d < 32; ++d) O[d] *= alpha;
#pragma unroll
        for (int kk = 0; kk < 8; ++kk) {
            int kl = sp * 8 + kk;
            float sv = sb[kk];
            float e = __expf(sv - mnew);
            float sg = 1.f / (1.f + __expf(-sv));
            float p = e * sg;
            lrun += e;
#pragma unroll
            for (int d4 = 0; d4 < 8; ++d4) {
                float4 vv = *(const float4*)&vt[kl][d4 * 4];
                O[d4 * 4 + 0] += p * vv.x; O[d4 * 4 + 1] += p * vv.y;
                O[d4 * 4 + 2] += p * vv.z; O[d4 * 4 + 3] += p * vv.w;
            }
        }
        mrun = mnew;
    }

#pragma unroll
    for (int d4 = 0; d4 < 8; ++d4)
        *(float4*)&Os[sp][row][d4 * 4] =
            make_float4(O[d4*4+0], O[d4*4+1], O[d4*4+2], O[d4*4+3]);
    ms[sp][row] = mrun;
    ls[sp][row] = lrun;
    __syncthreads();

    {
        int g = sp;
        float m0 = fmaxf(fmaxf(ms[0][row], ms[1][row]), fmaxf(ms[2][row], ms[3][row]));
        float mt = (kcr < SEQ_) ? fmaxf(m0, 0.f) : m0;
        float w0 = __expf(ms[0][row] - mt), w1 = __expf(ms[1][row] - mt);
        float w2 = __expf(ms[2][row] - mt), w3 = __expf(ms[3][row] - mt);
        float Lt = ls[0][row]*w0 + ls[1][row]*w1 + ls[2][row]*w2 + ls[3][row]*w3;
        float ew = 0.f;
        if (kcr < SEQ_) {
            ew = __expf(-mt);
            Lt += (float)(SEQ_ - kcr) * ew;
        }
        float invL = 1.f / Lt;
        unsigned int packed[4];
#pragma unroll
        for (int dd = 0; dd < 8; dd += 2) {
            int d0 = g * 8 + dd, d1 = d0 + 1;
            float n0 = Os[0][row][d0]*w0 + Os[1][row][d0]*w1 + Os[2][row][d0]*w2 + Os[3][row][d0]*w3;
            float n1 = Os[0][row][d1]*w0 + Os[1][row][d1]*w1 + Os[2][row][d1]*w2 + Os[3][row][d1]*w3;
            if (kcr < SEQ_) {
                float vt0 = vtmp[0][d0] + vtmp[1][d0] + vtmp[2][d0] + vtmp[3][d0];
                float vt1 = vtmp[0][d1] + vtmp[1][d1] + vtmp[2][d1] + vtmp[3][d1];
                n0 += 0.5f * ew * vt0; n1 += 0.5f * ew * vt1;
            }
            packed[dd >> 1] = (unsigned)f2bf(n0 * invL) | ((unsigned)f2bf(n1 * invL) << 16);
        }
        unsigned short* obf = ctxbf + ((size_t)(b * SEQ_ + qrow)) * D_ + hh * DK_ + g * 8;
        *(uint4*)obf = make_uint4(packed[0], packed[1], packed[2], packed[3]);
    }
}

// ---------------------------------------------------------------------------
// Kernel 4: o-proj + residual + LN1. Block = 16 rows x 256 cols, grid M/16.
// Stages only 128 KB of wo per block (K=256, 8 steps of 16 KB).
// ---------------------------------------------------------------------------
__global__ __launch_bounds__(256) void oproj_ln1(
    const unsigned short* __restrict__ ctx, const unsigned short* __restrict__ wo,
    const float* __restrict__ ob, const float* __restrict__ resid,
    const float* __restrict__ g1, const float* __restrict__ bt1,
    float* __restrict__ h1out, unsigned short* __restrict__ h1bf)
{
    __shared__ unsigned short As[16 * 32];      // 64 slots
    __shared__ unsigned short Bs[256 * 32];     // 1024 slots
    __shared__ float lsum[4][16], lsq[4][16], mean_s[16], inv_s[16];

    int tid = threadIdx.x;
    int wave = tid >> 6, lane = tid & 63;
    int bm = blockIdx.x * 16;
    int fr = lane & 15, kb = lane >> 4;
    int q = kb, cl = fr;
    int swz = (fr >> 1) & 3;

    const unsigned short* gpB[4];
    unsigned short* lpB[4];
#pragma unroll
    for (int i = 0; i < 4; ++i) {
        int sB = i * 256 + tid;
        int r = sB >> 2, ck = (sB & 3) ^ ((r >> 1) & 3);
        gpB[i] = wo + (size_t)r * 256 + ck * 8;
        lpB[i] = &Bs[sB * 8];
    }
    const unsigned short* gpA = nullptr;
    unsigned short* lpA = nullptr;
    if (tid < 64) {
        int r = tid >> 2, ck = (tid & 3) ^ ((r >> 1) & 3);
        gpA = ctx + (size_t)(bm + r) * 256 + ck * 8;
        lpA = &As[tid * 8];
    }

    int oA = fr * 32 + ((kb ^ swz) * 8);
    int oB[4];
#pragma unroll
    for (int t = 0; t < 4; ++t) {
        int n = wave * 64 + t * 16 + fr;
        oB[t] = n * 32 + ((kb ^ swz) * 8);
    }

    f32x4 acc[4];
#pragma unroll
    for (int j = 0; j < 4; ++j) acc[j] = (f32x4){0.f, 0.f, 0.f, 0.f};

    for (int k0 = 0; k0 < 256; k0 += 32) {
        __syncthreads();
#pragma unroll
        for (int i = 0; i < 4; ++i) gload_lds16(gpB[i] + k0, lpB[i]);
        if (tid < 64) gload_lds16(gpA + k0, lpA);
        __syncthreads();

        bf16x8 af = *(const bf16x8*)&As[oA];
#pragma unroll
        for (int j = 0; j < 4; ++j)
            acc[j] = __builtin_amdgcn_mfma_f32_16x16x32_bf16(
                af, *(const bf16x8*)&Bs[oB[j]], acc[j], 0, 0, 0);
    }

    // z = acc + bias + resid; LN over the 256-col row
    float zsum[4] = {0.f, 0.f, 0.f, 0.f}, zsq[4] = {0.f, 0.f, 0.f, 0.f};
    float zv[4][4];
#pragma unroll
    for (int ct = 0; ct < 4; ++ct) {
        int col = wave * 64 + ct * 16 + cl;
        float bj = ob[col];
#pragma unroll
        for (int r = 0; r < 4; ++r) {
            int row = bm + q * 4 + r;
            float z = acc[ct][r] + bj + resid[(size_t)row * 256 + col];
            zv[ct][r] = z;
            zsum[r] += z;
            zsq[r]  += z * z;
        }
    }
#pragma unroll
    for (int r = 0; r < 4; ++r) {
#pragma unroll
        for (int off = 1; off < 16; off <<= 1) {
            zsum[r] += __shfl_xor(zsum[r], off);
            zsq[r]  += __shfl_xor(zsq[r], off);
        }
    }
    if (cl == 0) {
#pragma unroll
        for (int r = 0; r < 4; ++r) {
            lsum[wave][q * 4 + r] = zsum[r];
            lsq[wave][q * 4 + r]  = zsq[r];
        }
    }
    __syncthreads();
    if (tid < 16) {
        float s  = lsum[0][tid] + lsum[1][tid] + lsum[2][tid] + lsum[3][tid];
        float sq = lsq[0][tid] + lsq[1][tid] + lsq[2][tid] + lsq[3][tid];
        float mean = s * (1.f / 256.f);
        float var  = sq * (1.f / 256.f) - mean * mean;
        mean_s[tid] = mean;
        inv_s[tid]  = rsqrtf(var + 1e-5f);
    }
    __syncthreads();

#pragma unroll
    for (int ct = 0; ct < 4; ++ct) {
        int col = wave * 64 + ct * 16 + cl;
        float gc = g1[col], bc = bt1[col];
#pragma unroll
        for (int r = 0; r < 4; ++r) {
            int lr = q * 4 + r;
            float o = (zv[ct][r] - mean_s[lr]) * inv_s[lr] * gc + bc;
            size_t off = (size_t)(bm + lr) * 256 + col;
            h1out[off] = o;
            h1bf[off]  = f2bf(o);
        }
    }
}

// ---------------------------------------------------------------------------
// Kernel 5: fused FFN chunk. Block = 64 rows x 256-of-1024 ff-cols.
// grid (4 chunks, M/64): ff = relu(h1@w1c^T + f1b_c) kept in LDS, then
// part[c] = ff @ w2c^T (FFN2 K-chunk partial, fp32, no bias).
// ---------------------------------------------------------------------------
__global__ __launch_bounds__(256) void ffn_fused(
    const unsigned short* __restrict__ h1bf, const unsigned short* __restrict__ w1,
    const float* __restrict__ f1b, const unsigned short* __restrict__ w2,
    float* __restrict__ part)
{
    __shared__ unsigned short As[64 * 32];      // 256 slots (h1 K-slab)
    __shared__ unsigned short Bs[256 * 32];     // 1024 slots (weight K-slab)
    __shared__ unsigned short ffs[64 * 264];    // relu chunk, bf16

    int tid = threadIdx.x;
    int wave = tid >> 6, lane = tid & 63;
    int c = blockIdx.x;           // ff-chunk 0..3
    int bm = blockIdx.y * 64;
    int fr = lane & 15, kb = lane >> 4;
    int q = kb, cl = fr;
    int swz = (fr >> 1) & 3;

    // A staging (1 slot/thread)
    int ar = tid >> 2, ack = (tid & 3) ^ ((ar >> 1) & 3);
    const unsigned short* gA = h1bf + (size_t)(bm + ar) * 256 + ack * 8;
    unsigned short* lA = &As[tid * 8];

    int oA[4], oB[4];
#pragma unroll
    for (int t = 0; t < 4; ++t) {
        oA[t] = (t * 16 + fr) * 32 + ((kb ^ swz) * 8);
        int n = wave * 64 + t * 16 + fr;
        oB[t] = n * 32 + ((kb ^ swz) * 8);
    }

    // ---------- Phase 1: ff = relu(h1 @ w1c^T + f1b_c) ----------
    f32x4 a1[4][4];
#pragma unroll
    for (int i = 0; i < 4; ++i)
#pragma unroll
        for (int j = 0; j < 4; ++j) a1[i][j] = (f32x4){0.f, 0.f, 0.f, 0.f};

    for (int ks = 0; ks < 8; ++ks) {
        __syncthreads();
        gload_lds16(gA + ks * 32, lA);
#pragma unroll
        for (int i = 0; i < 4; ++i) {
            int sB = i * 256 + tid;
            int r = sB >> 2, ck = (sB & 3) ^ ((r >> 1) & 3);
            gload_lds16(w1 + (size_t)(c * 256 + r) * 256 + ks * 32 + ck * 8, &Bs[sB * 8]);
        }
        __syncthreads();

        bf16x8 af[4], bf[4];
#pragma unroll
        for (int t = 0; t < 4; ++t) af[t] = *(const bf16x8*)&As[oA[t]];
#pragma unroll
        for (int t = 0; t < 4; ++t) bf[t] = *(const bf16x8*)&Bs[oB[t]];
#pragma unroll
        for (int i = 0; i < 4; ++i)
#pragma unroll
            for (int j = 0; j < 4; ++j)
                a1[i][j] = __builtin_amdgcn_mfma_f32_16x16x32_bf16(af[i], bf[j], a1[i][j], 0, 0, 0);
    }

    // relu + bias -> ffs (local 64 x 256 bf16)
#pragma unroll
    for (int ct = 0; ct < 4; ++ct) {
        int col = wave * 64 + ct * 16 + cl;
        float bj = f1b[c * 256 + col];
#pragma unroll
        for (int rt = 0; rt < 4; ++rt)
#pragma unroll
            for (int r = 0; r < 4; ++r) {
                float v = fmaxf(a1[rt][ct][r] + bj, 0.f);
                ffs[(rt * 16 + q * 4 + r) * 264 + col] = f2bf(v);
            }
    }

    // ---------- Phase 2: part_c = ff @ w2c^T ----------
    f32x4 a2[4][4];
#pragma unroll
    for (int i = 0; i < 4; ++i)
#pragma unroll
        for (int j = 0; j < 4; ++j) a2[i][j] = (f32x4){0.f, 0.f, 0.f, 0.f};

    for (int ks = 0; ks < 8; ++ks) {
        __syncthreads();     // first iter: also makes ffs visible
#pragma unroll
        for (int i = 0; i < 4; ++i) {
            int sB = i * 256 + tid;
            int r = sB >> 2, ck = (sB & 3) ^ ((r >> 1) & 3);
            gload_lds16(w2 + (size_t)r * 1024 + c * 256 + ks * 32 + ck * 8, &Bs[sB * 8]);
        }
        __syncthreads();

        bf16x8 af[4], bf[4];
#pragma unroll
        for (int t = 0; t < 4; ++t)
            af[t] = *(const bf16x8*)&ffs[(t * 16 + fr) * 264 + ks * 32 + kb * 8];
#pragma unroll
        for (int t = 0; t < 4; ++t) bf[t] = *(const bf16x8*)&Bs[oB[t]];
#pragma unroll
        for (int i = 0; i < 4; ++i)
#pragma unroll
            for (int j = 0; j < 4; ++j)
                a2[i][j] = __builtin_amdgcn_mfma_f32_16x16x32_bf16(af[i], bf[j], a2[i][j], 0, 0, 0);
    }

    // write fp32 partials: part[c][row][col]
#pragma unroll
    for (int ct = 0; ct < 4; ++ct) {
        int col = wave * 64 + ct * 16 + cl;
#pragma unroll
        for (int rt = 0; rt < 4; ++rt)
#pragma unroll
            for (int r = 0; r < 4; ++r)
                part[((size_t)c * 4096 + bm + rt * 16 + q * 4 + r) * 256 + col] = a2[rt][ct][r];
    }
}

// ---------------------------------------------------------------------------
// Kernel 6: merge FFN2 partials + bias + h1 residual + LN2 (+final fold).
// Wave per row, 4 rows/block, grid M/4.
// ---------------------------------------------------------------------------
__global__ __launch_bounds__(256) void merge_ln2(
    const float* __restrict__ h1, const float* __restrict__ part,
    const float* __restrict__ f2b, const float* __restrict__ g2,
    const float* __restrict__ bt2,
    float* __restrict__ hout, unsigned short* __restrict__ hbf,
    const float* __restrict__ outW, const float* __restrict__ outb,
    float* __restrict__ out, int doFinal)
{
    int row = blockIdx.x * 4 + (threadIdx.x >> 6);
    int lane = threadIdx.x & 63;
    int d = lane * 4;

    float4 z = *(const float4*)(h1 + (size_t)row * 256 + d);
    float4 b4 = *(const float4*)(f2b + d);
    z.x += b4.x; z.y += b4.y; z.z += b4.z; z.w += b4.w;
#pragma unroll
    for (int c = 0; c < 4; ++c) {
        float4 p = *(const float4*)(part + ((size_t)c * 4096 + row) * 256 + d);
        z.x += p.x; z.y += p.y; z.z += p.z; z.w += p.w;
    }

    float s = z.x + z.y + z.z + z.w;
    float ss = z.x * z.x + z.y * z.y + z.z * z.z + z.w * z.w;
#pragma unroll
    for (int off = 1; off < 64; off <<= 1) {
        s += __shfl_xor(s, off);
        ss += __shfl_xor(ss, off);
    }
    float mean = s * (1.f / 256.f);
    float var = ss * (1.f / 256.f) - mean * mean;
    float inv = rsqrtf(var + 1e-5f);

    float4 g4 = *(const float4*)(g2 + d);
    float4 t4 = *(const float4*)(bt2 + d);
    float4 o;
    o.x = (z.x - mean) * inv * g4.x + t4.x;
    o.y = (z.y - mean) * inv * g4.y + t4.y;
    o.z = (z.z - mean) * inv * g4.z + t4.z;
    o.w = (z.w - mean) * inv * g4.w + t4.w;
    *(float4*)(hout + (size_t)row * 256 + d) = o;
    unsigned int u01 = (unsigned)f2bf(o.x) | ((unsigned)f2bf(o.y) << 16);
    unsigned int u23 = (unsigned)f2bf(o.z) | ((unsigned)f2bf(o.w) << 16);
    *(uint2*)&hbf[(size_t)row * 256 + d] = make_uint2(u01, u23);

    if (doFinal && (row == 2047 || row == 4095)) {
        float4 w4 = *(const float4*)(outW + d);
        float s2 = o.x * w4.x + o.y * w4.y + o.z * w4.z + o.w * w4.w;
#pragma unroll
        for (int off = 1; off < 64; off <<= 1) s2 += __shfl_xor(s2, off);
        if (lane == 0) out[row >> 11] = s2 * 0.5f + outb[0];
    }
}

// ---------------------------------------------------------------------------
extern "C" void kernel_launch(void* const* d_in, const int* in_sizes, int n_in,
                              void* d_out, int out_size, void* d_ws, size_t ws_size,
                              hipStream_t stream)
{
    (void)in_sizes; (void)n_in; (void)out_size; (void)ws_size;
    const float* x      = (const float*)d_in[0];
    const float* conv_w = (const float*)d_in[1];
    const float* conv_b = (const float*)d_in[2];
    const float* bn_g   = (const float*)d_in[3];
    const float* bn_b   = (const float*)d_in[4];
    const float* pe     = (const float*)d_in[5];
    const float* qW     = (const float*)d_in[6];
    const float* qb     = (const float*)d_in[7];
    const float* kW     = (const float*)d_in[8];
    const float* kb     = (const float*)d_in[9];
    const float* vW     = (const float*)d_in[10];
    const float* vb     = (const float*)d_in[11];
    const float* oW     = (const float*)d_in[12];
    const float* ob     = (const float*)d_in[13];
    const float* scale  = (const float*)d_in[14];
    const float* td     = (const float*)d_in[15];
    const float* ln1g   = (const float*)d_in[16];
    const float* ln1b   = (const float*)d_in[17];
    const float* f1W    = (const float*)d_in[18];
    const float* f1b    = (const float*)d_in[19];
    const float* f2W    = (const float*)d_in[20];
    const float* f2b    = (const float*)d_in[21];
    const float* ln2g   = (const float*)d_in[22];
    const float* ln2b   = (const float*)d_in[23];
    const float* outW   = (const float*)d_in[24];
    const float* outb   = (const float*)d_in[25];
    float* out = (float*)d_out;

    float* ws = (float*)d_ws;
    const size_t MT = (size_t)B_ * SEQ_ * D_;      // 1,048,576
    float* h     = ws;                             // MT fp32
    float* h1    = ws + MT;                        // MT fp32
    float* vpart = ws + 2 * MT;                    // 64*256 fp32
    float* part  = ws + 2 * MT + 16384;            // 4*MT fp32
    unsigned short* bfb = (unsigned short*)(ws + 6 * MT + 16384);
    unsigned short* h_bf   = bfb;
    unsigned short* ctx_bf = bfb + MT;
    unsigned short* q_bf   = bfb + 2 * MT;
    unsigned short* k_bf   = bfb + 3 * MT;
    unsigned short* v_bf   = bfb + 4 * MT;
    unsigned short* h1_bf  = bfb + 5 * MT;
    unsigned short* wq_bf  = bfb + 6 * MT;
    unsigned short* wk_bf  = wq_bf + MT / 8;
    unsigned short* wv_bf  = wk_bf + MT / 8;
    unsigned short* wo_bf  = wv_bf + MT / 8;
    unsigned short* wf1_bf = wo_bf + MT / 8;
    unsigned short* wf2_bf = wf1_bf + MT / 2;

    const int Mrows = B_ * SEQ_;                   // 4096

    prep_kernel<<<768 + (B_ * SEQ_ * D_) / 256, 256, 0, stream>>>(
        x, conv_w, conv_b, bn_g, bn_b, pe, h, h_bf,
        qW, kW, vW, oW, f1W, f2W,
        wq_bf, wk_bf, wv_bf, wo_bf, wf1_bf, wf2_bf);

    for (int l = 0; l < L_; ++l) {
        const unsigned short* wq_l  = wq_bf  + (size_t)l * D_ * D_;
        const unsigned short* wk_l  = wk_bf  + (size_t)l * D_ * D_;
        const unsigned short* wv_l  = wv_bf  + (size_t)l * D_ * D_;
        const unsigned short* wo_l  = wo_bf  + (size_t)l * D_ * D_;
        const unsigned short* wf1_l = wf1_bf + (size_t)l * DFF_ * D_;
        const unsigned short* wf2_l = wf2_bf + (size_t)l * DFF_ * D_;

        gemm_qkv<<<dim3(D_ / 64, Mrows / 64, 3), 256, 0, stream>>>(
            h_bf, wq_l, wk_l, wv_l, qb + l * D_, kb + l * D_, vb + l * D_,
            q_bf, k_bf, v_bf, td + l * H_, vpart, Mrows, D_, D_);

        attn_kernel<<<dim3(SEQ_ / 32, H_, B_), 128, 0, stream>>>(
            q_bf, k_bf, v_bf, vpart, ctx_bf, scale + l, td + l * H_);

        oproj_ln1<<<Mrows / 16, 256, 0, stream>>>(
            ctx_bf, wo_l, ob + l * D_, h,
            ln1g + l * D_, ln1b + l * D_, h1, h1_bf);

        ffn_fused<<<dim3(4, Mrows / 64), 256, 0, stream>>>(
            h1_bf, wf1_l, f1b + l * DFF_, wf2_l, part);

        merge_ln2<<<Mrows / 4, 256, 0, stream>>>(
            h1, part, f2b + l * D_, ln2g + l * D_, ln2b + l * D_,
            h, h_bf, outW, outb, out, (l == L_ - 1) ? 1 : 0);
    }
}

// Round 10
// 204.878 us; speedup vs baseline: 1.5175x; 1.0257x over previous
//
#include <hip/hip_runtime.h>
#include <math.h>

#define B_    2
#define SEQ_  2048
#define D_    256
#define H_    8
#define DK_   32
#define L_    2
#define DFF_  1024

#define TD_CUT 44.0f

typedef short  bf16x8 __attribute__((ext_vector_type(8)));
typedef float  f32x4  __attribute__((ext_vector_type(4)));

__device__ __forceinline__ int compute_kcut(float tdv) {
    int kcut = SEQ_;
    if (tdv > 1e-9f) {
        float kc = TD_CUT / tdv;
        kcut = (kc >= (float)SEQ_) ? SEQ_ : ((int)kc + 1);
    }
    int kcr = (kcut + 31) & ~31;
    if (kcr > SEQ_) kcr = SEQ_;
    return kcr;
}

__device__ __forceinline__ unsigned short f2bf(float f) {
    unsigned int u = __float_as_uint(f);
    unsigned int r = u + 0x7FFFu + ((u >> 16) & 1u);   // RNE
    return (unsigned short)(r >> 16);
}
__device__ __forceinline__ float bf2f(unsigned short u) {
    return __uint_as_float(((unsigned int)u) << 16);
}

__device__ __forceinline__ void gload_lds16(const unsigned short* g, unsigned short* l) {
    __builtin_amdgcn_global_load_lds(
        (const __attribute__((address_space(1))) unsigned int*)(const unsigned int*)g,
        (__attribute__((address_space(3))) unsigned int*)(unsigned int*)l,
        16, 0, 0);
}

// ---------------------------------------------------------------------------
// Kernel 1: prep = weight cvt (blocks 0..767) + conv/pe (rest) + vtail zero.
// ---------------------------------------------------------------------------
__global__ __launch_bounds__(256) void prep_kernel(
    const float* __restrict__ x, const float* __restrict__ w,
    const float* __restrict__ cb, const float* __restrict__ bg,
    const float* __restrict__ bb, const float* __restrict__ pe,
    float* __restrict__ h, unsigned short* __restrict__ hbf,
    const float* __restrict__ p0, const float* __restrict__ p1,
    const float* __restrict__ p2, const float* __restrict__ p3,
    const float* __restrict__ p4, const float* __restrict__ p5,
    unsigned short* __restrict__ q0, unsigned short* __restrict__ q1,
    unsigned short* __restrict__ q2, unsigned short* __restrict__ q3,
    unsigned short* __restrict__ q4, unsigned short* __restrict__ q5,
    float* __restrict__ vtail)
{
    int bid = blockIdx.x;
    if (bid < 4) vtail[bid * 256 + threadIdx.x] = 0.f;   // L*B*256 = 1024 floats
    if (bid < 768) {                              // ---- cvt path
        int t = bid * 256 + threadIdx.x;
        const float* src; unsigned short* dst; int base;
        if (t < 65536) {
            int a = t >> 14;
            src = a == 0 ? p0 : a == 1 ? p1 : a == 2 ? p2 : p3;
            dst = a == 0 ? q0 : a == 1 ? q1 : a == 2 ? q2 : q3;
            base = (t & 16383) * 8;
        } else {
            int u = t - 65536;
            int a = u >> 16;
            src = a ? p5 : p4;
            dst = a ? q5 : q4;
            base = (u & 65535) * 8;
        }
        float4 v0 = *(const float4*)(src + base);
        float4 v1 = *(const float4*)(src + base + 4);
        bf16x8 o;
        o[0] = (short)f2bf(v0.x); o[1] = (short)f2bf(v0.y);
        o[2] = (short)f2bf(v0.z); o[3] = (short)f2bf(v0.w);
        o[4] = (short)f2bf(v1.x); o[5] = (short)f2bf(v1.y);
        o[6] = (short)f2bf(v1.z); o[7] = (short)f2bf(v1.w);
        *(bf16x8*)(dst + base) = o;
        return;
    }
    // ---- conv path
    int idx = (bid - 768) * 256 + threadIdx.x;    // b*SEQ*D + s*D + d
    int d = idx & 255;
    int s = (idx >> 8) & 2047;
    int b = idx >> 19;

    const float* xp = x + b * SEQ_;
    float xm1 = (s > 0)        ? xp[s - 1] : 0.f;
    float x0  = xp[s];
    float xp1 = (s < SEQ_ - 1) ? xp[s + 1] : 0.f;

    float acc = xm1 * w[d * 3 + 0] + x0 * w[d * 3 + 1] + xp1 * w[d * 3 + 2];
    acc += cb[d];
    acc = acc * rsqrtf(1.f + 1e-5f) * bg[d] + bb[d];
    acc = fmaxf(acc, 0.f);
    float v = acc + pe[s * D_ + d];
    h[idx] = v;
    hbf[idx] = f2bf(v);
}

// ---------------------------------------------------------------------------
// Kernel 2: q/k/v GEMM (bf16 in/out); z==2 accumulates vtail[b][col] via
// device-scope atomicAdd (visible to attn at next dispatch boundary).
// ---------------------------------------------------------------------------
__global__ __launch_bounds__(256) void gemm_qkv(
    const unsigned short* __restrict__ A,
    const unsigned short* __restrict__ W0, const unsigned short* __restrict__ W1,
    const unsigned short* __restrict__ W2,
    const float* __restrict__ b0, const float* __restrict__ b1,
    const float* __restrict__ b2,
    unsigned short* __restrict__ O0, unsigned short* __restrict__ O1,
    unsigned short* __restrict__ O2,
    const float* __restrict__ td_l, float* __restrict__ vtail_l,
    int M, int N, int K)
{
    int z = blockIdx.z;
    const unsigned short* W = (z == 0) ? W0 : (z == 1) ? W1 : W2;
    const float* bias = (z == 0) ? b0 : (z == 1) ? b1 : b2;
    unsigned short* C = (z == 0) ? O0 : (z == 1) ? O1 : O2;

    __shared__ unsigned short As[64 * 32];
    __shared__ unsigned short Bs[64 * 32];
    __shared__ float vsc[4][2][16];

    int tid  = threadIdx.x;
    int wave = tid >> 6, lane = tid & 63;
    int wm = (wave & 1) * 32, wn = (wave >> 1) * 32;
    int bm = blockIdx.y * 64, bn = blockIdx.x * 64;

    int sr  = tid >> 2;
    int scb = (tid & 3) ^ ((sr >> 1) & 3);
    const unsigned short* aG = A + (size_t)(bm + sr) * K + scb * 8;
    const unsigned short* wG = W + (size_t)(bn + sr) * K + scb * 8;
    unsigned short* aL = &As[tid * 8];
    unsigned short* bL = &Bs[tid * 8];

    int fr = lane & 15;
    int kb = lane >> 4;
    int cb = (kb ^ ((fr >> 1) & 3)) * 8;
    int oA0 = (wm + fr) * 32 + cb;
    int oA1 = (wm + 16 + fr) * 32 + cb;
    int oB0 = (wn + fr) * 32 + cb;
    int oB1 = (wn + 16 + fr) * 32 + cb;

    f32x4 acc[2][2];
#pragma unroll
    for (int i = 0; i < 2; ++i)
#pragma unroll
        for (int j = 0; j < 2; ++j) acc[i][j] = (f32x4){0.f, 0.f, 0.f, 0.f};

    for (int k0 = 0; k0 < K; k0 += 32) {
        __syncthreads();
        gload_lds16(aG + k0, aL);
        gload_lds16(wG + k0, bL);
        __syncthreads();

        bf16x8 a0f = *(const bf16x8*)&As[oA0];
        bf16x8 a1f = *(const bf16x8*)&As[oA1];
        bf16x8 b0f = *(const bf16x8*)&Bs[oB0];
        bf16x8 b1f = *(const bf16x8*)&Bs[oB1];

        acc[0][0] = __builtin_amdgcn_mfma_f32_16x16x32_bf16(a0f, b0f, acc[0][0], 0, 0, 0);
        acc[0][1] = __builtin_amdgcn_mfma_f32_16x16x32_bf16(a0f, b1f, acc[0][1], 0, 0, 0);
        acc[1][0] = __builtin_amdgcn_mfma_f32_16x16x32_bf16(a1f, b0f, acc[1][0], 0, 0, 0);
        acc[1][1] = __builtin_amdgcn_mfma_f32_16x16x32_bf16(a1f, b1f, acc[1][1], 0, 0, 0);
    }

    int crow = (lane >> 4) * 4;
    int ccol = lane & 15;
    float psum[2] = {0.f, 0.f};
    int kc[2];
    kc[0] = compute_kcut(td_l[(bn + wn) >> 5]);
    kc[1] = compute_kcut(td_l[(bn + wn + 16) >> 5]);

#pragma unroll
    for (int j = 0; j < 2; ++j) {
        float bj = bias[bn + wn + j * 16 + ccol];
#pragma unroll
        for (int i = 0; i < 2; ++i) {
#pragma unroll
            for (int r = 0; r < 4; ++r) {
                float v = acc[i][j][r] + bj;
                unsigned short ubf = f2bf(v);
                C[(size_t)(bm + wm + i * 16 + crow + r) * N + bn + wn + j * 16 + ccol] = ubf;
                if (z == 2) {
                    int srow = (bm + wm + i * 16 + crow + r) & 2047;
                    if (srow >= kc[j]) psum[j] += bf2f(ubf);
                }
            }
        }
    }

    if (z == 2) {
#pragma unroll
        for (int j = 0; j < 2; ++j) {
            psum[j] += __shfl_xor(psum[j], 16);
            psum[j] += __shfl_xor(psum[j], 32);
        }
        if (lane < 16) { vsc[wave][0][lane] = psum[0]; vsc[wave][1][lane] = psum[1]; }
        __syncthreads();
        if (tid < 64) {
            int wh = tid >> 5, jj = (tid >> 4) & 1, cc = tid & 15;
            float s = vsc[2 * wh][jj][cc] + vsc[2 * wh + 1][jj][cc];
            int b = blockIdx.y >> 5;       // 64-row blocks, 2048 rows/batch
            atomicAdd(&vtail_l[b * 256 + bn + wh * 32 + jj * 16 + cc], s);
        }
    }
}

// ---------------------------------------------------------------------------
// Kernel 3: decay-truncated flash attention, 4-way key-split + LDS merge.
// vtail[b][256] precomputed by gemm_qkv.
// ---------------------------------------------------------------------------
__global__ __launch_bounds__(128) void attn_kernel(
    const unsigned short* __restrict__ q, const unsigned short* __restrict__ k,
    const unsigned short* __restrict__ v, const float* __restrict__ vtail_l,
    unsigned short* __restrict__ ctxbf,
    const float* __restrict__ scale_p, const float* __restrict__ td_l)
{
    int b = blockIdx.z, hh = blockIdx.y;
    int tid = threadIdx.x;
    int row = tid >> 2;
    int sp  = tid & 3;
    int qrow = blockIdx.x * 32 + row;

    float sc  = 0.17677669529663687f * scale_p[0];
    float tdv = td_l[hh];
    int kcr = compute_kcut(tdv);
    int ntiles = kcr >> 5;

    __shared__ float kt[32][36];
    __shared__ float vt[32][36];
    __shared__ float Os[4][32][36];
    __shared__ float ms[4][32], ls[4][32];
    __shared__ float vts[32];

    if (tid < 32) vts[tid] = vtail_l[b * 256 + hh * 32 + tid];

    const unsigned short* qptr = q + ((size_t)(b * SEQ_ + qrow)) * D_ + hh * DK_;
    float qreg[32];
#pragma unroll
    for (int j = 0; j < 4; ++j) {
        uint4 u = ((const uint4*)qptr)[j];
        qreg[j*8+0] = __uint_as_float(u.x << 16); qreg[j*8+1] = __uint_as_float(u.x & 0xFFFF0000u);
        qreg[j*8+2] = __uint_as_float(u.y << 16); qreg[j*8+3] = __uint_as_float(u.y & 0xFFFF0000u);
        qreg[j*8+4] = __uint_as_float(u.z << 16); qreg[j*8+5] = __uint_as_float(u.z & 0xFFFF0000u);
        qreg[j*8+6] = __uint_as_float(u.w << 16); qreg[j*8+7] = __uint_as_float(u.w & 0xFFFF0000u);
    }
    float O[32];
#pragma unroll
    for (int d = 0; d < 32; ++d) O[d] = 0.f;
    float mrun = -1e30f, lrun = 0.f;

    for (int t = 0; t < ntiles; ++t) {
        int k0 = t * 32;
        __syncthreads();
        {
            int r = tid >> 2, c8 = (tid & 3) * 8;
            size_t goff = ((size_t)(b * SEQ_ + k0 + r)) * D_ + hh * DK_ + c8;
            uint4 uk = *(const uint4*)(k + goff);
            uint4 uv = *(const uint4*)(v + goff);
            *(float4*)&kt[r][c8]     = make_float4(__uint_as_float(uk.x << 16), __uint_as_float(uk.x & 0xFFFF0000u),
                                                   __uint_as_float(uk.y << 16), __uint_as_float(uk.y & 0xFFFF0000u));
            *(float4*)&kt[r][c8 + 4] = make_float4(__uint_as_float(uk.z << 16), __uint_as_float(uk.z & 0xFFFF0000u),
                                                   __uint_as_float(uk.w << 16), __uint_as_float(uk.w & 0xFFFF0000u));
            *(float4*)&vt[r][c8]     = make_float4(__uint_as_float(uv.x << 16), __uint_as_float(uv.x & 0xFFFF0000u),
                                                   __uint_as_float(uv.y << 16), __uint_as_float(uv.y & 0xFFFF0000u));
            *(float4*)&vt[r][c8 + 4] = make_float4(__uint_as_float(uv.z << 16), __uint_as_float(uv.z & 0xFFFF0000u),
                                                   __uint_as_float(uv.w << 16), __uint_as_float(uv.w & 0xFFFF0000u));
        }
        __syncthreads();

        float sb[8];
        float tmax = -1e30f;
#pragma unroll
        for (int kk = 0; kk < 8; ++kk) {
            int kl = sp * 8 + kk;
            float acc = 0.f;
#pragma unroll
            for (int d4 = 0; d4 < 8; ++d4) {
                float4 kv = *(const float4*)&kt[kl][d4 * 4];
                acc += qreg[d4 * 4 + 0] * kv.x + qreg[d4 * 4 + 1] * kv.y
                     + qreg[d4 * 4 + 2] * kv.z + qreg[d4 * 4 + 3] * kv.w;
            }
            float dec = __expf(-tdv * (float)(k0 + kl));
            float sv = acc * sc * dec;
            sb[kk] = sv;
            tmax = fmaxf(tmax, sv);
        }
        float mnew = fmaxf(mrun, tmax);
        float alpha = __expf(mrun - mnew);
        lrun *= alpha;
#pragma unroll
        for (int d = 0; d < 32; ++d) O[d] *= alpha;
#pragma unroll
        for (int kk = 0; kk < 8; ++kk) {
            int kl = sp * 8 + kk;
            float sv = sb[kk];
            float e = __expf(sv - mnew);
            float sg = 1.f / (1.f + __expf(-sv));
            float p = e * sg;
            lrun += e;
#pragma unroll
            for (int d4 = 0; d4 < 8; ++d4) {
                float4 vv = *(const float4*)&vt[kl][d4 * 4];
                O[d4 * 4 + 0] += p * vv.x; O[d4 * 4 + 1] += p * vv.y;
                O[d4 * 4 + 2] += p * vv.z; O[d4 * 4 + 3] += p * vv.w;
            }
        }
        mrun = mnew;
    }

#pragma unroll
    for (int d4 = 0; d4 < 8; ++d4)
        *(float4*)&Os[sp][row][d4 * 4] =
            make_float4(O[d4*4+0], O[d4*4+1], O[d4*4+2], O[d4*4+3]);
    ms[sp][row] = mrun;
    ls[sp][row] = lrun;
    __syncthreads();

    {
        int g = sp;
        float m0 = fmaxf(fmaxf(ms[0][row], ms[1][row]), fmaxf(ms[2][row], ms[3][row]));
        float mt = (kcr < SEQ_) ? fmaxf(m0, 0.f) : m0;
        float w0 = __expf(ms[0][row] - mt), w1 = __expf(ms[1][row] - mt);
        float w2 = __expf(ms[2][row] - mt), w3 = __expf(ms[3][row] - mt);
        float Lt = ls[0][row]*w0 + ls[1][row]*w1 + ls[2][row]*w2 + ls[3][row]*w3;
        float ew = 0.f;
        if (kcr < SEQ_) {
            ew = __expf(-mt);
            Lt += (float)(SEQ_ - kcr) * ew;
        }
        float invL = 1.f / Lt;
        unsigned int packed[4];
#pragma unroll
        for (int dd = 0; dd < 8; dd += 2) {
            int d0 = g * 8 + dd, d1 = d0 + 1;
            float n0 = Os[0][row][d0]*w0 + Os[1][row][d0]*w1 + Os[2][row][d0]*w2 + Os[3][row][d0]*w3;
            float n1 = Os[0][row][d1]*w0 + Os[1][row][d1]*w1 + Os[2][row][d1]*w2 + Os[3][row][d1]*w3;
            if (kcr < SEQ_) {
                n0 += 0.5f * ew * vts[d0];
                n1 += 0.5f * ew * vts[d1];
            }
            packed[dd >> 1] = (unsigned)f2bf(n0 * invL) | ((unsigned)f2bf(n1 * invL) << 16);
        }
        unsigned short* obf = ctxbf + ((size_t)(b * SEQ_ + qrow)) * D_ + hh * DK_ + g * 8;
        *(uint4*)obf = make_uint4(packed[0], packed[1], packed[2], packed[3]);
    }
}

// ---------------------------------------------------------------------------
// Kernel 4: o-proj + residual + LN1. Block = 16 rows x 256 cols, grid M/16.
// ---------------------------------------------------------------------------
__global__ __launch_bounds__(256) void oproj_ln1(
    const unsigned short* __restrict__ ctx, const unsigned short* __restrict__ wo,
    const float* __restrict__ ob, const float* __restrict__ resid,
    const float* __restrict__ g1, const float* __restrict__ bt1,
    float* __restrict__ h1out, unsigned short* __restrict__ h1bf)
{
    __shared__ unsigned short As[16 * 32];      // 64 slots
    __shared__ unsigned short Bs[256 * 32];     // 1024 slots
    __shared__ float lsum[4][16], lsq[4][16], mean_s[16], inv_s[16];

    int tid = threadIdx.x;
    int wave = tid >> 6, lane = tid & 63;
    int bm = blockIdx.x * 16;
    int fr = lane & 15, kb = lane >> 4;
    int q = kb, cl = fr;
    int swz = (fr >> 1) & 3;

    const unsigned short* gpB[4];
    unsigned short* lpB[4];
#pragma unroll
    for (int i = 0; i < 4; ++i) {
        int sB = i * 256 + tid;
        int r = sB >> 2, ck = (sB & 3) ^ ((r >> 1) & 3);
        gpB[i] = wo + (size_t)r * 256 + ck * 8;
        lpB[i] = &Bs[sB * 8];
    }
    const unsigned short* gpA = nullptr;
    unsigned short* lpA = nullptr;
    if (tid < 64) {
        int r = tid >> 2, ck = (tid & 3) ^ ((r >> 1) & 3);
        gpA = ctx + (size_t)(bm + r) * 256 + ck * 8;
        lpA = &As[tid * 8];
    }

    int oA = fr * 32 + ((kb ^ swz) * 8);
    int oB[4];
#pragma unroll
    for (int t = 0; t < 4; ++t) {
        int n = wave * 64 + t * 16 + fr;
        oB[t] = n * 32 + ((kb ^ swz) * 8);
    }

    f32x4 acc[4];
#pragma unroll
    for (int j = 0; j < 4; ++j) acc[j] = (f32x4){0.f, 0.f, 0.f, 0.f};

    for (int k0 = 0; k0 < 256; k0 += 32) {
        __syncthreads();
#pragma unroll
        for (int i = 0; i < 4; ++i) gload_lds16(gpB[i] + k0, lpB[i]);
        if (tid < 64) gload_lds16(gpA + k0, lpA);
        __syncthreads();

        bf16x8 af = *(const bf16x8*)&As[oA];
#pragma unroll
        for (int j = 0; j < 4; ++j)
            acc[j] = __builtin_amdgcn_mfma_f32_16x16x32_bf16(
                af, *(const bf16x8*)&Bs[oB[j]], acc[j], 0, 0, 0);
    }

    float zsum[4] = {0.f, 0.f, 0.f, 0.f}, zsq[4] = {0.f, 0.f, 0.f, 0.f};
    float zv[4][4];
#pragma unroll
    for (int ct = 0; ct < 4; ++ct) {
        int col = wave * 64 + ct * 16 + cl;
        float bj = ob[col];
#pragma unroll
        for (int r = 0; r < 4; ++r) {
            int row = bm + q * 4 + r;
            float z = acc[ct][r] + bj + resid[(size_t)row * 256 + col];
            zv[ct][r] = z;
            zsum[r] += z;
            zsq[r]  += z * z;
        }
    }
#pragma unroll
    for (int r = 0; r < 4; ++r) {
#pragma unroll
        for (int off = 1; off < 16; off <<= 1) {
            zsum[r] += __shfl_xor(zsum[r], off);
            zsq[r]  += __shfl_xor(zsq[r], off);
        }
    }
    if (cl == 0) {
#pragma unroll
        for (int r = 0; r < 4; ++r) {
            lsum[wave][q * 4 + r] = zsum[r];
            lsq[wave][q * 4 + r]  = zsq[r];
        }
    }
    __syncthreads();
    if (tid < 16) {
        float s  = lsum[0][tid] + lsum[1][tid] + lsum[2][tid] + lsum[3][tid];
        float sq = lsq[0][tid] + lsq[1][tid] + lsq[2][tid] + lsq[3][tid];
        float mean = s * (1.f / 256.f);
        float var  = sq * (1.f / 256.f) - mean * mean;
        mean_s[tid] = mean;
        inv_s[tid]  = rsqrtf(var + 1e-5f);
    }
    __syncthreads();

#pragma unroll
    for (int ct = 0; ct < 4; ++ct) {
        int col = wave * 64 + ct * 16 + cl;
        float gc = g1[col], bc = bt1[col];
#pragma unroll
        for (int r = 0; r < 4; ++r) {
            int lr = q * 4 + r;
            float o = (zv[ct][r] - mean_s[lr]) * inv_s[lr] * gc + bc;
            size_t off = (size_t)(bm + lr) * 256 + col;
            h1out[off] = o;
            h1bf[off]  = f2bf(o);
        }
    }
}

// ---------------------------------------------------------------------------
// Kernel 5: fused FFN chunk. Block = 32 rows x 256-of-1024 ff-cols.
// grid (4, M/32) = 512 blocks -> 2+ blocks/CU for staging/compute overlap.
// Phase1: ff = relu(h1@w1c^T + f1b_c) -> LDS; Phase2: part[c] = ff @ w2c^T.
// ---------------------------------------------------------------------------
__global__ __launch_bounds__(256) void ffn_fused(
    const unsigned short* __restrict__ h1bf, const unsigned short* __restrict__ w1,
    const float* __restrict__ f1b, const unsigned short* __restrict__ w2,
    float* __restrict__ part)
{
    __shared__ unsigned short As[32 * 32];      // 128 slots (h1 K-slab)
    __shared__ unsigned short Bs[256 * 32];     // 1024 slots (weight K-slab)
    __shared__ unsigned short ffs[32 * 264];    // relu chunk, bf16 (16.5 KB)

    int tid = threadIdx.x;
    int wave = tid >> 6, lane = tid & 63;
    int c = blockIdx.x;           // ff-chunk 0..3
    int bm = blockIdx.y * 32;
    int fr = lane & 15, kb = lane >> 4;
    int q = kb, cl = fr;
    int swz = (fr >> 1) & 3;

    // A staging: 128 slots, threads < 128 take one
    const unsigned short* gA = nullptr;
    unsigned short* lA = nullptr;
    if (tid < 128) {
        int ar = tid >> 2, ack = (tid & 3) ^ ((ar >> 1) & 3);
        gA = h1bf + (size_t)(bm + ar) * 256 + ack * 8;
        lA = &As[tid * 8];
    }

    int oA1[2], oB[4];
#pragma unroll
    for (int t = 0; t < 2; ++t) {
        int m = t * 16 + fr;
        oA1[t] = m * 32 + ((kb ^ ((m >> 1) & 3)) * 8);
    }
#pragma unroll
    for (int t = 0; t < 4; ++t) {
        int n = wave * 64 + t * 16 + fr;
        oB[t] = n * 32 + ((kb ^ ((n >> 1) & 3)) * 8);
    }

    // ---------- Phase 1: ff = relu(h1 @ w1c^T + f1b_c) (32x256, K=256) -----
    f32x4 a1[2][4];
#pragma unroll
    for (int i = 0; i < 2; ++i)
#pragma unroll
        for (int j = 0; j < 4; ++j) a1[i][j] = (f32x4){0.f, 0.f, 0.f, 0.f};

    for (int ks = 0; ks < 8; ++ks) {
        __syncthreads();
        if (tid < 128) gload_lds16(gA + ks * 32, lA);
#pragma unroll
        for (int i = 0; i < 4; ++i) {
            int sB = i * 256 + tid;
            int r = sB >> 2, ck = (sB & 3) ^ ((r >> 1) & 3);
            gload_lds16(w1 + (size_t)(c * 256 + r) * 256 + ks * 32 + ck * 8, &Bs[sB * 8]);
        }
        __syncthreads();

        bf16x8 af[2], bfv[4];
#pragma unroll
        for (int t = 0; t < 2; ++t) af[t] = *(const bf16x8*)&As[oA1[t]];
#pragma unroll
        for (int t = 0; t < 4; ++t) bfv[t] = *(const bf16x8*)&Bs[oB[t]];
#pragma unroll
        for (int i = 0; i < 2; ++i)
#pragma unroll
            for (int j = 0; j < 4; ++j)
                a1[i][j] = __builtin_amdgcn_mfma_f32_16x16x32_bf16(af[i], bfv[j], a1[i][j], 0, 0, 0);
    }

    // relu + bias -> ffs (32 x 256 bf16, padded rows)
#pragma unroll
    for (int ct = 0; ct < 4; ++ct) {
        int col = wave * 64 + ct * 16 + cl;
        float bj = f1b[c * 256 + col];
#pragma unroll
        for (int rt = 0; rt < 2; ++rt)
#pragma unroll
            for (int r = 0; r < 4; ++r) {
                float v = fmaxf(a1[rt][ct][r] + bj, 0.f);
                ffs[(rt * 16 + q * 4 + r) * 264 + col] = f2bf(v);
            }
    }

    // ---------- Phase 2: part_c = ff @ w2c^T (32x256, K=256) ----------
    f32x4 a2[2][4];
#pragma unroll
    for (int i = 0; i < 2; ++i)
#pragma unroll
        for (int j = 0; j < 4; ++j) a2[i][j] = (f32x4){0.f, 0.f, 0.f, 0.f};

    for (int ks = 0; ks < 8; ++ks) {
        __syncthreads();     // first iter: also publishes ffs, drains Bs reads
#pragma unroll
        for (int i = 0; i < 4; ++i) {
            int sB = i * 256 + tid;
            int r = sB >> 2, ck = (sB & 3) ^ ((r >> 1) & 3);
            gload_lds16(w2 + (size_t)r * 1024 + c * 256 + ks * 32 + ck * 8, &Bs[sB * 8]);
        }
        __syncthreads();

        bf16x8 af[2], bfv[4];
#pragma unroll
        for (int t = 0; t < 2; ++t)
            af[t] = *(const bf16x8*)&ffs[(t * 16 + fr) * 264 + ks * 32 + kb * 8];
#pragma unroll
        for (int t = 0; t < 4; ++t) bfv[t] = *(const bf16x8*)&Bs[oB[t]];
#pragma unroll
        for (int i = 0; i < 2; ++i)
#pragma unroll
            for (int j = 0; j < 4; ++j)
                a2[i][j] = __builtin_amdgcn_mfma_f32_16x16x32_bf16(af[i], bfv[j], a2[i][j], 0, 0, 0);
    }

    // write fp32 partials: part[c][row][col]
#pragma unroll
    for (int ct = 0; ct < 4; ++ct) {
        int col = wave * 64 + ct * 16 + cl;
#pragma unroll
        for (int rt = 0; rt < 2; ++rt)
#pragma unroll
            for (int r = 0; r < 4; ++r)
                part[((size_t)c * 4096 + bm + rt * 16 + q * 4 + r) * 256 + col] = a2[rt][ct][r];
    }
}

// ---------------------------------------------------------------------------
// Kernel 6: merge FFN2 partials + bias + h1 residual + LN2 (+final fold).
// ---------------------------------------------------------------------------
__global__ __launch_bounds__(256) void merge_ln2(
    const float* __restrict__ h1, const float* __restrict__ part,
    const float* __restrict__ f2b, const float* __restrict__ g2,
    const float* __restrict__ bt2,
    float* __restrict__ hout, unsigned short* __restrict__ hbf,
    const float* __restrict__ outW, const float* __restrict__ outb,
    float* __restrict__ out, int doFinal)
{
    int row = blockIdx.x * 4 + (threadIdx.x >> 6);
    int lane = threadIdx.x & 63;
    int d = lane * 4;

    float4 z = *(const float4*)(h1 + (size_t)row * 256 + d);
    float4 b4 = *(const float4*)(f2b + d);
    z.x += b4.x; z.y += b4.y; z.z += b4.z; z.w += b4.w;
#pragma unroll
    for (int c = 0; c < 4; ++c) {
        float4 p = *(const float4*)(part + ((size_t)c * 4096 + row) * 256 + d);
        z.x += p.x; z.y += p.y; z.z += p.z; z.w += p.w;
    }

    float s = z.x + z.y + z.z + z.w;
    float ss = z.x * z.x + z.y * z.y + z.z * z.z + z.w * z.w;
#pragma unroll
    for (int off = 1; off < 64; off <<= 1) {
        s += __shfl_xor(s, off);
        ss += __shfl_xor(ss, off);
    }
    float mean = s * (1.f / 256.f);
    float var = ss * (1.f / 256.f) - mean * mean;
    float inv = rsqrtf(var + 1e-5f);

    float4 g4 = *(const float4*)(g2 + d);
    float4 t4 = *(const float4*)(bt2 + d);
    float4 o;
    o.x = (z.x - mean) * inv * g4.x + t4.x;
    o.y = (z.y - mean) * inv * g4.y + t4.y;
    o.z = (z.z - mean) * inv * g4.z + t4.z;
    o.w = (z.w - mean) * inv * g4.w + t4.w;
    *(float4*)(hout + (size_t)row * 256 + d) = o;
    unsigned int u01 = (unsigned)f2bf(o.x) | ((unsigned)f2bf(o.y) << 16);
    unsigned int u23 = (unsigned)f2bf(o.z) | ((unsigned)f2bf(o.w) << 16);
    *(uint2*)&hbf[(size_t)row * 256 + d] = make_uint2(u01, u23);

    if (doFinal && (row == 2047 || row == 4095)) {
        float4 w4 = *(const float4*)(outW + d);
        float s2 = o.x * w4.x + o.y * w4.y + o.z * w4.z + o.w * w4.w;
#pragma unroll
        for (int off = 1; off < 64; off <<= 1) s2 += __shfl_xor(s2, off);
        if (lane == 0) out[row >> 11] = s2 * 0.5f + outb[0];
    }
}

// ---------------------------------------------------------------------------
extern "C" void kernel_launch(void* const* d_in, const int* in_sizes, int n_in,
                              void* d_out, int out_size, void* d_ws, size_t ws_size,
                              hipStream_t stream)
{
    (void)in_sizes; (void)n_in; (void)out_size; (void)ws_size;
    const float* x      = (const float*)d_in[0];
    const float* conv_w = (const float*)d_in[1];
    const float* conv_b = (const float*)d_in[2];
    const float* bn_g   = (const float*)d_in[3];
    const float* bn_b   = (const float*)d_in[4];
    const float* pe     = (const float*)d_in[5];
    const float* qW     = (const float*)d_in[6];
    const float* qb     = (const float*)d_in[7];
    const float* kW     = (const float*)d_in[8];
    const float* kb     = (const float*)d_in[9];
    const float* vW     = (const float*)d_in[10];
    const float* vb     = (const float*)d_in[11];
    const float* oW     = (const float*)d_in[12];
    const float* ob     = (const float*)d_in[13];
    const float* scale  = (const float*)d_in[14];
    const float* td     = (const float*)d_in[15];
    const float* ln1g   = (const float*)d_in[16];
    const float* ln1b   = (const float*)d_in[17];
    const float* f1W    = (const float*)d_in[18];
    const float* f1b    = (const float*)d_in[19];
    const float* f2W    = (const float*)d_in[20];
    const float* f2b    = (const float*)d_in[21];
    const float* ln2g   = (const float*)d_in[22];
    const float* ln2b   = (const float*)d_in[23];
    const float* outW   = (const float*)d_in[24];
    const float* outb   = (const float*)d_in[25];
    float* out = (float*)d_out;

    float* ws = (float*)d_ws;
    const size_t MT = (size_t)B_ * SEQ_ * D_;      // 1,048,576
    float* h     = ws;                             // MT fp32
    float* h1    = ws + MT;                        // MT fp32
    float* part  = ws + 2 * MT;                    // 4*MT fp32
    float* vtail = ws + 6 * MT;                    // 1024 fp32 (L*B*256)
    unsigned short* bfb = (unsigned short*)(ws + 6 * MT + 1024);
    unsigned short* h_bf   = bfb;
    unsigned short* ctx_bf = bfb + MT;
    unsigned short* q_bf   = bfb + 2 * MT;
    unsigned short* k_bf   = bfb + 3 * MT;
    unsigned short* v_bf   = bfb + 4 * MT;
    unsigned short* h1_bf  = bfb + 5 * MT;
    unsigned short* wq_bf  = bfb + 6 * MT;
    unsigned short* wk_bf  = wq_bf + MT / 8;
    unsigned short* wv_bf  = wk_bf + MT / 8;
    unsigned short* wo_bf  = wv_bf + MT / 8;
    unsigned short* wf1_bf = wo_bf + MT / 8;
    unsigned short* wf2_bf = wf1_bf + MT / 2;

    const int Mrows = B_ * SEQ_;                   // 4096

    prep_kernel<<<768 + (B_ * SEQ_ * D_) / 256, 256, 0, stream>>>(
        x, conv_w, conv_b, bn_g, bn_b, pe, h, h_bf,
        qW, kW, vW, oW, f1W, f2W,
        wq_bf, wk_bf, wv_bf, wo_bf, wf1_bf, wf2_bf, vtail);

    for (int l = 0; l < L_; ++l) {
        const unsigned short* wq_l  = wq_bf  + (size_t)l * D_ * D_;
        const unsigned short* wk_l  = wk_bf  + (size_t)l * D_ * D_;
        const unsigned short* wv_l  = wv_bf  + (size_t)l * D_ * D_;
        const unsigned short* wo_l  = wo_bf  + (size_t)l * D_ * D_;
        const unsigned short* wf1_l = wf1_bf + (size_t)l * DFF_ * D_;
        const unsigned short* wf2_l = wf2_bf + (size_t)l * DFF_ * D_;
        float* vtail_l = vtail + l * B_ * 256;

        gemm_qkv<<<dim3(D_ / 64, Mrows / 64, 3), 256, 0, stream>>>(
            h_bf, wq_l, wk_l, wv_l, qb + l * D_, kb + l * D_, vb + l * D_,
            q_bf, k_bf, v_bf, td + l * H_, vtail_l, Mrows, D_, D_);

        attn_kernel<<<dim3(SEQ_ / 32, H_, B_), 128, 0, stream>>>(
            q_bf, k_bf, v_bf, vtail_l, ctx_bf, scale + l, td + l * H_);

        oproj_ln1<<<Mrows / 16, 256, 0, stream>>>(
            ctx_bf, wo_l, ob + l * D_, h,
            ln1g + l * D_, ln1b + l * D_, h1, h1_bf);

        ffn_fused<<<dim3(4, Mrows / 32), 256, 0, stream>>>(
            h1_bf, wf1_l, f1b + l * DFF_, wf2_l, part);

        merge_ln2<<<Mrows / 4, 256, 0, stream>>>(
            h1, part, f2b + l * D_, ln2g + l * D_, ln2b + l * D_,
            h, h_bf, outW, outb, out, (l == L_ - 1) ? 1 : 0);
    }
}